// Round 1
// baseline (1171.247 us; speedup 1.0000x reference)
//
#include <hip/hip_runtime.h>
#include <stdint.h>
#include <float.h>

#define N_    384
#define NTHR  512

// dynamic LDS layout (bytes)
#define ATT_OFF   0              // float[384*8]     = 12288
#define EV_OFF    12288          // bf16[384*128]    = 98304 (uint4-swizzled rows)
#define UNI_OFF   110592         // 16384-byte union: invA f32[32*128] / avc bf16[64*128] / partb f32[512]
#define CATT_OFF  126976         // float[64]
#define RED_OFF   127232         // float[32]: [0]=mask count, [1..3]=coor acc
#define LDS_TOTAL 127360

__device__ __forceinline__ uint32_t f2bf(float x){
  union{float f; uint32_t u;} v; v.f = x;
  return (v.u + 0x7fffu + ((v.u >> 16) & 1u)) >> 16;   // RNE bf16
}
__device__ __forceinline__ uint32_t packbf(float a, float b){
  return f2bf(a) | (f2bf(b) << 16);
}
__device__ __forceinline__ void unpack8(uint4 u, float* f){
  uint32_t w[4] = {u.x, u.y, u.z, u.w};
  #pragma unroll
  for (int q = 0; q < 4; ++q){
    union{uint32_t u; float f;} lo, hi;
    lo.u = w[q] << 16; hi.u = w[q] & 0xffff0000u;
    f[2*q] = lo.f; f[2*q+1] = hi.f;
  }
}
__device__ __forceinline__ void ld8(const float* __restrict__ p, float* f){
  float4 a = *(const float4*)p, b = *(const float4*)(p + 4);
  f[0]=a.x; f[1]=a.y; f[2]=a.z; f[3]=a.w; f[4]=b.x; f[5]=b.y; f[6]=b.z; f[7]=b.w;
}
// octet swizzle: keeps strided-row b128 LDS reads to <=2-way bank aliasing (free)
__device__ __forceinline__ int sw16(int j, int o){ return (o + j + (j >> 3)) & 15; }

// ---------------- qk = x @ W_qk + b_qk ----------------
__global__ __launch_bounds__(256) void qk_kernel(
    const float* __restrict__ x, const float* __restrict__ Wqk,
    const float* __restrict__ bqk, float* __restrict__ qkout)
{
  __shared__ float xs[4][128];
  const int r0 = blockIdx.x * 4;
  const int t = threadIdx.x;
  for (int idx = t; idx < 512; idx += 256){
    int r = idx >> 7, k = idx & 127;
    xs[r][k] = x[(size_t)(r0 + r)*128 + k];
  }
  __syncthreads();
  float acc[4][2];
  #pragma unroll
  for (int r = 0; r < 4; ++r){ acc[r][0] = bqk[t]; acc[r][1] = bqk[t + 256]; }
  #pragma unroll 4
  for (int k = 0; k < 128; ++k){
    float w0 = Wqk[(size_t)k*512 + t], w1 = Wqk[(size_t)k*512 + t + 256];
    #pragma unroll
    for (int r = 0; r < 4; ++r){
      acc[r][0] = fmaf(xs[r][k], w0, acc[r][0]);
      acc[r][1] = fmaf(xs[r][k], w1, acc[r][1]);
    }
  }
  #pragma unroll
  for (int r = 0; r < 4; ++r){
    qkout[(size_t)(r0+r)*512 + t]       = acc[r][0];
    qkout[(size_t)(r0+r)*512 + t + 256] = acc[r][1];
  }
}

// ---------------- fused main kernel: one block per (b,i) ----------------
__global__ __launch_bounds__(NTHR, 1) void se3_main(
    const float* __restrict__ coor, const float* __restrict__ edge_attr,
    const float* __restrict__ We,   const float* __restrict__ be,
    const float* __restrict__ Wnode,const float* __restrict__ bnode,
    const float* __restrict__ Wedge,const float* __restrict__ bedge,
    const float* __restrict__ Wc1,  const float* __restrict__ bc1,
    const float* __restrict__ Wc2,  const float* __restrict__ bc2,
    const int* __restrict__ emask,  const int* __restrict__ fmask,
    const float* __restrict__ qk,
    float* __restrict__ node_out, float* __restrict__ edge_out, float* __restrict__ coor_out)
{
  extern __shared__ char smem[];
  float* att   = (float*)(smem + ATT_OFF);   // [384][8] logits -> probs
  uint4* ev4   = (uint4*)(smem + EV_OFF);    // [384][16] bf16x8 octets (swizzled)
  float* invA  = (float*)(smem + UNI_OFF);   // phase1 A-tile [32][128]
  uint4* avc4  = (uint4*)(smem + UNI_OFF);   // phase3 av chunk [64][16] bf16x8
  float* partb = (float*)(smem + UNI_OFF);   // node partials [512]
  float* catt  = (float*)(smem + CATT_OFF);  // [64]
  float* red   = (float*)(smem + RED_OFF);   // [32]

  const int t  = threadIdx.x;
  const int bi = blockIdx.x;
  const int b  = (bi >= N_) ? 1 : 0;
  const float cix = coor[bi*3+0], ciy = coor[bi*3+1], ciz = coor[bi*3+2];
  const size_t qk_i = (size_t)bi * 512;

  if (t < 32) red[t] = 0.f;

  // ---------- phase 1: e = leaky([edge_attr | rbf] @ W_e + b_e); logits + e_v ----------
  const int cblk = t & 31;          // 0..31 -> c0 = cblk*8 over 256 channels
  const int jblk1 = t >> 5;         // 0..15 -> 2 j's each
  const int c0 = cblk * 8;
  const int jj01 = jblk1 * 2;
  float lmv[8], bev[8];
  ld8(&qk[qk_i + c0], lmv);         // l_m[i] channels (used when cblk<16)
  ld8(&be[c0], bev);

  for (int jt = 0; jt < 12; ++jt){
    const int j0 = jt * 32;
    __syncthreads();
    for (int idx = t; idx < 32*128; idx += NTHR){
      const int jj = idx >> 7, k = idx & 127;
      const int j = j0 + jj;
      float v;
      if (k < 64){
        v = edge_attr[((size_t)bi*N_ + j)*64 + k];
      } else {
        const float dx = cix - coor[(size_t)(b*N_+j)*3+0];
        const float dy = ciy - coor[(size_t)(b*N_+j)*3+1];
        const float dz = ciz - coor[(size_t)(b*N_+j)*3+2];
        const float dist = sqrtf(dx*dx + dy*dy + dz*dz);
        const float dd = fminf(dist, 2.0f) - (float)(k - 64) * (2.0f/63.0f);
        v = __expf(-496.125f * dd * dd);   // coeff = -0.5/(2/63)^2
      }
      invA[idx] = v;
    }
    __syncthreads();

    float acc0[8], acc1[8];
    #pragma unroll
    for (int cc = 0; cc < 8; ++cc){ acc0[cc] = 0.f; acc1[cc] = 0.f; }
    #pragma unroll 2
    for (int k = 0; k < 128; k += 4){
      float4 a0v = *(const float4*)&invA[jj01*128 + k];
      float4 a1v = *(const float4*)&invA[(jj01+1)*128 + k];
      float a0[4] = {a0v.x, a0v.y, a0v.z, a0v.w};
      float a1[4] = {a1v.x, a1v.y, a1v.z, a1v.w};
      #pragma unroll
      for (int kk = 0; kk < 4; ++kk){
        float wv[8]; ld8(&We[(size_t)(k+kk)*256 + c0], wv);
        #pragma unroll
        for (int cc = 0; cc < 8; ++cc){
          acc0[cc] = fmaf(a0[kk], wv[cc], acc0[cc]);
          acc1[cc] = fmaf(a1[kk], wv[cc], acc1[cc]);
        }
      }
    }
    #pragma unroll
    for (int cc = 0; cc < 8; ++cc){
      float e0 = acc0[cc] + bev[cc]; acc0[cc] = e0 > 0.f ? e0 : 0.01f*e0;
      float e1 = acc1[cc] + bev[cc]; acc1[cc] = e1 > 0.f ? e1 : 0.01f*e1;
    }
    if (cblk < 16){
      // e_m half: tri-linear logits, reduce 8 d's here + partner thread via shfl
      const int h = cblk >> 1;
      #pragma unroll
      for (int jj = 0; jj < 2; ++jj){
        const int j = j0 + jj01 + jj;
        float rv[8]; ld8(&qk[(size_t)(b*N_+j)*512 + 128 + c0], rv);
        const float* ac = jj ? acc1 : acc0;
        float s = 0.f;
        #pragma unroll
        for (int cc = 0; cc < 8; ++cc) s += lmv[cc] * rv[cc] * ac[cc];
        s += __shfl_xor(s, 1);
        if ((cblk & 1) == 0){
          att[j*8 + h] = emask[(size_t)bi*N_ + j] ? s*0.25f : -FLT_MAX;
        }
      }
    } else {
      // e_v half: pack bf16x8 -> swizzled LDS
      const int o = cblk - 16;
      #pragma unroll
      for (int jj = 0; jj < 2; ++jj){
        const int j = j0 + jj01 + jj;
        const float* ac = jj ? acc1 : acc0;
        uint4 u;
        u.x = packbf(ac[0], ac[1]); u.y = packbf(ac[2], ac[3]);
        u.z = packbf(ac[4], ac[5]); u.w = packbf(ac[6], ac[7]);
        ev4[j*16 + sw16(j, o)] = u;
      }
    }
  }
  __syncthreads();

  // ---------- phase 2: softmax over j (one wave per h) + mask count ----------
  {
    const int h = t >> 6, lane = t & 63;
    float m = -FLT_MAX;
    #pragma unroll
    for (int q = 0; q < 6; ++q) m = fmaxf(m, att[(lane + q*64)*8 + h]);
    #pragma unroll
    for (int o = 32; o >= 1; o >>= 1) m = fmaxf(m, __shfl_xor(m, o));
    float pv[6], s = 0.f;
    #pragma unroll
    for (int q = 0; q < 6; ++q){ float p = __expf(att[(lane + q*64)*8 + h] - m); pv[q] = p; s += p; }
    #pragma unroll
    for (int o = 32; o >= 1; o >>= 1) s += __shfl_xor(s, o);
    const float inv = 1.f / s;
    #pragma unroll
    for (int q = 0; q < 6; ++q) att[(lane + q*64)*8 + h] = pv[q] * inv;
    int mk = (t < N_) ? (emask[(size_t)bi*N_ + t] != 0) : 0;
    unsigned long long bl = __ballot(mk);
    if (lane == 0) atomicAdd(&red[0], (float)__popcll(bl));
  }
  __syncthreads();

  // ---------- phase 2.5: fold p into e_v (evp = p * e_v) ----------
  for (int idx = t; idx < N_*16; idx += NTHR){
    const int j = idx >> 4, o = idx & 15;
    const float p = att[j*8 + (o >> 1)];
    const int a = j*16 + sw16(j, o);
    uint4 u = ev4[a];
    float f[8]; unpack8(u, f);
    u.x = packbf(f[0]*p, f[1]*p); u.y = packbf(f[2]*p, f[3]*p);
    u.z = packbf(f[4]*p, f[5]*p); u.w = packbf(f[6]*p, f[7]*p);
    ev4[a] = u;
  }
  __syncthreads();

  // ---------- edge_out = evp @ W_edge + b_edge (all 384 j, 6j x 8g per thread) ----------
  {
    const int gblk = t & 7, jblkE = t >> 3;     // 8 g-blocks x 64 j-blocks
    const int g0 = gblk*8, jj0E = jblkE*6;
    float eacc[6][8];
    #pragma unroll
    for (int jj = 0; jj < 6; ++jj)
      #pragma unroll
      for (int cc = 0; cc < 8; ++cc) eacc[jj][cc] = 0.f;
    for (int k = 0; k < 128; k += 8){
      const int o = k >> 3;
      uint4 ua[6];
      #pragma unroll
      for (int jj = 0; jj < 6; ++jj){ const int j = jj0E + jj; ua[jj] = ev4[j*16 + sw16(j, o)]; }
      #pragma unroll
      for (int kk = 0; kk < 8; ++kk){
        float wv[8]; ld8(&Wedge[(size_t)(k+kk)*64 + g0], wv);
        #pragma unroll
        for (int jj = 0; jj < 6; ++jj){
          const uint32_t uw = (&ua[jj].x)[kk >> 1];
          union{uint32_t u; float f;} av;
          av.u = (kk & 1) ? (uw & 0xffff0000u) : (uw << 16);
          #pragma unroll
          for (int cc = 0; cc < 8; ++cc) eacc[jj][cc] = fmaf(av.f, wv[cc], eacc[jj][cc]);
        }
      }
    }
    float beg[8]; ld8(&bedge[g0], beg);
    #pragma unroll
    for (int jj = 0; jj < 6; ++jj){
      float o8[8];
      #pragma unroll
      for (int cc = 0; cc < 8; ++cc) o8[cc] = eacc[jj][cc] + beg[cc];
      float* dst = &edge_out[((size_t)bi*N_ + (jj0E + jj))*64 + g0];
      *(float4*)dst       = *(float4*)o8;
      *(float4*)(dst + 4) = *(float4*)(o8 + 4);
    }
  }

  // ---------- phase 3: coor path, 6 chunks of 64 j ----------
  for (int ch = 0; ch < 6; ++ch){
    const int j0 = ch * 64;
    __syncthreads();
    if (t < 64) catt[t] = 0.f;
    for (int idx = t; idx < 64*16; idx += NTHR){
      const int jj = idx >> 4, o = idx & 15;
      const int j = j0 + jj, hd0 = o*8;
      uint4 u = ev4[j*16 + sw16(j, o)];
      float f[8]; unpack8(u, f);
      float lv[8]; ld8(&qk[qk_i + 256 + hd0], lv);
      float rv[8]; ld8(&qk[(size_t)(b*N_+j)*512 + 384 + hd0], rv);
      uint4 ou;
      ou.x = packbf(f[0]*lv[0]*rv[0], f[1]*lv[1]*rv[1]);
      ou.y = packbf(f[2]*lv[2]*rv[2], f[3]*lv[3]*rv[3]);
      ou.z = packbf(f[4]*lv[4]*rv[4], f[5]*lv[5]*rv[5]);
      ou.w = packbf(f[6]*lv[6]*rv[6], f[7]*lv[7]*rv[7]);
      avc4[jj*16 + sw16(jj, o)] = ou;
    }
    __syncthreads();
    {
      const int cb = t & 15, jb = t >> 4;   // 16 c-blocks x 32 j-blocks
      const int cc0 = cb*8, jjA = jb*2;
      float acc0[8], acc1[8];
      #pragma unroll
      for (int cc = 0; cc < 8; ++cc){ acc0[cc] = 0.f; acc1[cc] = 0.f; }
      for (int k = 0; k < 128; k += 8){
        const int o = k >> 3;
        uint4 u0 = avc4[jjA*16 + sw16(jjA, o)];
        uint4 u1 = avc4[(jjA+1)*16 + sw16(jjA+1, o)];
        float a0[8], a1[8]; unpack8(u0, a0); unpack8(u1, a1);
        #pragma unroll
        for (int kk = 0; kk < 8; ++kk){
          float wv[8]; ld8(&Wc1[(size_t)(k+kk)*128 + cc0], wv);
          #pragma unroll
          for (int cc = 0; cc < 8; ++cc){
            acc0[cc] = fmaf(a0[kk], wv[cc], acc0[cc]);
            acc1[cc] = fmaf(a1[kk], wv[cc], acc1[cc]);
          }
        }
      }
      float bcv[8]; ld8(&bc1[cc0], bcv);
      float w2v[8]; ld8(&Wc2[cc0], w2v);
      float s0 = 0.f, s1 = 0.f;
      #pragma unroll
      for (int cc = 0; cc < 8; ++cc){
        float y0 = acc0[cc] + bcv[cc]; y0 = y0 > 0.f ? y0 : 0.01f*y0; s0 += y0 * w2v[cc];
        float y1 = acc1[cc] + bcv[cc]; y1 = y1 > 0.f ? y1 : 0.01f*y1; s1 += y1 * w2v[cc];
      }
      atomicAdd(&catt[jjA],     s0);
      atomicAdd(&catt[jjA + 1], s1);
    }
    __syncthreads();
    if (t < 64){
      const int j = j0 + t;
      if (emask[(size_t)bi*N_ + j]){
        const float s = catt[t] + bc2[0];
        const float dx = cix - coor[(size_t)(b*N_+j)*3+0];
        const float dy = ciy - coor[(size_t)(b*N_+j)*3+1];
        const float dz = ciz - coor[(size_t)(b*N_+j)*3+2];
        const float nrm = sqrtf(dx*dx + dy*dy + dz*dz);
        if (nrm > 0.f){
          const float q = s / fmaxf(nrm, 1e-8f);
          atomicAdd(&red[1], q*dx);
          atomicAdd(&red[2], q*dy);
          atomicAdd(&red[3], q*dz);
        }
      }
    }
  }
  __syncthreads();

  // ---------- node path: einsum + W_node ----------
  {
    const int hf = t >> 8, c = t & 255;
    const int h = c >> 5, d2 = c & 31;
    const int chan = (d2 < 16) ? (256 + h*16 + d2) : (384 + h*16 + d2 - 16);
    float a0 = 0.f;
    const int jb = hf * 192;
    #pragma unroll 4
    for (int j = jb; j < jb + 192; ++j)
      a0 = fmaf(att[j*8 + h], qk[(size_t)(b*N_+j)*512 + chan], a0);
    partb[t] = a0;
  }
  __syncthreads();
  if (t < 256) partb[t] += partb[t + 256];
  __syncthreads();
  if (t < 128){
    float s = bnode[t];
    #pragma unroll 4
    for (int k = 0; k < 256; ++k) s = fmaf(partb[k], Wnode[(size_t)k*128 + t], s);
    node_out[(size_t)bi*128 + t] = s;
  }
  if (t < 3){
    coor_out[bi*3 + t] = red[1 + t] / (red[0] + 1e-7f) * (float)fmask[bi];
  }
}

extern "C" void kernel_launch(void* const* d_in, const int* in_sizes, int n_in,
                              void* d_out, int out_size, void* d_ws, size_t ws_size,
                              hipStream_t stream)
{
  const float* x     = (const float*)d_in[0];
  const float* coor  = (const float*)d_in[1];
  const float* eattr = (const float*)d_in[2];
  const float* Wqk   = (const float*)d_in[3];
  const float* bqk   = (const float*)d_in[4];
  const float* We    = (const float*)d_in[5];
  const float* be    = (const float*)d_in[6];
  const float* Wnode = (const float*)d_in[7];
  const float* bnode = (const float*)d_in[8];
  const float* Wedge = (const float*)d_in[9];
  const float* bedge = (const float*)d_in[10];
  const float* Wc1   = (const float*)d_in[11];
  const float* bc1   = (const float*)d_in[12];
  const float* Wc2   = (const float*)d_in[13];
  const float* bc2   = (const float*)d_in[14];
  const int*   emask = (const int*)d_in[15];
  const int*   fmask = (const int*)d_in[16];

  float* qkbuf = (float*)d_ws;                 // 768*512 f32 = 1.5 MB
  float* out      = (float*)d_out;
  float* node_out = out;                        // 2*384*128
  float* edge_out = out + 98304;                // 2*384*384*64
  float* coor_out = out + 98304 + 18874368;     // 2*384*3

  qk_kernel<<<dim3(192), dim3(256), 0, stream>>>(x, Wqk, bqk, qkbuf);
  se3_main<<<dim3(768), dim3(NTHR), LDS_TOTAL, stream>>>(
      coor, eattr, We, be, Wnode, bnode, Wedge, bedge,
      Wc1, bc1, Wc2, bc2, emask, fmask, qkbuf,
      node_out, edge_out, coor_out);
}

// Round 2
// 365.568 us; speedup vs baseline: 3.2039x; 3.2039x over previous
//
#include <hip/hip_runtime.h>
#include <stdint.h>
#include <float.h>

#define N_   384
#define NB   768
typedef unsigned short u16;
typedef unsigned int   u32;
typedef __attribute__((ext_vector_type(8))) short short8;   // 8 bf16 (4 VGPRs)
typedef __attribute__((ext_vector_type(4))) float f32x4;    // MFMA accumulator

__device__ __forceinline__ u32 f2bf(float x){
  union{float f; u32 u;} v; v.f = x;
  return (v.u + 0x7fffu + ((v.u >> 16) & 1u)) >> 16;   // RNE bf16
}
__device__ __forceinline__ float bf2f(u16 s){
  union{u32 u; float f;} v; v.u = ((u32)s) << 16; return v.f;
}
__device__ __forceinline__ u32 packbf(float a, float b){
  return f2bf(a) | (f2bf(b) << 16);
}
__device__ __forceinline__ uint4 pack8(const float* f){
  uint4 u;
  u.x = packbf(f[0],f[1]); u.y = packbf(f[2],f[3]);
  u.z = packbf(f[4],f[5]); u.w = packbf(f[6],f[7]);
  return u;
}
// element index into a [rows][128] bf16 tile with granule-XOR swizzle (16B granules)
__device__ __forceinline__ int swze(int row, int k){
  return row*128 + (((k >> 3) ^ (row & 7)) << 3) + (k & 7);
}

// ---------------- prep: transpose + bf16 + swizzle weights into ws ----------------
// WeT[256][128] from We[128][256]; WgT[64][128] from Wedge[128][64]; Wc1T[128][128] from Wc1[128][128]
__global__ __launch_bounds__(512) void prep_wt(
    const float* __restrict__ We, const float* __restrict__ Wedge,
    const float* __restrict__ Wc1, u16* __restrict__ WeT,
    u16* __restrict__ WgT, u16* __restrict__ Wc1T)
{
  const int id = blockIdx.x*512 + threadIdx.x;
  const float* src; u16* dst; int c, g, stride;
  if (id < 4096){        int q = id;      c = q>>4; g = q&15; src = We    + (size_t)g*8*256 + c; stride = 256; dst = WeT  + c*128 + ((g ^ (c&7))<<3); }
  else if (id < 5120){   int q = id-4096; c = q>>4; g = q&15; src = Wedge + (size_t)g*8*64  + c; stride = 64;  dst = WgT  + c*128 + ((g ^ (c&7))<<3); }
  else if (id < 7168){   int q = id-5120; c = q>>4; g = q&15; src = Wc1   + (size_t)g*8*128 + c; stride = 128; dst = Wc1T + c*128 + ((g ^ (c&7))<<3); }
  else return;
  float f[8];
  #pragma unroll
  for (int e = 0; e < 8; ++e) f[e] = src[(size_t)e*stride];
  *(uint4*)dst = pack8(f);
}

// ---------------- qk = x @ W_qk + b_qk  (bf16 out) ----------------
__global__ __launch_bounds__(256) void qk_kernel(
    const float* __restrict__ x, const float* __restrict__ Wqk,
    const float* __restrict__ bqk, u16* __restrict__ qkbf)
{
  __shared__ float xs[4][128];
  const int r0 = blockIdx.x * 4;
  const int t = threadIdx.x;
  for (int idx = t; idx < 512; idx += 256){
    int r = idx >> 7, k = idx & 127;
    xs[r][k] = x[(size_t)(r0 + r)*128 + k];
  }
  __syncthreads();
  float acc[4][2];
  #pragma unroll
  for (int r = 0; r < 4; ++r){ acc[r][0] = bqk[t]; acc[r][1] = bqk[t + 256]; }
  #pragma unroll 4
  for (int k = 0; k < 128; ++k){
    float w0 = Wqk[(size_t)k*512 + t], w1 = Wqk[(size_t)k*512 + t + 256];
    #pragma unroll
    for (int r = 0; r < 4; ++r){
      acc[r][0] = fmaf(xs[r][k], w0, acc[r][0]);
      acc[r][1] = fmaf(xs[r][k], w1, acc[r][1]);
    }
  }
  #pragma unroll
  for (int r = 0; r < 4; ++r){
    qkbf[(size_t)(r0+r)*512 + t]       = (u16)f2bf(acc[r][0]);
    qkbf[(size_t)(r0+r)*512 + t + 256] = (u16)f2bf(acc[r][1]);
  }
}

// ---------------- shared A-tile builder: [64 rows][128 k] = [edge_attr | rbf] bf16 swizzled ----------------
__device__ __forceinline__ void build_A(u16* As, int j0, int bi, int b, int t,
    const float* __restrict__ coor, const float* __restrict__ edge_attr,
    float cix, float ciy, float ciz)
{
  for (int idx = t; idx < 1024; idx += 512){
    const int row = idx >> 4, g = idx & 15;
    const int j = j0 + row;
    float f[8];
    if (g < 8){
      const float* src = &edge_attr[((size_t)bi*N_ + j)*64 + g*8];
      float4 a = *(const float4*)src, c4 = *(const float4*)(src + 4);
      f[0]=a.x; f[1]=a.y; f[2]=a.z; f[3]=a.w; f[4]=c4.x; f[5]=c4.y; f[6]=c4.z; f[7]=c4.w;
    } else {
      const float dx = cix - coor[(size_t)(b*N_+j)*3+0];
      const float dy = ciy - coor[(size_t)(b*N_+j)*3+1];
      const float dz = ciz - coor[(size_t)(b*N_+j)*3+2];
      const float dm = fminf(sqrtf(dx*dx + dy*dy + dz*dz), 2.0f);
      const int k0 = (g - 8)*8;
      #pragma unroll
      for (int e = 0; e < 8; ++e){
        const float dd = dm - (float)(k0+e)*(2.0f/63.0f);
        f[e] = __expf(-496.125f * dd * dd);   // coeff = -0.5/(2/63)^2
      }
    }
    ((uint4*)As)[row*16 + (g ^ (row & 7))] = pack8(f);
  }
}

// ---------------- pass A: e_m -> logits -> softmax -> probs to global ----------------
#define PA_ATT  0
#define PA_AS   12288
#define PA_WM   28672
#define PA_LM   61440
#define PA_SZ   61952

__global__ __launch_bounds__(512, 4) void pass_logits(
    const float* __restrict__ coor, const float* __restrict__ edge_attr,
    const float* __restrict__ be, const int* __restrict__ emask,
    const u16* __restrict__ qkbf, const u16* __restrict__ WeT,
    float* __restrict__ attw_base)
{
  extern __shared__ char smem[];
  float* att = (float*)(smem + PA_ATT);
  u16*   As  = (u16*)(smem + PA_AS);
  u16*   Wm  = (u16*)(smem + PA_WM);
  float* lmf = (float*)(smem + PA_LM);

  const int t = threadIdx.x, bi = blockIdx.x;
  const int b = (bi >= N_) ? 1 : 0;
  const float cix = coor[bi*3], ciy = coor[bi*3+1], ciz = coor[bi*3+2];

  for (int idx = t; idx < 2048; idx += 512) ((uint4*)Wm)[idx] = ((const uint4*)WeT)[idx];
  if (t < 128) lmf[t] = bf2f(qkbf[(size_t)bi*512 + t]);
  __syncthreads();

  const int w = t >> 6, l = t & 63;
  const int jsb = (w & 3) * 16, chh = w >> 2;
  const int lr = l & 15, kg = l >> 4;

  for (int ch = 0; ch < 6; ++ch){
    const int j0 = ch * 64;
    build_A(As, j0, bi, b, t, coor, edge_attr, cix, ciy, ciz);
    __syncthreads();

    f32x4 acc[4];
    #pragma unroll
    for (int f = 0; f < 4; ++f) acc[f] = (f32x4){0.f,0.f,0.f,0.f};
    #pragma unroll
    for (int ks = 0; ks < 4; ++ks){
      const int arow = jsb + lr;
      short8 a = *(const short8*)&As[swze(arow, ks*32 + kg*8)];
      #pragma unroll
      for (int f = 0; f < 4; ++f){
        const int c = chh*64 + f*16 + lr;
        short8 bb = *(const short8*)&Wm[swze(c, ks*32 + kg*8)];
        acc[f] = __builtin_amdgcn_mfma_f32_16x16x32_bf16(a, bb, acc[f], 0, 0, 0);
      }
    }
    #pragma unroll
    for (int f = 0; f < 4; ++f){
      const int c = chh*64 + f*16 + lr;
      const float bec = be[c], lmc = lmf[c];
      const int h = chh*4 + f;
      #pragma unroll
      for (int r = 0; r < 4; ++r){
        const int j = j0 + jsb + kg*4 + r;
        float e = acc[f][r] + bec; e = e > 0.f ? e : 0.01f*e;
        float rm = bf2f(qkbf[(size_t)(b*N_+j)*512 + 128 + c]);
        float s = lmc * rm * e;
        s += __shfl_xor(s, 1); s += __shfl_xor(s, 2);
        s += __shfl_xor(s, 4); s += __shfl_xor(s, 8);
        if (lr == 0)
          att[j*8 + h] = emask[(size_t)bi*N_ + j] ? s*0.25f : -FLT_MAX;
      }
    }
    __syncthreads();
  }

  // softmax over j (one wave per h)
  {
    const int h = t >> 6, lane = t & 63;
    float m = -FLT_MAX;
    #pragma unroll
    for (int q = 0; q < 6; ++q) m = fmaxf(m, att[(lane + q*64)*8 + h]);
    #pragma unroll
    for (int o = 32; o >= 1; o >>= 1) m = fmaxf(m, __shfl_xor(m, o));
    float pv[6], s = 0.f;
    #pragma unroll
    for (int q = 0; q < 6; ++q){ float p = __expf(att[(lane + q*64)*8 + h] - m); pv[q] = p; s += p; }
    #pragma unroll
    for (int o = 32; o >= 1; o >>= 1) s += __shfl_xor(s, o);
    const float inv = 1.f / s;
    #pragma unroll
    for (int q = 0; q < 6; ++q) att[(lane + q*64)*8 + h] = pv[q] * inv;
  }
  __syncthreads();
  float* attw = attw_base + (size_t)bi*24576 + 21504;   // tail of this block's edge_out slice
  for (int idx = t; idx < 3072; idx += 512) attw[idx] = att[idx];
}

// ---------------- pass B: e_v, edge GEMM, coor GEMM, node path ----------------
#define PB_ATT  0
#define PB_AS   12288
#define PB_EV   28672
#define PB_WV   45056
#define PB_WG   77824
#define PB_W1   94208
#define PB_QI   126976
#define PB_RED  129024
#define PB_SZ   129056

__global__ __launch_bounds__(512, 2) void pass_main(
    const float* __restrict__ coor, const float* __restrict__ edge_attr,
    const float* __restrict__ be, const float* __restrict__ bedge,
    const float* __restrict__ Wnode, const float* __restrict__ bnode,
    const float* __restrict__ bc1, const float* __restrict__ Wc2,
    const float* __restrict__ bc2, const int* __restrict__ emask,
    const int* __restrict__ fmask, const u16* __restrict__ qkbf,
    const u16* __restrict__ WeTg, const u16* __restrict__ WgTg,
    const u16* __restrict__ Wc1Tg,
    float* __restrict__ node_out, float* __restrict__ edge_out, float* __restrict__ coor_out)
{
  extern __shared__ char smem[];
  float* att = (float*)(smem + PB_ATT);
  u16*   As  = (u16*)(smem + PB_AS);
  u16*   Ev  = (u16*)(smem + PB_EV);
  u16*   Wv  = (u16*)(smem + PB_WV);
  u16*   Wg  = (u16*)(smem + PB_WG);
  u16*   W1  = (u16*)(smem + PB_W1);
  float* qif = (float*)(smem + PB_QI);
  float* red = (float*)(smem + PB_RED);

  const int t = threadIdx.x, bi = blockIdx.x;
  const int b = (bi >= N_) ? 1 : 0;
  const float cix = coor[bi*3], ciy = coor[bi*3+1], ciz = coor[bi*3+2];

  // stage weights/att/qk-row
  for (int idx = t; idx < 2048; idx += 512) ((uint4*)Wv)[idx] = ((const uint4*)(WeTg + 16384))[idx];
  for (int idx = t; idx < 1024; idx += 512) ((uint4*)Wg)[idx] = ((const uint4*)WgTg)[idx];
  for (int idx = t; idx < 2048; idx += 512) ((uint4*)W1)[idx] = ((const uint4*)Wc1Tg)[idx];
  {
    const float* attw = edge_out + (size_t)bi*24576 + 21504;
    for (int idx = t; idx < 768; idx += 512) ((float4*)att)[idx] = ((const float4*)attw)[idx];
  }
  qif[t] = bf2f(qkbf[(size_t)bi*512 + t]);
  if (t < 8) red[t] = 0.f;
  __syncthreads();

  if (t < N_){
    int mk = emask[(size_t)bi*N_ + t] != 0;
    unsigned long long bl = __ballot(mk);
    if ((t & 63) == 0) atomicAdd(&red[0], (float)__popcll(bl));
  }

  const int w = t >> 6, l = t & 63;
  const int jsb = (w & 3) * 16, chh = w >> 2;
  const int lr = l & 15, kg = l >> 4;

  for (int ch = 0; ch < 6; ++ch){
    const int j0 = ch * 64;
    build_A(As, j0, bi, b, t, coor, edge_attr, cix, ciy, ciz);
    __syncthreads();   // B1

    // ---- e_v GEMM: [64 j] x [128 c_v] ----
    f32x4 acc[4];
    #pragma unroll
    for (int f = 0; f < 4; ++f) acc[f] = (f32x4){0.f,0.f,0.f,0.f};
    #pragma unroll
    for (int ks = 0; ks < 4; ++ks){
      short8 a = *(const short8*)&As[swze(jsb + lr, ks*32 + kg*8)];
      #pragma unroll
      for (int f = 0; f < 4; ++f){
        const int cL = chh*64 + f*16 + lr;
        short8 bb = *(const short8*)&Wv[swze(cL, ks*32 + kg*8)];
        acc[f] = __builtin_amdgcn_mfma_f32_16x16x32_bf16(a, bb, acc[f], 0, 0, 0);
      }
    }
    // epilogue: leaky, *p, pack-pair -> Ev (evp)
    #pragma unroll
    for (int f = 0; f < 4; ++f){
      const int cL = chh*64 + f*16 + lr;
      const float bec = be[128 + cL];
      const int h = chh*4 + f;
      #pragma unroll
      for (int r = 0; r < 4; ++r){
        const int jl = jsb + kg*4 + r, j = j0 + jl;
        float e = acc[f][r] + bec; e = e > 0.f ? e : 0.01f*e;
        float ev = e * att[j*8 + h];
        float pr = __shfl_xor(ev, 1);
        if (!(l & 1)){
          u32 u = packbf(ev, pr);
          *(u32*)&Ev[jl*128 + (((cL>>3) ^ (jl&7))<<3) + (cL&7)] = u;
        }
      }
    }
    __syncthreads();   // B2

    // ---- edge GEMM: evp @ WedgeT -> edge_out ----
    {
      f32x4 eacc[2];
      eacc[0] = (f32x4){0.f,0.f,0.f,0.f}; eacc[1] = (f32x4){0.f,0.f,0.f,0.f};
      #pragma unroll
      for (int ks = 0; ks < 4; ++ks){
        short8 a = *(const short8*)&Ev[swze(jsb + lr, ks*32 + kg*8)];
        #pragma unroll
        for (int f = 0; f < 2; ++f){
          const int g = chh*32 + f*16 + lr;
          short8 bb = *(const short8*)&Wg[swze(g, ks*32 + kg*8)];
          eacc[f] = __builtin_amdgcn_mfma_f32_16x16x32_bf16(a, bb, eacc[f], 0, 0, 0);
        }
      }
      #pragma unroll
      for (int f = 0; f < 2; ++f){
        const int g = chh*32 + f*16 + lr;
        const float bg = bedge[g];
        #pragma unroll
        for (int r = 0; r < 4; ++r){
          const int j = j0 + jsb + kg*4 + r;
          edge_out[((size_t)bi*N_ + j)*64 + g] = eacc[f][r] + bg;
        }
      }
    }

    // ---- c1 GEMM: (lv*rv*evp) @ Wc1T -> coor_att ----
    {
      f32x4 cacc[4];
      #pragma unroll
      for (int f = 0; f < 4; ++f) cacc[f] = (f32x4){0.f,0.f,0.f,0.f};
      const int jrow = j0 + jsb + lr;
      #pragma unroll
      for (int ks = 0; ks < 4; ++ks){
        const int k0 = ks*32 + kg*8;
        short8 ar = *(const short8*)&Ev[swze(jsb + lr, k0)];
        uint4 rvu = *(const uint4*)&qkbf[(size_t)(b*N_+jrow)*512 + 384 + k0];
        short8 am;
        u16* arp = (u16*)&ar; u16* rvp = (u16*)&rvu; u16* amp = (u16*)&am;
        #pragma unroll
        for (int e = 0; e < 8; ++e)
          amp[e] = (u16)f2bf(bf2f(arp[e]) * qif[256 + k0 + e] * bf2f(rvp[e]));
        #pragma unroll
        for (int f = 0; f < 4; ++f){
          const int c2 = chh*64 + f*16 + lr;
          short8 bb = *(const short8*)&W1[swze(c2, k0)];
          cacc[f] = __builtin_amdgcn_mfma_f32_16x16x32_bf16(am, bb, cacc[f], 0, 0, 0);
        }
      }
      float sr[4] = {0.f, 0.f, 0.f, 0.f};
      #pragma unroll
      for (int f = 0; f < 4; ++f){
        const int c2 = chh*64 + f*16 + lr;
        const float b1 = bc1[c2], w2 = Wc2[c2];
        #pragma unroll
        for (int r = 0; r < 4; ++r){
          float y = cacc[f][r] + b1; y = y > 0.f ? y : 0.01f*y;
          sr[r] += y * w2;
        }
      }
      #pragma unroll
      for (int r = 0; r < 4; ++r){
        float s = sr[r];
        s += __shfl_xor(s, 1); s += __shfl_xor(s, 2);
        s += __shfl_xor(s, 4); s += __shfl_xor(s, 8);
        if (lr == 0){
          const int j = j0 + jsb + kg*4 + r;
          if (emask[(size_t)bi*N_ + j]){
            const float val = s + (chh == 0 ? bc2[0] : 0.f);
            const float dx = cix - coor[(size_t)(b*N_+j)*3+0];
            const float dy = ciy - coor[(size_t)(b*N_+j)*3+1];
            const float dz = ciz - coor[(size_t)(b*N_+j)*3+2];
            const float nrm = sqrtf(dx*dx + dy*dy + dz*dz);
            if (nrm > 0.f){
              const float q = val / fmaxf(nrm, 1e-8f);
              atomicAdd(&red[1], q*dx);
              atomicAdd(&red[2], q*dy);
              atomicAdd(&red[3], q*dz);
            }
          }
        }
      }
    }
  }
  __syncthreads();

  // ---- node path: sum_j p[j,h] * v[j, h, d2] then @ W_node ----
  float* partb = (float*)As;
  {
    const int hf = t >> 8, c = t & 255;
    const int h = c >> 5, d2 = c & 31;
    const int chan = 256 + (d2 < 16 ? h*16 + d2 : 128 + h*16 + (d2 - 16));
    float a0 = 0.f;
    const int jb = hf * 192;
    for (int j = jb; j < jb + 192; ++j)
      a0 = fmaf(att[j*8 + h], bf2f(qkbf[(size_t)(b*N_+j)*512 + chan]), a0);
    partb[t] = a0;
  }
  __syncthreads();
  if (t < 256) partb[t] += partb[t + 256];
  __syncthreads();
  if (t < 128){
    float s = bnode[t];
    #pragma unroll 4
    for (int k = 0; k < 256; ++k) s = fmaf(partb[k], Wnode[(size_t)k*128 + t], s);
    node_out[(size_t)bi*128 + t] = s;
  }
  if (t < 3)
    coor_out[bi*3 + t] = red[1 + t] / (red[0] + 1e-7f) * (float)fmask[bi];
}

extern "C" void kernel_launch(void* const* d_in, const int* in_sizes, int n_in,
                              void* d_out, int out_size, void* d_ws, size_t ws_size,
                              hipStream_t stream)
{
  const float* x     = (const float*)d_in[0];
  const float* coor  = (const float*)d_in[1];
  const float* eattr = (const float*)d_in[2];
  const float* Wqk   = (const float*)d_in[3];
  const float* bqk   = (const float*)d_in[4];
  const float* We    = (const float*)d_in[5];
  const float* be    = (const float*)d_in[6];
  const float* Wnode = (const float*)d_in[7];
  const float* bnode = (const float*)d_in[8];
  const float* Wedge = (const float*)d_in[9];
  const float* bedge = (const float*)d_in[10];
  const float* Wc1   = (const float*)d_in[11];
  const float* bc1   = (const float*)d_in[12];
  const float* Wc2   = (const float*)d_in[13];
  const float* bc2   = (const float*)d_in[14];
  const int*   emask = (const int*)d_in[15];
  const int*   fmask = (const int*)d_in[16];

  // ws layout (all within the known-safe 1.5 MB)
  u16* qkbf = (u16*)d_ws;                         // 768*512 bf16 = 786432 B
  u16* WeT  = (u16*)((char*)d_ws + 786432);       // 65536 B
  u16* WgT  = (u16*)((char*)d_ws + 851968);       // 16384 B
  u16* Wc1T = (u16*)((char*)d_ws + 868352);       // 32768 B

  float* out      = (float*)d_out;
  float* node_out = out;                           // 2*384*128
  float* edge_out = out + 98304;                   // 2*384*384*64
  float* coor_out = out + 98304 + 18874368;        // 2*384*3

  prep_wt<<<dim3(14), dim3(512), 0, stream>>>(We, Wedge, Wc1, WeT, WgT, Wc1T);
  qk_kernel<<<dim3(192), dim3(256), 0, stream>>>(x, Wqk, bqk, qkbf);
  pass_logits<<<dim3(NB), dim3(512), PA_SZ, stream>>>(coor, eattr, be, emask, qkbf, WeT, edge_out);
  pass_main<<<dim3(NB), dim3(512), PB_SZ, stream>>>(
      coor, eattr, be, bedge, Wnode, bnode, bc1, Wc2, bc2,
      emask, fmask, qkbf, WeT, WgT, Wc1T, node_out, edge_out, coor_out);
}

// Round 3
// 318.547 us; speedup vs baseline: 3.6768x; 1.1476x over previous
//
#include <hip/hip_runtime.h>
#include <stdint.h>
#include <float.h>

#define N_   384
#define NB   768
typedef unsigned short u16;
typedef unsigned int   u32;
typedef __attribute__((ext_vector_type(8))) short short8;   // 8 bf16 (4 VGPRs)
typedef __attribute__((ext_vector_type(4))) float f32x4;    // MFMA accumulator

__device__ __forceinline__ u32 f2bf(float x){
  union{float f; u32 u;} v; v.f = x;
  return (v.u + 0x7fffu + ((v.u >> 16) & 1u)) >> 16;   // RNE bf16
}
__device__ __forceinline__ float bf2f(u16 s){
  union{u32 u; float f;} v; v.u = ((u32)s) << 16; return v.f;
}
__device__ __forceinline__ u32 packbf(float a, float b){
  return f2bf(a) | (f2bf(b) << 16);
}
__device__ __forceinline__ uint4 pack8(const float* f){
  uint4 u;
  u.x = packbf(f[0],f[1]); u.y = packbf(f[2],f[3]);
  u.z = packbf(f[4],f[5]); u.w = packbf(f[6],f[7]);
  return u;
}
__device__ __forceinline__ void unpack8(uint4 u, float* f){
  u32 w[4] = {u.x, u.y, u.z, u.w};
  #pragma unroll
  for (int q = 0; q < 4; ++q){
    union{u32 u; float f;} lo, hi;
    lo.u = w[q] << 16; hi.u = w[q] & 0xffff0000u;
    f[2*q] = lo.f; f[2*q+1] = hi.f;
  }
}
// element index into a [rows][128] bf16 tile, 16B-granule XOR swizzle
__device__ __forceinline__ int swze(int row, int k){
  return row*128 + (((k >> 3) ^ (row & 7)) << 3) + (k & 7);
}

// ---------------- prep: transpose + bf16 + swizzle weights ----------------
__global__ __launch_bounds__(512) void prep_wt(
    const float* __restrict__ We, const float* __restrict__ Wedge,
    const float* __restrict__ Wc1, u16* __restrict__ WeT,
    u16* __restrict__ WgT, u16* __restrict__ Wc1T)
{
  const int id = blockIdx.x*512 + threadIdx.x;
  const float* src; u16* dst; int c, g, stride;
  if (id < 4096){        int q = id;      c = q>>4; g = q&15; src = We    + (size_t)g*8*256 + c; stride = 256; dst = WeT  + c*128 + ((g ^ (c&7))<<3); }
  else if (id < 5120){   int q = id-4096; c = q>>4; g = q&15; src = Wedge + (size_t)g*8*64  + c; stride = 64;  dst = WgT  + c*128 + ((g ^ (c&7))<<3); }
  else if (id < 7168){   int q = id-5120; c = q>>4; g = q&15; src = Wc1   + (size_t)g*8*128 + c; stride = 128; dst = Wc1T + c*128 + ((g ^ (c&7))<<3); }
  else return;
  float f[8];
  #pragma unroll
  for (int e = 0; e < 8; ++e) f[e] = src[(size_t)e*stride];
  *(uint4*)dst = pack8(f);
}

// ---------------- qk = x @ W_qk + b_qk  (bf16 out) ----------------
__global__ __launch_bounds__(256) void qk_kernel(
    const float* __restrict__ x, const float* __restrict__ Wqk,
    const float* __restrict__ bqk, u16* __restrict__ qkbf)
{
  __shared__ float xs[4][128];
  const int r0 = blockIdx.x * 4;
  const int t = threadIdx.x;
  for (int idx = t; idx < 512; idx += 256){
    int r = idx >> 7, k = idx & 127;
    xs[r][k] = x[(size_t)(r0 + r)*128 + k];
  }
  __syncthreads();
  float acc[4][2];
  #pragma unroll
  for (int r = 0; r < 4; ++r){ acc[r][0] = bqk[t]; acc[r][1] = bqk[t + 256]; }
  #pragma unroll 4
  for (int k = 0; k < 128; ++k){
    float w0 = Wqk[(size_t)k*512 + t], w1 = Wqk[(size_t)k*512 + t + 256];
    #pragma unroll
    for (int r = 0; r < 4; ++r){
      acc[r][0] = fmaf(xs[r][k], w0, acc[r][0]);
      acc[r][1] = fmaf(xs[r][k], w1, acc[r][1]);
    }
  }
  #pragma unroll
  for (int r = 0; r < 4; ++r){
    qkbf[(size_t)(r0+r)*512 + t]       = (u16)f2bf(acc[r][0]);
    qkbf[(size_t)(r0+r)*512 + t + 256] = (u16)f2bf(acc[r][1]);
  }
}

// ---------------- fused main kernel ----------------
// LDS layout (bytes)
#define L_ATT   0        // 12288 : float att[384*8]
#define L_AS    12288    // 32768 : bf16 As[2][64][128]   (phase2: Ev dbuf)
#define L_WE    45056    // 65536 : bf16 WeT[256][128]    (phase1)
#define L_WG    45056    // 16384 : bf16 Wg[64][128]      (phase2)
#define L_W1    61440    // 32768 : bf16 W1s[128][128]    (phase2, lv-folded)
#define L_PART  94208    // 16384 : float part[16][256]   (node)
#define L_EVP   110592   // 16384 : bf16 Evpack[64][128]  (phase1)
#define L_CATT  110592   // 3072  : float catt[2][384]    (phase2)
#define L_RED2  113664   // 1024  : float red2[256]
#define L_MISC  126976   // 512   : float misc[128]
#define L_QIF   127488   // 2048  : float qif[512]
#define L_TOTAL 129536

__global__ __launch_bounds__(512, 1) void se3_fused(
    const float* __restrict__ coor, const float* __restrict__ edge_attr,
    const float* __restrict__ be, const float* __restrict__ bedge,
    const float* __restrict__ Wnode, const float* __restrict__ bnode,
    const float* __restrict__ bc1, const float* __restrict__ Wc2,
    const float* __restrict__ bc2, const int* __restrict__ emask,
    const int* __restrict__ fmask, const u16* __restrict__ qkbf,
    const u16* __restrict__ WeTg, const u16* __restrict__ WgTg,
    const u16* __restrict__ Wc1Tg,
    float* __restrict__ node_out, float* __restrict__ edge_out, float* __restrict__ coor_out)
{
  extern __shared__ char smem[];
  float* att  = (float*)(smem + L_ATT);
  float* qif  = (float*)(smem + L_QIF);
  float* misc = (float*)(smem + L_MISC);

  const int t  = threadIdx.x;
  const int bi = blockIdx.x;
  const int b  = (bi >= N_) ? 1 : 0;
  const float cix = coor[bi*3], ciy = coor[bi*3+1], ciz = coor[bi*3+2];

  const int w  = t >> 6, l = t & 63;
  const int chh = w >> 2, jsb = (w & 3) * 16;
  const int lr = l & 15, kg = l >> 4;

  // ---- stage WeT + qif ----
  for (int idx = t; idx < 4096; idx += 512)
    ((uint4*)(smem + L_WE))[idx] = ((const uint4*)WeTg)[idx];
  qif[t] = bf2f(qkbf[(size_t)bi*512 + t]);
  __syncthreads();

  // per-wave hoisted constants for phase 1
  float bevf[8], lmvf[8];
  #pragma unroll
  for (int f = 0; f < 8; ++f){
    const int c = chh*128 + f*16 + lr;
    bevf[f] = be[c];
    lmvf[f] = (chh == 0) ? qif[c] : 0.f;
  }

  // edge_attr prefetch regs (threads with (t&15)<8 own rows t>>4 and t>>4+32)
  float4 pa0, pb0, pa1, pb1;
  const int gq = t & 15, rq = t >> 4;
  auto issue_ea = [&](int j0){
    if (gq < 8){
      const float* s0 = &edge_attr[((size_t)bi*N_ + j0 + rq)*64 + gq*8];
      const float* s1 = &edge_attr[((size_t)bi*N_ + j0 + rq + 32)*64 + gq*8];
      pa0 = *(const float4*)s0; pb0 = *(const float4*)(s0 + 4);
      pa1 = *(const float4*)s1; pb1 = *(const float4*)(s1 + 4);
    }
  };

  uint4* evg = (uint4*)(edge_out + (size_t)bi*24576);   // this block's edge slice

  // ================= phase 1: e-GEMM -> logits + e_v(bf16)->global =================
  issue_ea(0);
  for (int ch = 0; ch < 6; ++ch){
    const int j0 = ch * 64;
    // write As[ch&1] from regs + RBF
    {
      u16* As = (u16*)(smem + L_AS + (ch & 1)*16384);
      #pragma unroll
      for (int q = 0; q < 2; ++q){
        const int row = rq + q*32;
        const int j = j0 + row;
        float f[8];
        if (gq < 8){
          float4 A = q ? pa1 : pa0, Bv = q ? pb1 : pb0;
          f[0]=A.x; f[1]=A.y; f[2]=A.z; f[3]=A.w;
          f[4]=Bv.x; f[5]=Bv.y; f[6]=Bv.z; f[7]=Bv.w;
        } else {
          const float dx = cix - coor[(size_t)(b*N_+j)*3+0];
          const float dy = ciy - coor[(size_t)(b*N_+j)*3+1];
          const float dz = ciz - coor[(size_t)(b*N_+j)*3+2];
          const float dm = fminf(sqrtf(dx*dx + dy*dy + dz*dz), 2.0f);
          const int k0 = (gq - 8)*8;
          #pragma unroll
          for (int e = 0; e < 8; ++e){
            const float dd = dm - (float)(k0+e)*(2.0f/63.0f);
            f[e] = __expf(-496.125f * dd * dd);
          }
        }
        ((uint4*)As)[row*16 + (gq ^ (row & 7))] = pack8(f);
      }
    }
    __syncthreads();   // A: As visible; prev Evpack copy reads done
    if (ch + 1 < 6) issue_ea((ch+1)*64);   // in flight under GEMM+epilogue

    // GEMM: 8 fragments over 256 channels
    f32x4 acc[8];
    #pragma unroll
    for (int f = 0; f < 8; ++f) acc[f] = (f32x4){0.f,0.f,0.f,0.f};
    {
      u16* As  = (u16*)(smem + L_AS + (ch & 1)*16384);
      u16* WeL = (u16*)(smem + L_WE);
      #pragma unroll
      for (int ks = 0; ks < 4; ++ks){
        const int k0 = ks*32 + kg*8;
        short8 a = *(const short8*)&As[swze(jsb + lr, k0)];
        #pragma unroll
        for (int f = 0; f < 8; ++f){
          const int c = chh*128 + f*16 + lr;
          short8 bb = *(const short8*)&WeL[swze(c, k0)];
          acc[f] = __builtin_amdgcn_mfma_f32_16x16x32_bf16(a, bb, acc[f], 0, 0, 0);
        }
      }
    }
    if (chh == 0){
      // logits epilogue: head h = f
      #pragma unroll
      for (int f = 0; f < 8; ++f){
        #pragma unroll
        for (int r = 0; r < 4; ++r){
          const int j = j0 + jsb + kg*4 + r;
          float e = acc[f][r] + bevf[f]; e = e > 0.f ? e : 0.01f*e;
          const float rm = bf2f(qkbf[(size_t)(b*N_+j)*512 + 128 + f*16 + lr]);
          float s = lmvf[f] * rm * e;
          s += __shfl_xor(s, 1); s += __shfl_xor(s, 2);
          s += __shfl_xor(s, 4); s += __shfl_xor(s, 8);
          if (lr == 0)
            att[j*8 + f] = emask[(size_t)bi*N_ + j] ? s*0.25f : -FLT_MAX;
        }
      }
    } else {
      // e_v pack epilogue -> Evpack (swizzled)
      u16* Evp = (u16*)(smem + L_EVP);
      #pragma unroll
      for (int f = 0; f < 8; ++f){
        #pragma unroll
        for (int r = 0; r < 4; ++r){
          float e = acc[f][r] + bevf[f]; e = e > 0.f ? e : 0.01f*e;
          const float pr = __shfl_xor(e, 1);
          if (!(lr & 1)){
            const int jl = jsb + kg*4 + r;
            const int cv = f*16 + lr;
            *(u32*)&Evp[jl*128 + (((cv>>3) ^ (jl&7))<<3) + (cv&7)] = packbf(e, pr);
          }
        }
      }
    }
    __syncthreads();   // B: Evpack complete (drains ea prefetch under GEMM)
    // copy Evpack -> global (verbatim, swizzle preserved)
    {
      const uint4* Evp4 = (const uint4*)(smem + L_EVP);
      #pragma unroll
      for (int q = 0; q < 2; ++q)
        evg[ch*1024 + t + q*512] = Evp4[t + q*512];
    }
  }

  // ================= softmax over j (one wave per h) =================
  {
    const int h = w, lane = l;
    float m = -FLT_MAX;
    #pragma unroll
    for (int q = 0; q < 6; ++q) m = fmaxf(m, att[(lane + q*64)*8 + h]);
    #pragma unroll
    for (int o = 32; o >= 1; o >>= 1) m = fmaxf(m, __shfl_xor(m, o));
    float pv[6], s = 0.f;
    #pragma unroll
    for (int q = 0; q < 6; ++q){ float p = __expf(att[(lane + q*64)*8 + h] - m); pv[q] = p; s += p; }
    #pragma unroll
    for (int o = 32; o >= 1; o >>= 1) s += __shfl_xor(s, o);
    const float inv = 1.f / s;
    #pragma unroll
    for (int q = 0; q < 6; ++q) att[(lane + q*64)*8 + h] = pv[q] * inv;
  }

  // ================= stage phase-2 weights (overwrites WeT) =================
  for (int idx = t; idx < 1024; idx += 512)
    ((uint4*)(smem + L_WG))[idx] = ((const uint4*)WgTg)[idx];
  for (int idx = t; idx < 2048; idx += 512){
    const int c = idx >> 4, g = idx & 15;
    uint4 u = ((const uint4*)Wc1Tg)[idx];
    const int k0 = ((g ^ (c & 7)) << 3);
    float f[8]; unpack8(u, f);
    #pragma unroll
    for (int e = 0; e < 8; ++e) f[e] *= qif[256 + k0 + e];   // fold l_v
    ((uint4*)(smem + L_W1))[idx] = pack8(f);
  }

  // phase-2 hoisted constants
  float bgv[2], bc1v[4], w2v[4];
  #pragma unroll
  for (int f = 0; f < 2; ++f) bgv[f] = bedge[chh*32 + f*16 + lr];
  #pragma unroll
  for (int f = 0; f < 4; ++f){
    const int c2 = chh*64 + f*16 + lr;
    bc1v[f] = bc1[c2]; w2v[f] = Wc2[c2];
  }

  // e_v readback regs
  uint4 eva, evb;
  auto issue_ev = [&](int ch){
    eva = evg[ch*1024 + t];
    evb = evg[ch*1024 + t + 512];
  };
  issue_ev(0);
  __syncthreads();   // weights + att final visible

  float* catt = (float*)(smem + L_CATT);

  // ================= phase 2: edge GEMM + c1 GEMM =================
  for (int ch = 0; ch < 6; ++ch){
    const int j0 = ch * 64;
    {
      uint4* Ev4 = (uint4*)(smem + L_AS + (ch & 1)*16384);
      Ev4[t] = eva; Ev4[t + 512] = evb;
    }
    if (ch + 1 < 6) issue_ev(ch + 1);
    __syncthreads();

    u16* Ev  = (u16*)(smem + L_AS + (ch & 1)*16384);
    u16* WgL = (u16*)(smem + L_WG);
    u16* W1L = (u16*)(smem + L_W1);
    const int jrow = j0 + jsb + lr;

    f32x4 eacc[2], cacc[4];
    eacc[0] = (f32x4){0.f,0.f,0.f,0.f}; eacc[1] = (f32x4){0.f,0.f,0.f,0.f};
    #pragma unroll
    for (int f = 0; f < 4; ++f) cacc[f] = (f32x4){0.f,0.f,0.f,0.f};

    #pragma unroll
    for (int ks = 0; ks < 4; ++ks){
      const int k0 = ks*32 + kg*8;
      short8 ar = *(const short8*)&Ev[swze(jsb + lr, k0)];
      const float p = att[jrow*8 + (k0 >> 4)];
      uint4 rvu = *(const uint4*)&qkbf[(size_t)(b*N_+jrow)*512 + 384 + k0];
      short8 ame, amc;
      const u16* arp = (const u16*)&ar; const u16* rvp = (const u16*)&rvu;
      u16* amep = (u16*)&ame; u16* amcp = (u16*)&amc;
      #pragma unroll
      for (int e = 0; e < 8; ++e){
        const float ef = bf2f(arp[e]) * p;
        amep[e] = (u16)f2bf(ef);
        amcp[e] = (u16)f2bf(ef * bf2f(rvp[e]));
      }
      #pragma unroll
      for (int f = 0; f < 2; ++f){
        short8 bb = *(const short8*)&WgL[swze(chh*32 + f*16 + lr, k0)];
        eacc[f] = __builtin_amdgcn_mfma_f32_16x16x32_bf16(ame, bb, eacc[f], 0, 0, 0);
      }
      #pragma unroll
      for (int f = 0; f < 4; ++f){
        short8 bb = *(const short8*)&W1L[swze(chh*64 + f*16 + lr, k0)];
        cacc[f] = __builtin_amdgcn_mfma_f32_16x16x32_bf16(amc, bb, cacc[f], 0, 0, 0);
      }
    }
    // edge store (overwrites e_v rows just consumed)
    #pragma unroll
    for (int f = 0; f < 2; ++f){
      const int g = chh*32 + f*16 + lr;
      #pragma unroll
      for (int r = 0; r < 4; ++r){
        const int j = j0 + jsb + kg*4 + r;
        edge_out[((size_t)bi*N_ + j)*64 + g] = eacc[f][r] + bgv[f];
      }
    }
    // c1 reduce -> catt
    {
      float sr[4] = {0.f,0.f,0.f,0.f};
      #pragma unroll
      for (int f = 0; f < 4; ++f){
        #pragma unroll
        for (int r = 0; r < 4; ++r){
          float y = cacc[f][r] + bc1v[f]; y = y > 0.f ? y : 0.01f*y;
          sr[r] += y * w2v[f];
        }
      }
      #pragma unroll
      for (int r = 0; r < 4; ++r){
        float s = sr[r];
        s += __shfl_xor(s, 1); s += __shfl_xor(s, 2);
        s += __shfl_xor(s, 4); s += __shfl_xor(s, 8);
        if (lr == 0) catt[chh*N_ + j0 + jsb + kg*4 + r] = s;
      }
    }
  }
  __syncthreads();

  // ================= coor finale =================
  {
    float vx = 0.f, vy = 0.f, vz = 0.f, cnt = 0.f;
    if (t < N_){
      const int j = t;
      const int mk = emask[(size_t)bi*N_ + j];
      cnt = (mk != 0) ? 1.f : 0.f;
      if (mk){
        const float val = catt[j] + catt[N_ + j] + bc2[0];
        const float dx = cix - coor[(size_t)(b*N_+j)*3+0];
        const float dy = ciy - coor[(size_t)(b*N_+j)*3+1];
        const float dz = ciz - coor[(size_t)(b*N_+j)*3+2];
        const float nrm = sqrtf(dx*dx + dy*dy + dz*dz);
        if (nrm > 0.f){
          const float qq = val / fmaxf(nrm, 1e-8f);
          vx = qq*dx; vy = qq*dy; vz = qq*dz;
        }
      }
    }
    #pragma unroll
    for (int o = 32; o >= 1; o >>= 1){
      vx += __shfl_xor(vx, o); vy += __shfl_xor(vy, o);
      vz += __shfl_xor(vz, o); cnt += __shfl_xor(cnt, o);
    }
    if (l == 0){
      float* wr = misc + 16 + w*4;
      wr[0] = vx; wr[1] = vy; wr[2] = vz; wr[3] = cnt;
    }
  }
  __syncthreads();
  if (t == 0){
    float sx=0.f, sy=0.f, sz=0.f, sc=0.f;
    #pragma unroll
    for (int ww = 0; ww < 8; ++ww){
      sx += misc[16+ww*4]; sy += misc[16+ww*4+1];
      sz += misc[16+ww*4+2]; sc += misc[16+ww*4+3];
    }
    const float d = sc + 1e-7f, fm = (float)fmask[bi];
    coor_out[bi*3+0] = sx/d*fm; coor_out[bi*3+1] = sy/d*fm; coor_out[bi*3+2] = sz/d*fm;
  }

  // ================= node path =================
  {
    float* part = (float*)(smem + L_PART);
    const int c8 = t & 31, jg = t >> 5;
    const int ch0 = 256 + c8*8;
    const int h = (c8 < 16) ? (c8 >> 1) : ((c8 - 16) >> 1);
    const int slot0 = (c8 < 16) ? (h*32 + (c8 & 1)*8) : (h*32 + 16 + (c8 & 1)*8);
    float a8[8];
    #pragma unroll
    for (int e = 0; e < 8; ++e) a8[e] = 0.f;
    for (int q = 0; q < 24; ++q){
      const int j = jg*24 + q;
      const float p = att[j*8 + h];
      uint4 v = *(const uint4*)&qkbf[(size_t)(b*N_+j)*512 + ch0];
      const u16* vp = (const u16*)&v;
      #pragma unroll
      for (int e = 0; e < 8; ++e) a8[e] = fmaf(p, bf2f(vp[e]), a8[e]);
    }
    float4 o0 = {a8[0],a8[1],a8[2],a8[3]}, o1 = {a8[4],a8[5],a8[6],a8[7]};
    *(float4*)&part[jg*256 + slot0]     = o0;
    *(float4*)&part[jg*256 + slot0 + 4] = o1;
  }
  __syncthreads();
  {
    float* part = (float*)(smem + L_PART);
    float* red2 = (float*)(smem + L_RED2);
    if (t < 256){
      float s = 0.f;
      #pragma unroll
      for (int g = 0; g < 16; ++g) s += part[g*256 + t];
      red2[t] = s;
    }
  }
  __syncthreads();
  {
    float* part = (float*)(smem + L_PART);
    float* red2 = (float*)(smem + L_RED2);
    const int c = t & 127, qq = t >> 7;
    float s = 0.f;
    #pragma unroll 4
    for (int k = qq*64; k < qq*64 + 64; ++k)
      s = fmaf(red2[k], Wnode[(size_t)k*128 + c], s);
    part[qq*128 + c] = s;
    __syncthreads();
    if (t < 128)
      node_out[(size_t)bi*128 + t] = part[t] + part[128+t] + part[256+t] + part[384+t] + bnode[t];
  }
}

extern "C" void kernel_launch(void* const* d_in, const int* in_sizes, int n_in,
                              void* d_out, int out_size, void* d_ws, size_t ws_size,
                              hipStream_t stream)
{
  const float* x     = (const float*)d_in[0];
  const float* coor  = (const float*)d_in[1];
  const float* eattr = (const float*)d_in[2];
  const float* Wqk   = (const float*)d_in[3];
  const float* bqk   = (const float*)d_in[4];
  const float* We    = (const float*)d_in[5];
  const float* be    = (const float*)d_in[6];
  const float* Wnode = (const float*)d_in[7];
  const float* bnode = (const float*)d_in[8];
  const float* Wedge = (const float*)d_in[9];
  const float* bedge = (const float*)d_in[10];
  const float* Wc1   = (const float*)d_in[11];
  const float* bc1   = (const float*)d_in[12];
  const float* Wc2   = (const float*)d_in[13];
  const float* bc2   = (const float*)d_in[14];
  const int*   emask = (const int*)d_in[15];
  const int*   fmask = (const int*)d_in[16];

  u16* qkbf = (u16*)d_ws;                         // 786432 B
  u16* WeT  = (u16*)((char*)d_ws + 786432);       // 65536 B
  u16* WgT  = (u16*)((char*)d_ws + 851968);       // 16384 B
  u16* Wc1T = (u16*)((char*)d_ws + 868352);       // 32768 B

  float* out      = (float*)d_out;
  float* node_out = out;                           // 2*384*128
  float* edge_out = out + 98304;                   // 2*384*384*64
  float* coor_out = out + 98304 + 18874368;        // 2*384*3

  prep_wt<<<dim3(14), dim3(512), 0, stream>>>(We, Wedge, Wc1, WeT, WgT, Wc1T);
  qk_kernel<<<dim3(192), dim3(256), 0, stream>>>(x, Wqk, bqk, qkbf);
  se3_fused<<<dim3(NB), dim3(512), L_TOTAL, stream>>>(
      coor, eattr, be, bedge, Wnode, bnode, bc1, Wc2, bc2,
      emask, fmask, qkbf, WeT, WgT, Wc1T, node_out, edge_out, coor_out);
}

// Round 5
// 314.773 us; speedup vs baseline: 3.7209x; 1.0120x over previous
//
#include <hip/hip_runtime.h>
#include <stdint.h>
#include <float.h>

#define N_   384
#define NB   768
typedef unsigned short u16;
typedef unsigned int   u32;
typedef __attribute__((ext_vector_type(8))) short short8;   // 8 bf16 (4 VGPRs)
typedef __attribute__((ext_vector_type(4))) float f32x4;    // MFMA accumulator

__device__ __forceinline__ u32 f2bf(float x){
  union{float f; u32 u;} v; v.f = x;
  return (v.u + 0x7fffu + ((v.u >> 16) & 1u)) >> 16;   // RNE bf16
}
__device__ __forceinline__ float bf2f(u16 s){
  union{u32 u; float f;} v; v.u = ((u32)s) << 16; return v.f;
}
__device__ __forceinline__ u32 packbf(float a, float b){
  return f2bf(a) | (f2bf(b) << 16);
}
__device__ __forceinline__ uint4 pack8(const float* f){
  uint4 u;
  u.x = packbf(f[0],f[1]); u.y = packbf(f[2],f[3]);
  u.z = packbf(f[4],f[5]); u.w = packbf(f[6],f[7]);
  return u;
}
__device__ __forceinline__ void unpack8(uint4 u, float* f){
  u32 w[4] = {u.x, u.y, u.z, u.w};
  #pragma unroll
  for (int q = 0; q < 4; ++q){
    union{u32 u; float f;} lo, hi;
    lo.u = w[q] << 16; hi.u = w[q] & 0xffff0000u;
    f[2*q] = lo.f; f[2*q+1] = hi.f;
  }
}
// element index into a [rows][128] bf16 tile, 16B-granule XOR swizzle
__device__ __forceinline__ int swze(int row, int k){
  return row*128 + (((k >> 3) ^ (row & 7)) << 3) + (k & 7);
}

// ---------------- qk = x @ W_qk + b_qk  (bf16 out) ----------------
__global__ __launch_bounds__(256) void qk_kernel(
    const float* __restrict__ x, const float* __restrict__ Wqk,
    const float* __restrict__ bqk, u16* __restrict__ qkbf)
{
  __shared__ float xs[4][128];
  const int r0 = blockIdx.x * 4;
  const int t = threadIdx.x;
  for (int idx = t; idx < 512; idx += 256){
    int r = idx >> 7, k = idx & 127;
    xs[r][k] = x[(size_t)(r0 + r)*128 + k];
  }
  __syncthreads();
  float acc[4][2];
  #pragma unroll
  for (int r = 0; r < 4; ++r){ acc[r][0] = bqk[t]; acc[r][1] = bqk[t + 256]; }
  #pragma unroll 4
  for (int k = 0; k < 128; ++k){
    float w0 = Wqk[(size_t)k*512 + t], w1 = Wqk[(size_t)k*512 + t + 256];
    #pragma unroll
    for (int r = 0; r < 4; ++r){
      acc[r][0] = fmaf(xs[r][k], w0, acc[r][0]);
      acc[r][1] = fmaf(xs[r][k], w1, acc[r][1]);
    }
  }
  #pragma unroll
  for (int r = 0; r < 4; ++r){
    qkbf[(size_t)(r0+r)*512 + t]       = (u16)f2bf(acc[r][0]);
    qkbf[(size_t)(r0+r)*512 + t + 256] = (u16)f2bf(acc[r][1]);
  }
}

// =====================================================================
// ===================== PRIMARY (split) PATH ==========================
// =====================================================================

// fragment-major weight pack: frag (fc,ks): lane l holds W[k=ks*32+(l>>4)*8+e][c=fc*16+(l&15)]
__global__ __launch_bounds__(256) void prep_frag(
    const float* __restrict__ We, const float* __restrict__ Wedge,
    const float* __restrict__ Wc1, u16* __restrict__ WeF,
    u16* __restrict__ WgF, u16* __restrict__ W1F)
{
  const int id = blockIdx.x*256 + threadIdx.x;   // 28 blocks * 256 = 7168 = 112 frags * 64
  const int frag = id >> 6, lane = id & 63;
  if (frag >= 112) return;
  const float* src; u16* dst; int C, fc, ks;
  if (frag < 64){       fc = frag >> 2;      ks = frag & 3; src = We;    C = 256; dst = WeF + (size_t)frag*512; }
  else if (frag < 80){  int fr = frag - 64; fc = fr >> 2;   ks = fr & 3; src = Wedge; C = 64;  dst = WgF + (size_t)fr*512; }
  else {                int fr = frag - 80; fc = fr >> 2;   ks = fr & 3; src = Wc1;   C = 128; dst = W1F + (size_t)fr*512; }
  const int c = fc*16 + (lane & 15);
  const int kb = ks*32 + (lane >> 4)*8;
  float f[8];
  #pragma unroll
  for (int e = 0; e < 8; ++e) f[e] = src[(size_t)(kb + e)*C + c];
  *(uint4*)(dst + lane*8) = pack8(f);
}

// ---------------- K1: e-GEMM -> logits(ws) + e_v(bf16)->edge_out ----------------
__global__ __launch_bounds__(256, 4) void k1_logits_ev(
    const float* __restrict__ coor, const float* __restrict__ edge_attr,
    const float* __restrict__ be, const int* __restrict__ emask,
    const u16* __restrict__ qkbf, const u16* __restrict__ WeF,
    u16* __restrict__ attL, u16* __restrict__ evG)
{
  __shared__ u16 As[64*128];
  __shared__ u16 Evp[64*128];
  const int t = threadIdx.x;
  const int ch = blockIdx.x, bi = blockIdx.y;
  const int b = (bi >= N_) ? 1 : 0;
  const int j0 = ch * 64;
  const float cix = coor[bi*3], ciy = coor[bi*3+1], ciz = coor[bi*3+2];

  for (int idx = t; idx < 1024; idx += 256){
    const int row = idx >> 4, g = idx & 15;
    const int j = j0 + row;
    float f[8];
    if (g < 8){
      const float* src = &edge_attr[((size_t)bi*N_ + j)*64 + g*8];
      float4 a = *(const float4*)src, c4 = *(const float4*)(src + 4);
      f[0]=a.x; f[1]=a.y; f[2]=a.z; f[3]=a.w; f[4]=c4.x; f[5]=c4.y; f[6]=c4.z; f[7]=c4.w;
    } else {
      const float dx = cix - coor[(size_t)(b*N_+j)*3+0];
      const float dy = ciy - coor[(size_t)(b*N_+j)*3+1];
      const float dz = ciz - coor[(size_t)(b*N_+j)*3+2];
      const float dm = fminf(sqrtf(dx*dx + dy*dy + dz*dz), 2.0f);
      const int k0 = (g - 8)*8;
      #pragma unroll
      for (int e = 0; e < 8; ++e){
        const float dd = dm - (float)(k0+e)*(2.0f/63.0f);
        f[e] = __expf(-496.125f * dd * dd);   // coeff = -0.5/(2/63)^2
      }
    }
    ((uint4*)As)[row*16 + (g ^ (row & 7))] = pack8(f);
  }
  __syncthreads();

  const int w = t >> 6, l = t & 63, lr = l & 15, kg = l >> 4;
  f32x4 acc[4][4];
  #pragma unroll
  for (int js = 0; js < 4; ++js)
    #pragma unroll
    for (int f = 0; f < 4; ++f) acc[js][f] = (f32x4){0.f,0.f,0.f,0.f};

  #pragma unroll
  for (int ks = 0; ks < 4; ++ks){
    const int k0 = ks*32 + kg*8;
    short8 a[4];
    #pragma unroll
    for (int js = 0; js < 4; ++js) a[js] = *(const short8*)&As[swze(js*16 + lr, k0)];
    #pragma unroll
    for (int f = 0; f < 4; ++f){
      const int fc = w*4 + f;
      short8 bb = *(const short8*)&WeF[(size_t)((fc*4 + ks)*64 + l)*8];
      #pragma unroll
      for (int js = 0; js < 4; ++js)
        acc[js][f] = __builtin_amdgcn_mfma_f32_16x16x32_bf16(a[js], bb, acc[js][f], 0, 0, 0);
    }
  }

  if (w < 2){
    const u16 NEG = (u16)f2bf(-1e30f);
    #pragma unroll
    for (int f = 0; f < 4; ++f){
      const int c = w*64 + f*16 + lr;
      const float lm = bf2f(qkbf[(size_t)bi*512 + c]);
      const float bec = be[c];
      const int h = w*4 + f;
      #pragma unroll
      for (int js = 0; js < 4; ++js){
        #pragma unroll
        for (int r = 0; r < 4; ++r){
          const int j = j0 + js*16 + kg*4 + r;
          float e = acc[js][f][r] + bec; e = e > 0.f ? e : 0.01f*e;
          const float rm = bf2f(qkbf[(size_t)(b*N_+j)*512 + 128 + c]);
          float s = lm * rm * e;
          s += __shfl_xor(s, 1); s += __shfl_xor(s, 2);
          s += __shfl_xor(s, 4); s += __shfl_xor(s, 8);
          if (lr == 0){
            attL[(size_t)bi*3072 + j*8 + h] =
              emask[(size_t)bi*N_ + j] ? (u16)f2bf(s*0.25f) : NEG;
          }
        }
      }
    }
  } else {
    #pragma unroll
    for (int f = 0; f < 4; ++f){
      const int cv = (w-2)*64 + f*16 + lr;
      const float bec = be[128 + cv];
      #pragma unroll
      for (int js = 0; js < 4; ++js){
        #pragma unroll
        for (int r = 0; r < 4; ++r){
          float e = acc[js][f][r] + bec; e = e > 0.f ? e : 0.01f*e;
          const float pr = __shfl_xor(e, 1);
          if (!(lr & 1)){
            const int jl = js*16 + kg*4 + r;
            *(u32*)&Evp[jl*128 + (((cv>>3) ^ (jl&7))<<3) + (cv&7)] = packbf(e, pr);
          }
        }
      }
    }
  }
  __syncthreads();
  // park swizzled e_v image in this (bi,ch) slice of edge_out (coalesced)
  uint4* dst = (uint4*)evG + ((size_t)bi*6 + ch)*1024;
  const uint4* E4 = (const uint4*)Evp;
  #pragma unroll
  for (int q = 0; q < 4; ++q) dst[t + q*256] = E4[t + q*256];
}

// ---------------- K2: softmax over j, probs bf16 in place ----------------
__global__ __launch_bounds__(512) void k2_softmax(u16* __restrict__ attL)
{
  __shared__ u16 sl[3072];
  const int t = threadIdx.x, bi = blockIdx.x;
  uint4* sl4 = (uint4*)sl;
  if (t < 384) sl4[t] = ((const uint4*)(attL + (size_t)bi*3072))[t];
  __syncthreads();
  const int h = t >> 6, lane = t & 63;
  float v[6]; float m = -FLT_MAX;
  #pragma unroll
  for (int q = 0; q < 6; ++q){ v[q] = bf2f(sl[(lane + q*64)*8 + h]); m = fmaxf(m, v[q]); }
  #pragma unroll
  for (int o = 32; o >= 1; o >>= 1) m = fmaxf(m, __shfl_xor(m, o));
  float s = 0.f;
  #pragma unroll
  for (int q = 0; q < 6; ++q){ v[q] = __expf(v[q] - m); s += v[q]; }
  #pragma unroll
  for (int o = 32; o >= 1; o >>= 1) s += __shfl_xor(s, o);
  const float inv = 1.f / s;
  #pragma unroll
  for (int q = 0; q < 6; ++q) sl[(lane + q*64)*8 + h] = (u16)f2bf(v[q] * inv);
  __syncthreads();
  if (t < 384) ((uint4*)(attL + (size_t)bi*3072))[t] = sl4[t];
}

// ---------------- K3: edge GEMM + c1 GEMM per (bi, chunk) ----------------
__global__ __launch_bounds__(256, 4) void k3_edge_c1(
    const float* __restrict__ bedge, const float* __restrict__ bc1,
    const float* __restrict__ Wc2, const u16* __restrict__ qkbf,
    const u16* __restrict__ WgF, const u16* __restrict__ W1F,
    const u16* __restrict__ attL, float* __restrict__ edge_out,
    float* __restrict__ cattB)
{
  __shared__ u16 Ev[64*128];
  __shared__ u16 pS[64*8];
  const int t = threadIdx.x, ch = blockIdx.x, bi = blockIdx.y;
  const int b = (bi >= N_) ? 1 : 0;
  const int j0 = ch * 64;
  {
    const uint4* src = (const uint4*)edge_out + ((size_t)bi*6 + ch)*1024;
    uint4* E4 = (uint4*)Ev;
    #pragma unroll
    for (int q = 0; q < 4; ++q) E4[t + q*256] = src[t + q*256];
    if (t < 64) ((uint4*)pS)[t] = ((const uint4*)(attL + (size_t)bi*3072 + j0*8))[t];
  }
  __syncthreads();
  const int w = t >> 6, l = t & 63, lr = l & 15, kg = l >> 4;
  const int jsb = w * 16;
  const int jloc = jsb + lr;
  const int jglob = j0 + jloc;

  f32x4 eacc[4], cacc[8];
  #pragma unroll
  for (int f = 0; f < 4; ++f) eacc[f] = (f32x4){0.f,0.f,0.f,0.f};
  #pragma unroll
  for (int f = 0; f < 8; ++f) cacc[f] = (f32x4){0.f,0.f,0.f,0.f};

  #pragma unroll
  for (int ks = 0; ks < 4; ++ks){
    const int k0 = ks*32 + kg*8;
    short8 ar = *(const short8*)&Ev[swze(jloc, k0)];
    const float p = bf2f(pS[jloc*8 + (k0 >> 4)]);
    uint4 rvu = *(const uint4*)&qkbf[(size_t)(b*N_ + jglob)*512 + 384 + k0];
    uint4 lvu = *(const uint4*)&qkbf[(size_t)bi*512 + 256 + k0];
    short8 ame, amc;
    const u16* arp = (const u16*)&ar;
    const u16* rvp = (const u16*)&rvu;
    const u16* lvp = (const u16*)&lvu;
    u16* amep = (u16*)&ame; u16* amcp = (u16*)&amc;
    #pragma unroll
    for (int e = 0; e < 8; ++e){
      const float ef = bf2f(arp[e]) * p;
      amep[e] = (u16)f2bf(ef);
      amcp[e] = (u16)f2bf(ef * bf2f(lvp[e]) * bf2f(rvp[e]));
    }
    #pragma unroll
    for (int f = 0; f < 4; ++f){
      short8 bb = *(const short8*)&WgF[(size_t)((f*4 + ks)*64 + l)*8];
      eacc[f] = __builtin_amdgcn_mfma_f32_16x16x32_bf16(ame, bb, eacc[f], 0, 0, 0);
    }
    #pragma unroll
    for (int f = 0; f < 8; ++f){
      short8 bb = *(const short8*)&W1F[(size_t)((f*4 + ks)*64 + l)*8];
      cacc[f] = __builtin_amdgcn_mfma_f32_16x16x32_bf16(amc, bb, cacc[f], 0, 0, 0);
    }
  }
  // edge epilogue (overwrites this block's e_v image range — already staged)
  #pragma unroll
  for (int f = 0; f < 4; ++f){
    const int g = f*16 + lr;
    const float bg = bedge[g];
    #pragma unroll
    for (int r = 0; r < 4; ++r){
      const int j = j0 + jsb + kg*4 + r;
      edge_out[((size_t)bi*N_ + j)*64 + g] = eacc[f][r] + bg;
    }
  }
  // c1 epilogue: full 128-ch sum within wave -> catt[j]
  {
    float sr[4] = {0.f,0.f,0.f,0.f};
    #pragma unroll
    for (int f = 0; f < 8; ++f){
      const int c = f*16 + lr;
      const float b1 = bc1[c], w2 = Wc2[c];
      #pragma unroll
      for (int r = 0; r < 4; ++r){
        float y = cacc[f][r] + b1; y = y > 0.f ? y : 0.01f*y;
        sr[r] += y * w2;
      }
    }
    #pragma unroll
    for (int r = 0; r < 4; ++r){
      float s = sr[r];
      s += __shfl_xor(s, 1); s += __shfl_xor(s, 2);
      s += __shfl_xor(s, 4); s += __shfl_xor(s, 8);
      if (lr == 0) cattB[(size_t)bi*N_ + j0 + jsb + kg*4 + r] = s;
    }
  }
}

// ---------------- K4: node einsum + W_node + coor finale ----------------
__global__ __launch_bounds__(256) void k4_node_coor(
    const float* __restrict__ coor, const float* __restrict__ Wnode,
    const float* __restrict__ bnode, const float* __restrict__ bc2,
    const int* __restrict__ emask, const int* __restrict__ fmask,
    const u16* __restrict__ qkbf, const u16* __restrict__ attL,
    const float* __restrict__ cattB, float* __restrict__ node_out,
    float* __restrict__ coor_out)
{
  __shared__ u16 pS[3072];
  __shared__ float red[256];
  __shared__ float halfb[256];
  __shared__ float cred[16];
  const int t = threadIdx.x, bi = blockIdx.x;
  const int b = (bi >= N_) ? 1 : 0;
  for (int idx = t; idx < 384; idx += 256)           // FIX: full 384 uint4 (was t<192)
    ((uint4*)pS)[idx] = ((const uint4*)(attL + (size_t)bi*3072))[idx];
  __syncthreads();
  // node pre: thread t = c2
  {
    const int h = t >> 5, d2 = t & 31;
    const int chan = 256 + (d2 < 16 ? h*16 + d2 : 128 + h*16 + (d2 - 16));
    float a0=0.f, a1=0.f, a2=0.f, a3=0.f;
    for (int j = 0; j < N_; j += 4){
      a0 = fmaf(bf2f(pS[(j  )*8 + h]), bf2f(qkbf[(size_t)(b*N_+j  )*512 + chan]), a0);
      a1 = fmaf(bf2f(pS[(j+1)*8 + h]), bf2f(qkbf[(size_t)(b*N_+j+1)*512 + chan]), a1);
      a2 = fmaf(bf2f(pS[(j+2)*8 + h]), bf2f(qkbf[(size_t)(b*N_+j+2)*512 + chan]), a2);
      a3 = fmaf(bf2f(pS[(j+3)*8 + h]), bf2f(qkbf[(size_t)(b*N_+j+3)*512 + chan]), a3);
    }
    red[t] = (a0+a1)+(a2+a3);
  }
  __syncthreads();
  {
    const int c = t & 127, qq = t >> 7;
    float s = 0.f;
    #pragma unroll 4
    for (int k = qq*128; k < qq*128 + 128; ++k)
      s = fmaf(red[k], Wnode[(size_t)k*128 + c], s);
    halfb[t] = s;
  }
  __syncthreads();
  if (t < 128)
    node_out[(size_t)bi*128 + t] = halfb[t] + halfb[128 + t] + bnode[t];

  // coor
  {
    const float cix = coor[bi*3], ciy = coor[bi*3+1], ciz = coor[bi*3+2];
    float vx=0.f, vy=0.f, vz=0.f, cnt=0.f;
    for (int j = t; j < N_; j += 256){
      if (emask[(size_t)bi*N_ + j]){
        cnt += 1.f;
        const float val = cattB[(size_t)bi*N_ + j] + bc2[0];
        const float dx = cix - coor[(size_t)(b*N_+j)*3+0];
        const float dy = ciy - coor[(size_t)(b*N_+j)*3+1];
        const float dz = ciz - coor[(size_t)(b*N_+j)*3+2];
        const float nrm = sqrtf(dx*dx + dy*dy + dz*dz);
        if (nrm > 0.f){
          const float q = val / fmaxf(nrm, 1e-8f);
          vx += q*dx; vy += q*dy; vz += q*dz;
        }
      }
    }
    #pragma unroll
    for (int o = 32; o >= 1; o >>= 1){
      vx += __shfl_xor(vx, o); vy += __shfl_xor(vy, o);
      vz += __shfl_xor(vz, o); cnt += __shfl_xor(cnt, o);
    }
    const int w = t >> 6, l = t & 63;
    if (l == 0){ cred[w*4]=vx; cred[w*4+1]=vy; cred[w*4+2]=vz; cred[w*4+3]=cnt; }
  }
  __syncthreads();
  if (t == 0){
    float sx=0.f, sy=0.f, sz=0.f, sc=0.f;
    #pragma unroll
    for (int ww = 0; ww < 4; ++ww){
      sx += cred[ww*4]; sy += cred[ww*4+1]; sz += cred[ww*4+2]; sc += cred[ww*4+3];
    }
    const float d = sc + 1e-7f, fm = (float)fmask[bi];
    coor_out[bi*3+0] = sx/d*fm;
    coor_out[bi*3+1] = sy/d*fm;
    coor_out[bi*3+2] = sz/d*fm;
  }
}

// =====================================================================
// ================= FALLBACK (R3 monolithic) PATH =====================
// =====================================================================

__global__ __launch_bounds__(512) void prep_wt(
    const float* __restrict__ We, const float* __restrict__ Wedge,
    const float* __restrict__ Wc1, u16* __restrict__ WeT,
    u16* __restrict__ WgT, u16* __restrict__ Wc1T)
{
  const int id = blockIdx.x*512 + threadIdx.x;
  const float* src; u16* dst; int c, g, stride;
  if (id < 4096){        int q = id;      c = q>>4; g = q&15; src = We    + (size_t)g*8*256 + c; stride = 256; dst = WeT  + c*128 + ((g ^ (c&7))<<3); }
  else if (id < 5120){   int q = id-4096; c = q>>4; g = q&15; src = Wedge + (size_t)g*8*64  + c; stride = 64;  dst = WgT  + c*128 + ((g ^ (c&7))<<3); }
  else if (id < 7168){   int q = id-5120; c = q>>4; g = q&15; src = Wc1   + (size_t)g*8*128 + c; stride = 128; dst = Wc1T + c*128 + ((g ^ (c&7))<<3); }
  else return;
  float f[8];
  #pragma unroll
  for (int e = 0; e < 8; ++e) f[e] = src[(size_t)e*stride];
  *(uint4*)dst = pack8(f);
}

#define L_ATT   0
#define L_AS    12288
#define L_WE    45056
#define L_WG    45056
#define L_W1    61440
#define L_PART  94208
#define L_EVP   110592
#define L_CATT  110592
#define L_RED2  113664
#define L_MISC  126976
#define L_QIF   127488
#define L_TOTAL 129536

__global__ __launch_bounds__(512, 1) void se3_fused(
    const float* __restrict__ coor, const float* __restrict__ edge_attr,
    const float* __restrict__ be, const float* __restrict__ bedge,
    const float* __restrict__ Wnode, const float* __restrict__ bnode,
    const float* __restrict__ bc1, const float* __restrict__ Wc2,
    const float* __restrict__ bc2, const int* __restrict__ emask,
    const int* __restrict__ fmask, const u16* __restrict__ qkbf,
    const u16* __restrict__ WeTg, const u16* __restrict__ WgTg,
    const u16* __restrict__ Wc1Tg,
    float* __restrict__ node_out, float* __restrict__ edge_out, float* __restrict__ coor_out)
{
  extern __shared__ char smem[];
  float* att  = (float*)(smem + L_ATT);
  float* qif  = (float*)(smem + L_QIF);
  float* misc = (float*)(smem + L_MISC);

  const int t  = threadIdx.x;
  const int bi = blockIdx.x;
  const int b  = (bi >= N_) ? 1 : 0;
  const float cix = coor[bi*3], ciy = coor[bi*3+1], ciz = coor[bi*3+2];

  const int w  = t >> 6, l = t & 63;
  const int chh = w >> 2, jsb = (w & 3) * 16;
  const int lr = l & 15, kg = l >> 4;

  for (int idx = t; idx < 4096; idx += 512)
    ((uint4*)(smem + L_WE))[idx] = ((const uint4*)WeTg)[idx];
  qif[t] = bf2f(qkbf[(size_t)bi*512 + t]);
  __syncthreads();

  float bevf[8], lmvf[8];
  #pragma unroll
  for (int f = 0; f < 8; ++f){
    const int c = chh*128 + f*16 + lr;
    bevf[f] = be[c];
    lmvf[f] = (chh == 0) ? qif[c] : 0.f;
  }

  float4 pa0, pb0, pa1, pb1;
  const int gq = t & 15, rq = t >> 4;
  auto issue_ea = [&](int j0){
    if (gq < 8){
      const float* s0 = &edge_attr[((size_t)bi*N_ + j0 + rq)*64 + gq*8];
      const float* s1 = &edge_attr[((size_t)bi*N_ + j0 + rq + 32)*64 + gq*8];
      pa0 = *(const float4*)s0; pb0 = *(const float4*)(s0 + 4);
      pa1 = *(const float4*)s1; pb1 = *(const float4*)(s1 + 4);
    }
  };

  uint4* evg = (uint4*)(edge_out + (size_t)bi*24576);

  issue_ea(0);
  for (int ch = 0; ch < 6; ++ch){
    const int j0 = ch * 64;
    {
      u16* As = (u16*)(smem + L_AS + (ch & 1)*16384);
      #pragma unroll
      for (int q = 0; q < 2; ++q){
        const int row = rq + q*32;
        const int j = j0 + row;
        float f[8];
        if (gq < 8){
          float4 A = q ? pa1 : pa0, Bv = q ? pb1 : pb0;
          f[0]=A.x; f[1]=A.y; f[2]=A.z; f[3]=A.w;
          f[4]=Bv.x; f[5]=Bv.y; f[6]=Bv.z; f[7]=Bv.w;
        } else {
          const float dx = cix - coor[(size_t)(b*N_+j)*3+0];
          const float dy = ciy - coor[(size_t)(b*N_+j)*3+1];
          const float dz = ciz - coor[(size_t)(b*N_+j)*3+2];
          const float dm = fminf(sqrtf(dx*dx + dy*dy + dz*dz), 2.0f);
          const int k0 = (gq - 8)*8;
          #pragma unroll
          for (int e = 0; e < 8; ++e){
            const float dd = dm - (float)(k0+e)*(2.0f/63.0f);
            f[e] = __expf(-496.125f * dd * dd);
          }
        }
        ((uint4*)As)[row*16 + (gq ^ (row & 7))] = pack8(f);
      }
    }
    __syncthreads();
    if (ch + 1 < 6) issue_ea((ch+1)*64);

    f32x4 acc[8];
    #pragma unroll
    for (int f = 0; f < 8; ++f) acc[f] = (f32x4){0.f,0.f,0.f,0.f};
    {
      u16* As  = (u16*)(smem + L_AS + (ch & 1)*16384);
      u16* WeL = (u16*)(smem + L_WE);
      #pragma unroll
      for (int ks = 0; ks < 4; ++ks){
        const int k0 = ks*32 + kg*8;
        short8 a = *(const short8*)&As[swze(jsb + lr, k0)];
        #pragma unroll
        for (int f = 0; f < 8; ++f){
          const int c = chh*128 + f*16 + lr;
          short8 bb = *(const short8*)&WeL[swze(c, k0)];
          acc[f] = __builtin_amdgcn_mfma_f32_16x16x32_bf16(a, bb, acc[f], 0, 0, 0);
        }
      }
    }
    if (chh == 0){
      #pragma unroll
      for (int f = 0; f < 8; ++f){
        #pragma unroll
        for (int r = 0; r < 4; ++r){
          const int j = j0 + jsb + kg*4 + r;
          float e = acc[f][r] + bevf[f]; e = e > 0.f ? e : 0.01f*e;
          const float rm = bf2f(qkbf[(size_t)(b*N_+j)*512 + 128 + f*16 + lr]);
          float s = lmvf[f] * rm * e;
          s += __shfl_xor(s, 1); s += __shfl_xor(s, 2);
          s += __shfl_xor(s, 4); s += __shfl_xor(s, 8);
          if (lr == 0)
            att[j*8 + f] = emask[(size_t)bi*N_ + j] ? s*0.25f : -FLT_MAX;
        }
      }
    } else {
      u16* Evp = (u16*)(smem + L_EVP);
      #pragma unroll
      for (int f = 0; f < 8; ++f){
        #pragma unroll
        for (int r = 0; r < 4; ++r){
          float e = acc[f][r] + bevf[f]; e = e > 0.f ? e : 0.01f*e;
          const float pr = __shfl_xor(e, 1);
          if (!(lr & 1)){
            const int jl = jsb + kg*4 + r;
            const int cv = f*16 + lr;
            *(u32*)&Evp[jl*128 + (((cv>>3) ^ (jl&7))<<3) + (cv&7)] = packbf(e, pr);
          }
        }
      }
    }
    __syncthreads();
    {
      const uint4* Evp4 = (const uint4*)(smem + L_EVP);
      #pragma unroll
      for (int q = 0; q < 2; ++q)
        evg[ch*1024 + t + q*512] = Evp4[t + q*512];
    }
  }

  {
    const int h = w, lane = l;
    float m = -FLT_MAX;
    #pragma unroll
    for (int q = 0; q < 6; ++q) m = fmaxf(m, att[(lane + q*64)*8 + h]);
    #pragma unroll
    for (int o = 32; o >= 1; o >>= 1) m = fmaxf(m, __shfl_xor(m, o));
    float pv[6], s = 0.f;
    #pragma unroll
    for (int q = 0; q < 6; ++q){ float p = __expf(att[(lane + q*64)*8 + h] - m); pv[q] = p; s += p; }
    #pragma unroll
    for (int o = 32; o >= 1; o >>= 1) s += __shfl_xor(s, o);
    const float inv = 1.f / s;
    #pragma unroll
    for (int q = 0; q < 6; ++q) att[(lane + q*64)*8 + h] = pv[q] * inv;
  }

  for (int idx = t; idx < 1024; idx += 512)
    ((uint4*)(smem + L_WG))[idx] = ((const uint4*)WgTg)[idx];
  for (int idx = t; idx < 2048; idx += 512){
    const int c = idx >> 4, g = idx & 15;
    uint4 u = ((const uint4*)Wc1Tg)[idx];
    const int k0 = ((g ^ (c & 7)) << 3);
    float f[8]; unpack8(u, f);
    #pragma unroll
    for (int e = 0; e < 8; ++e) f[e] *= qif[256 + k0 + e];
    ((uint4*)(smem + L_W1))[idx] = pack8(f);
  }

  float bgv[2], bc1v[4], w2v[4];
  #pragma unroll
  for (int f = 0; f < 2; ++f) bgv[f] = bedge[chh*32 + f*16 + lr];
  #pragma unroll
  for (int f = 0; f < 4; ++f){
    const int c2 = chh*64 + f*16 + lr;
    bc1v[f] = bc1[c2]; w2v[f] = Wc2[c2];
  }

  uint4 eva, evb;
  auto issue_ev = [&](int ch){
    eva = evg[ch*1024 + t];
    evb = evg[ch*1024 + t + 512];
  };
  issue_ev(0);
  __syncthreads();

  float* catt = (float*)(smem + L_CATT);

  for (int ch = 0; ch < 6; ++ch){
    const int j0 = ch * 64;
    {
      uint4* Ev4 = (uint4*)(smem + L_AS + (ch & 1)*16384);
      Ev4[t] = eva; Ev4[t + 512] = evb;
    }
    if (ch + 1 < 6) issue_ev(ch + 1);
    __syncthreads();

    u16* Ev  = (u16*)(smem + L_AS + (ch & 1)*16384);
    u16* WgL = (u16*)(smem + L_WG);
    u16* W1L = (u16*)(smem + L_W1);
    const int jrow = j0 + jsb + lr;

    f32x4 eacc[2], cacc[4];
    eacc[0] = (f32x4){0.f,0.f,0.f,0.f}; eacc[1] = (f32x4){0.f,0.f,0.f,0.f};
    #pragma unroll
    for (int f = 0; f < 4; ++f) cacc[f] = (f32x4){0.f,0.f,0.f,0.f};

    #pragma unroll
    for (int ks = 0; ks < 4; ++ks){
      const int k0 = ks*32 + kg*8;
      short8 ar = *(const short8*)&Ev[swze(jsb + lr, k0)];
      const float p = att[jrow*8 + (k0 >> 4)];
      uint4 rvu = *(const uint4*)&qkbf[(size_t)(b*N_+jrow)*512 + 384 + k0];
      short8 ame, amc;
      const u16* arp = (const u16*)&ar; const u16* rvp = (const u16*)&rvu;
      u16* amep = (u16*)&ame; u16* amcp = (u16*)&amc;
      #pragma unroll
      for (int e = 0; e < 8; ++e){
        const float ef = bf2f(arp[e]) * p;
        amep[e] = (u16)f2bf(ef);
        amcp[e] = (u16)f2bf(ef * bf2f(rvp[e]));
      }
      #pragma unroll
      for (int f = 0; f < 2; ++f){
        short8 bb = *(const short8*)&WgL[swze(chh*32 + f*16 + lr, k0)];
        eacc[f] = __builtin_amdgcn_mfma_f32_16x16x32_bf16(ame, bb, eacc[f], 0, 0, 0);
      }
      #pragma unroll
      for (int f = 0; f < 4; ++f){
        short8 bb = *(const short8*)&W1L[swze(chh*64 + f*16 + lr, k0)];
        cacc[f] = __builtin_amdgcn_mfma_f32_16x16x32_bf16(amc, bb, cacc[f], 0, 0, 0);
      }
    }
    #pragma unroll
    for (int f = 0; f < 2; ++f){
      const int g = chh*32 + f*16 + lr;
      #pragma unroll
      for (int r = 0; r < 4; ++r){
        const int j = j0 + jsb + kg*4 + r;
        edge_out[((size_t)bi*N_ + j)*64 + g] = eacc[f][r] + bgv[f];
      }
    }
    {
      float sr[4] = {0.f,0.f,0.f,0.f};
      #pragma unroll
      for (int f = 0; f < 4; ++f){
        #pragma unroll
        for (int r = 0; r < 4; ++r){
          float y = cacc[f][r] + bc1v[f]; y = y > 0.f ? y : 0.01f*y;
          sr[r] += y * w2v[f];
        }
      }
      #pragma unroll
      for (int r = 0; r < 4; ++r){
        float s = sr[r];
        s += __shfl_xor(s, 1); s += __shfl_xor(s, 2);
        s += __shfl_xor(s, 4); s += __shfl_xor(s, 8);
        if (lr == 0) catt[chh*N_ + j0 + jsb + kg*4 + r] = s;
      }
    }
  }
  __syncthreads();

  {
    float vx = 0.f, vy = 0.f, vz = 0.f, cnt = 0.f;
    if (t < N_){
      const int j = t;
      const int mk = emask[(size_t)bi*N_ + j];
      cnt = (mk != 0) ? 1.f : 0.f;
      if (mk){
        const float val = catt[j] + catt[N_ + j] + bc2[0];
        const float dx = cix - coor[(size_t)(b*N_+j)*3+0];
        const float dy = ciy - coor[(size_t)(b*N_+j)*3+1];
        const float dz = ciz - coor[(size_t)(b*N_+j)*3+2];
        const float nrm = sqrtf(dx*dx + dy*dy + dz*dz);
        if (nrm > 0.f){
          const float qq = val / fmaxf(nrm, 1e-8f);
          vx = qq*dx; vy = qq*dy; vz = qq*dz;
        }
      }
    }
    #pragma unroll
    for (int o = 32; o >= 1; o >>= 1){
      vx += __shfl_xor(vx, o); vy += __shfl_xor(vy, o);
      vz += __shfl_xor(vz, o); cnt += __shfl_xor(cnt, o);
    }
    if (l == 0){
      float* wr = misc + 16 + w*4;
      wr[0] = vx; wr[1] = vy; wr[2] = vz; wr[3] = cnt;
    }
  }
  __syncthreads();
  if (t == 0){
    float sx=0.f, sy=0.f, sz=0.f, sc=0.f;
    #pragma unroll
    for (int ww = 0; ww < 8; ++ww){
      sx += misc[16+ww*4]; sy += misc[16+ww*4+1];
      sz += misc[16+ww*4+2]; sc += misc[16+ww*4+3];
    }
    const float d = sc + 1e-7f, fm = (float)fmask[bi];
    coor_out[bi*3+0] = sx/d*fm; coor_out[bi*3+1] = sy/d*fm; coor_out[bi*3+2] = sz/d*fm;
  }

  {
    float* part = (float*)(smem + L_PART);
    const int c8 = t & 31, jg = t >> 5;
    const int ch0 = 256 + c8*8;
    const int h = (c8 < 16) ? (c8 >> 1) : ((c8 - 16) >> 1);
    const int slot0 = (c8 < 16) ? (h*32 + (c8 & 1)*8) : (h*32 + 16 + (c8 & 1)*8);
    float a8[8];
    #pragma unroll
    for (int e = 0; e < 8; ++e) a8[e] = 0.f;
    for (int q = 0; q < 24; ++q){
      const int j = jg*24 + q;
      const float p = att[j*8 + h];
      uint4 v = *(const uint4*)&qkbf[(size_t)(b*N_+j)*512 + ch0];
      const u16* vp = (const u16*)&v;
      #pragma unroll
      for (int e = 0; e < 8; ++e) a8[e] = fmaf(p, bf2f(vp[e]), a8[e]);
    }
    float4 o0 = {a8[0],a8[1],a8[2],a8[3]}, o1 = {a8[4],a8[5],a8[6],a8[7]};
    *(float4*)&part[jg*256 + slot0]     = o0;
    *(float4*)&part[jg*256 + slot0 + 4] = o1;
  }
  __syncthreads();
  {
    float* part = (float*)(smem + L_PART);
    float* red2 = (float*)(smem + L_RED2);
    if (t < 256){
      float s = 0.f;
      #pragma unroll
      for (int g = 0; g < 16; ++g) s += part[g*256 + t];
      red2[t] = s;
    }
  }
  __syncthreads();
  {
    float* part = (float*)(smem + L_PART);
    float* red2 = (float*)(smem + L_RED2);
    const int c = t & 127, qq = t >> 7;
    float s = 0.f;
    #pragma unroll 4
    for (int k = qq*64; k < qq*64 + 64; ++k)
      s = fmaf(red2[k], Wnode[(size_t)k*128 + c], s);
    part[qq*128 + c] = s;
    __syncthreads();
    if (t < 128)
      node_out[(size_t)bi*128 + t] = part[t] + part[128+t] + part[256+t] + part[384+t] + bnode[t];
  }
}

extern "C" void kernel_launch(void* const* d_in, const int* in_sizes, int n_in,
                              void* d_out, int out_size, void* d_ws, size_t ws_size,
                              hipStream_t stream)
{
  const float* x     = (const float*)d_in[0];
  const float* coor  = (const float*)d_in[1];
  const float* eattr = (const float*)d_in[2];
  const float* Wqk   = (const float*)d_in[3];
  const float* bqk   = (const float*)d_in[4];
  const float* We    = (const float*)d_in[5];
  const float* be    = (const float*)d_in[6];
  const float* Wnode = (const float*)d_in[7];
  const float* bnode = (const float*)d_in[8];
  const float* Wedge = (const float*)d_in[9];
  const float* bedge = (const float*)d_in[10];
  const float* Wc1   = (const float*)d_in[11];
  const float* bc1   = (const float*)d_in[12];
  const float* Wc2   = (const float*)d_in[13];
  const float* bc2   = (const float*)d_in[14];
  const int*   emask = (const int*)d_in[15];
  const int*   fmask = (const int*)d_in[16];

  u16* qkbf = (u16*)d_ws;                         // 786432 B

  float* out      = (float*)d_out;
  float* node_out = out;                           // 2*384*128
  float* edge_out = out + 98304;                   // 2*384*384*64
  float* coor_out = out + 98304 + 18874368;        // 2*384*3

  const size_t NEED = 6799360;
  if (ws_size >= NEED){
    u16*   WeF   = (u16*)((char*)d_ws + 786432);   // 65536
    u16*   WgF   = (u16*)((char*)d_ws + 851968);   // 16384
    u16*   W1F   = (u16*)((char*)d_ws + 868352);   // 32768
    u16*   attL  = (u16*)((char*)d_ws + 901120);   // 4718592
    float* cattB = (float*)((char*)d_ws + 5619712);// 1179648

    prep_frag<<<dim3(28), dim3(256), 0, stream>>>(We, Wedge, Wc1, WeF, WgF, W1F);
    qk_kernel<<<dim3(192), dim3(256), 0, stream>>>(x, Wqk, bqk, qkbf);
    k1_logits_ev<<<dim3(6, NB), dim3(256), 0, stream>>>(
        coor, eattr, be, emask, qkbf, WeF, attL, (u16*)edge_out);
    k2_softmax<<<dim3(NB), dim3(512), 0, stream>>>(attL);
    k3_edge_c1<<<dim3(6, NB), dim3(256), 0, stream>>>(
        bedge, bc1, Wc2, qkbf, WgF, W1F, attL, edge_out, cattB);
    k4_node_coor<<<dim3(NB), dim3(256), 0, stream>>>(
        coor, Wnode, bnode, bc2, emask, fmask, qkbf, attL, cattB, node_out, coor_out);
  } else {
    u16* WeT  = (u16*)((char*)d_ws + 786432);
    u16* WgT  = (u16*)((char*)d_ws + 851968);
    u16* Wc1T = (u16*)((char*)d_ws + 868352);
    prep_wt<<<dim3(14), dim3(512), 0, stream>>>(We, Wedge, Wc1, WeT, WgT, Wc1T);
    qk_kernel<<<dim3(192), dim3(256), 0, stream>>>(x, Wqk, bqk, qkbf);
    se3_fused<<<dim3(NB), dim3(512), L_TOTAL, stream>>>(
        coor, eattr, be, bedge, Wnode, bnode, bc1, Wc2, bc2,
        emask, fmask, qkbf, WeT, WgT, Wc1T, node_out, edge_out, coor_out);
  }
}

// Round 6
// 234.880 us; speedup vs baseline: 4.9866x; 1.3401x over previous
//
#include <hip/hip_runtime.h>
#include <stdint.h>
#include <float.h>

#define N_   384
#define NB   768
typedef unsigned short u16;
typedef unsigned int   u32;
typedef __attribute__((ext_vector_type(8))) short short8;   // 8 bf16 (4 VGPRs)
typedef __attribute__((ext_vector_type(4))) float f32x4;    // MFMA accumulator

__device__ __forceinline__ u32 f2bf(float x){
  union{float f; u32 u;} v; v.f = x;
  return (v.u + 0x7fffu + ((v.u >> 16) & 1u)) >> 16;   // RNE bf16
}
__device__ __forceinline__ float bf2f(u16 s){
  union{u32 u; float f;} v; v.u = ((u32)s) << 16; return v.f;
}
__device__ __forceinline__ u32 packbf(float a, float b){
  return f2bf(a) | (f2bf(b) << 16);
}
__device__ __forceinline__ uint4 pack8(const float* f){
  uint4 u;
  u.x = packbf(f[0],f[1]); u.y = packbf(f[2],f[3]);
  u.z = packbf(f[4],f[5]); u.w = packbf(f[6],f[7]);
  return u;
}
__device__ __forceinline__ void unpack8(uint4 u, float* f){
  u32 w[4] = {u.x, u.y, u.z, u.w};
  #pragma unroll
  for (int q = 0; q < 4; ++q){
    union{u32 u; float f;} lo, hi;
    lo.u = w[q] << 16; hi.u = w[q] & 0xffff0000u;
    f[2*q] = lo.f; f[2*q+1] = hi.f;
  }
}
// element index into a [rows][128] bf16 tile, 16B-granule XOR swizzle
__device__ __forceinline__ int swze(int row, int k){
  return row*128 + (((k >> 3) ^ (row & 7)) << 3) + (k & 7);
}

// ---------------- qk = x @ W_qk + b_qk  (bf16 out) ----------------
__global__ __launch_bounds__(256) void qk_kernel(
    const float* __restrict__ x, const float* __restrict__ Wqk,
    const float* __restrict__ bqk, u16* __restrict__ qkbf)
{
  __shared__ float xs[4][128];
  const int r0 = blockIdx.x * 4;
  const int t = threadIdx.x;
  for (int idx = t; idx < 512; idx += 256){
    int r = idx >> 7, k = idx & 127;
    xs[r][k] = x[(size_t)(r0 + r)*128 + k];
  }
  __syncthreads();
  float acc[4][2];
  #pragma unroll
  for (int r = 0; r < 4; ++r){ acc[r][0] = bqk[t]; acc[r][1] = bqk[t + 256]; }
  #pragma unroll 4
  for (int k = 0; k < 128; ++k){
    float w0 = Wqk[(size_t)k*512 + t], w1 = Wqk[(size_t)k*512 + t + 256];
    #pragma unroll
    for (int r = 0; r < 4; ++r){
      acc[r][0] = fmaf(xs[r][k], w0, acc[r][0]);
      acc[r][1] = fmaf(xs[r][k], w1, acc[r][1]);
    }
  }
  #pragma unroll
  for (int r = 0; r < 4; ++r){
    qkbf[(size_t)(r0+r)*512 + t]       = (u16)f2bf(acc[r][0]);
    qkbf[(size_t)(r0+r)*512 + t + 256] = (u16)f2bf(acc[r][1]);
  }
}

// =====================================================================
// ===================== PRIMARY (split) PATH ==========================
// =====================================================================

// fragment-major weight pack: frag (fc,ks): lane l holds W[k=ks*32+(l>>4)*8+e][c=fc*16+(l&15)]
__global__ __launch_bounds__(256) void prep_frag(
    const float* __restrict__ We, const float* __restrict__ Wedge,
    const float* __restrict__ Wc1, u16* __restrict__ WeF,
    u16* __restrict__ WgF, u16* __restrict__ W1F)
{
  const int id = blockIdx.x*256 + threadIdx.x;   // 28 blocks * 256 = 7168 = 112 frags * 64
  const int frag = id >> 6, lane = id & 63;
  if (frag >= 112) return;
  const float* src; u16* dst; int C, fc, ks;
  if (frag < 64){       fc = frag >> 2;      ks = frag & 3; src = We;    C = 256; dst = WeF + (size_t)frag*512; }
  else if (frag < 80){  int fr = frag - 64; fc = fr >> 2;   ks = fr & 3; src = Wedge; C = 64;  dst = WgF + (size_t)fr*512; }
  else {                int fr = frag - 80; fc = fr >> 2;   ks = fr & 3; src = Wc1;   C = 128; dst = W1F + (size_t)fr*512; }
  const int c = fc*16 + (lane & 15);
  const int kb = ks*32 + (lane >> 4)*8;
  float f[8];
  #pragma unroll
  for (int e = 0; e < 8; ++e) f[e] = src[(size_t)(kb + e)*C + c];
  *(uint4*)(dst + lane*8) = pack8(f);
}

// ---------------- K1r: barrier-free e-GEMM -> logits(ws) + e_v(bf16)->edge_out ----------------
// 4 independent waves: (w&1) selects 16-j half of the 32-j block; (w>>1) selects
// channel half (0: e_m->logits, 1: e_v->parked image). A-fragments built in registers.
__global__ __launch_bounds__(256, 4) void k1r_logits_ev(
    const float* __restrict__ coor, const float* __restrict__ edge_attr,
    const float* __restrict__ be, const int* __restrict__ emask,
    const u16* __restrict__ qkbf, const u16* __restrict__ WeF,
    u16* __restrict__ attL, u16* __restrict__ evG)
{
  __shared__ u16 Evp[32*128];   // 8 KB, only e_v waves touch it (own rows only)
  const int t = threadIdx.x;
  const int ch2 = blockIdx.x, bi = blockIdx.y;     // ch2: 0..11 (32-j blocks)
  const int b = (bi >= N_) ? 1 : 0;
  const int w = t >> 6, l = t & 63, lr = l & 15, kg = l >> 4;
  const int half = w >> 1;
  const int jw = ch2*32 + (w & 1)*16;
  const int ja = jw + lr;              // this lane's A-operand row

  // ---- A fragments in registers (layout: lane l -> row l&15, k = (l>>4)*8+e) ----
  short8 afr[4];
  {
    const float* src = &edge_attr[((size_t)bi*N_ + ja)*64 + kg*8];
    #pragma unroll
    for (int ks = 0; ks < 2; ++ks){
      float4 a  = *(const float4*)(src + ks*32);
      float4 c4 = *(const float4*)(src + ks*32 + 4);
      float f[8] = {a.x,a.y,a.z,a.w,c4.x,c4.y,c4.z,c4.w};
      *(uint4*)&afr[ks] = pack8(f);
    }
    const float cix = coor[bi*3], ciy = coor[bi*3+1], ciz = coor[bi*3+2];
    const float dx = cix - coor[(size_t)(b*N_+ja)*3+0];
    const float dy = ciy - coor[(size_t)(b*N_+ja)*3+1];
    const float dz = ciz - coor[(size_t)(b*N_+ja)*3+2];
    const float dm = fminf(sqrtf(dx*dx + dy*dy + dz*dz), 2.0f);
    #pragma unroll
    for (int ks = 2; ks < 4; ++ks){
      const int g0 = (ks-2)*32 + kg*8;
      float f[8];
      #pragma unroll
      for (int e = 0; e < 8; ++e){
        const float dd = dm - (float)(g0+e)*(2.0f/63.0f);
        f[e] = __expf(-496.125f * dd * dd);   // coeff = -0.5/(2/63)^2
      }
      *(uint4*)&afr[ks] = pack8(f);
    }
  }

  // ---- GEMM: 16 j x 128 c (this wave's channel half) ----
  f32x4 acc[8];
  #pragma unroll
  for (int f = 0; f < 8; ++f) acc[f] = (f32x4){0.f,0.f,0.f,0.f};
  #pragma unroll
  for (int ks = 0; ks < 4; ++ks){
    #pragma unroll
    for (int f = 0; f < 8; ++f){
      const int fc = half*8 + f;
      short8 bb = *(const short8*)&WeF[(size_t)((fc*4 + ks)*64 + l)*8];
      acc[f] = __builtin_amdgcn_mfma_f32_16x16x32_bf16(afr[ks], bb, acc[f], 0, 0, 0);
    }
  }

  if (half == 0){
    // logits epilogue: h = f (c = f*16+lr < 128)
    const u16 NEG = (u16)f2bf(-1e30f);
    int mk[4];
    #pragma unroll
    for (int r = 0; r < 4; ++r) mk[r] = emask[(size_t)bi*N_ + jw + kg*4 + r];
    #pragma unroll
    for (int f = 0; f < 8; ++f){
      const int c = f*16 + lr;
      const float lm = bf2f(qkbf[(size_t)bi*512 + c]);
      const float bec = be[c];
      #pragma unroll
      for (int r = 0; r < 4; ++r){
        const int jj = jw + kg*4 + r;
        float e = acc[f][r] + bec; e = e > 0.f ? e : 0.01f*e;
        const float rm = bf2f(qkbf[(size_t)(b*N_+jj)*512 + 128 + c]);
        float s = lm * rm * e;
        s += __shfl_xor(s, 1); s += __shfl_xor(s, 2);
        s += __shfl_xor(s, 4); s += __shfl_xor(s, 8);
        if (lr == 0)
          attL[(size_t)bi*3072 + jj*8 + f] = mk[r] ? (u16)f2bf(s*0.25f) : NEG;
      }
    }
  } else {
    // e_v pack epilogue -> own 16 rows of Evp (swizzled), then park to global
    #pragma unroll
    for (int f = 0; f < 8; ++f){
      const int cv = f*16 + lr;
      const float bec = be[128 + cv];
      #pragma unroll
      for (int r = 0; r < 4; ++r){
        float e = acc[f][r] + bec; e = e > 0.f ? e : 0.01f*e;
        const float pr = __shfl_xor(e, 1);
        if (!(lr & 1)){
          const int jl = (w & 1)*16 + kg*4 + r;
          *(u32*)&Evp[jl*128 + (((cv>>3) ^ (jl&7))<<3) + (cv&7)] = packbf(e, pr);
        }
      }
    }
    // copy own 16 rows (4 KB) into the (bi, ch2>>1) parked image slice
    uint4* dst = (uint4*)evG + ((size_t)bi*6 + (ch2>>1))*1024 + (ch2&1)*512 + (w&1)*256;
    const uint4* E4 = (const uint4*)Evp;
    #pragma unroll
    for (int q = 0; q < 4; ++q) dst[l + q*64] = E4[(w&1)*256 + l + q*64];
  }
}

// ---------------- K2: softmax over j, probs bf16 in place ----------------
__global__ __launch_bounds__(512) void k2_softmax(u16* __restrict__ attL)
{
  __shared__ u16 sl[3072];
  const int t = threadIdx.x, bi = blockIdx.x;
  uint4* sl4 = (uint4*)sl;
  if (t < 384) sl4[t] = ((const uint4*)(attL + (size_t)bi*3072))[t];
  __syncthreads();
  const int h = t >> 6, lane = t & 63;
  float v[6]; float m = -FLT_MAX;
  #pragma unroll
  for (int q = 0; q < 6; ++q){ v[q] = bf2f(sl[(lane + q*64)*8 + h]); m = fmaxf(m, v[q]); }
  #pragma unroll
  for (int o = 32; o >= 1; o >>= 1) m = fmaxf(m, __shfl_xor(m, o));
  float s = 0.f;
  #pragma unroll
  for (int q = 0; q < 6; ++q){ v[q] = __expf(v[q] - m); s += v[q]; }
  #pragma unroll
  for (int o = 32; o >= 1; o >>= 1) s += __shfl_xor(s, o);
  const float inv = 1.f / s;
  #pragma unroll
  for (int q = 0; q < 6; ++q) sl[(lane + q*64)*8 + h] = (u16)f2bf(v[q] * inv);
  __syncthreads();
  if (t < 384) ((uint4*)(attL + (size_t)bi*3072))[t] = sl4[t];
}

// ---------------- K3: barrier-free edge GEMM + c1 GEMM per (bi, 64-j chunk) ----------------
// A-fragments read DIRECTLY from the parked global image (swizzled row-major);
// each wave reads/writes only its own 16 rows -> no LDS, no barriers.
__global__ __launch_bounds__(256, 4) void k3_edge_c1(
    const float* __restrict__ bedge, const float* __restrict__ bc1,
    const float* __restrict__ Wc2, const u16* __restrict__ qkbf,
    const u16* __restrict__ WgF, const u16* __restrict__ W1F,
    const u16* __restrict__ attL, float* __restrict__ edge_out,
    float* __restrict__ cattB)
{
  const int t = threadIdx.x, ch = blockIdx.x, bi = blockIdx.y;
  const int b = (bi >= N_) ? 1 : 0;
  const int j0 = ch * 64;
  const int w = t >> 6, l = t & 63, lr = l & 15, kg = l >> 4;
  const int jsb = w * 16;
  const int jloc = jsb + lr;
  const int jglob = j0 + jloc;
  const u16* evS = (const u16*)edge_out + ((size_t)bi*6 + ch)*8192;

  f32x4 eacc[4], cacc[8];
  #pragma unroll
  for (int f = 0; f < 4; ++f) eacc[f] = (f32x4){0.f,0.f,0.f,0.f};
  #pragma unroll
  for (int f = 0; f < 8; ++f) cacc[f] = (f32x4){0.f,0.f,0.f,0.f};

  #pragma unroll
  for (int ks = 0; ks < 4; ++ks){
    const int k0 = ks*32 + kg*8;
    short8 ar = *(const short8*)&evS[swze(jloc, k0)];
    const float p = bf2f(attL[(size_t)bi*3072 + jglob*8 + (k0 >> 4)]);
    uint4 rvu = *(const uint4*)&qkbf[(size_t)(b*N_ + jglob)*512 + 384 + k0];
    uint4 lvu = *(const uint4*)&qkbf[(size_t)bi*512 + 256 + k0];
    short8 ame, amc;
    const u16* arp = (const u16*)&ar;
    const u16* rvp = (const u16*)&rvu;
    const u16* lvp = (const u16*)&lvu;
    u16* amep = (u16*)&ame; u16* amcp = (u16*)&amc;
    #pragma unroll
    for (int e = 0; e < 8; ++e){
      const float ef = bf2f(arp[e]) * p;
      amep[e] = (u16)f2bf(ef);
      amcp[e] = (u16)f2bf(ef * bf2f(lvp[e]) * bf2f(rvp[e]));
    }
    #pragma unroll
    for (int f = 0; f < 4; ++f){
      short8 bb = *(const short8*)&WgF[(size_t)((f*4 + ks)*64 + l)*8];
      eacc[f] = __builtin_amdgcn_mfma_f32_16x16x32_bf16(ame, bb, eacc[f], 0, 0, 0);
    }
    #pragma unroll
    for (int f = 0; f < 8; ++f){
      short8 bb = *(const short8*)&W1F[(size_t)((f*4 + ks)*64 + l)*8];
      cacc[f] = __builtin_amdgcn_mfma_f32_16x16x32_bf16(amc, bb, cacc[f], 0, 0, 0);
    }
  }
  // edge epilogue (wave overwrites only its own just-consumed rows)
  #pragma unroll
  for (int f = 0; f < 4; ++f){
    const int g = f*16 + lr;
    const float bg = bedge[g];
    #pragma unroll
    for (int r = 0; r < 4; ++r){
      const int j = j0 + jsb + kg*4 + r;
      edge_out[((size_t)bi*N_ + j)*64 + g] = eacc[f][r] + bg;
    }
  }
  // c1 epilogue: full 128-ch sum within wave -> catt[j]
  {
    float sr[4] = {0.f,0.f,0.f,0.f};
    #pragma unroll
    for (int f = 0; f < 8; ++f){
      const int c = f*16 + lr;
      const float b1 = bc1[c], w2 = Wc2[c];
      #pragma unroll
      for (int r = 0; r < 4; ++r){
        float y = cacc[f][r] + b1; y = y > 0.f ? y : 0.01f*y;
        sr[r] += y * w2;
      }
    }
    #pragma unroll
    for (int r = 0; r < 4; ++r){
      float s = sr[r];
      s += __shfl_xor(s, 1); s += __shfl_xor(s, 2);
      s += __shfl_xor(s, 4); s += __shfl_xor(s, 8);
      if (lr == 0) cattB[(size_t)bi*N_ + j0 + jsb + kg*4 + r] = s;
    }
  }
}

// ---------------- K4: node einsum + W_node + coor finale ----------------
__global__ __launch_bounds__(256) void k4_node_coor(
    const float* __restrict__ coor, const float* __restrict__ Wnode,
    const float* __restrict__ bnode, const float* __restrict__ bc2,
    const int* __restrict__ emask, const int* __restrict__ fmask,
    const u16* __restrict__ qkbf, const u16* __restrict__ attL,
    const float* __restrict__ cattB, float* __restrict__ node_out,
    float* __restrict__ coor_out)
{
  __shared__ u16 pS[3072];
  __shared__ float red[256];
  __shared__ float halfb[256];
  __shared__ float cred[16];
  const int t = threadIdx.x, bi = blockIdx.x;
  const int b = (bi >= N_) ? 1 : 0;
  for (int idx = t; idx < 384; idx += 256)
    ((uint4*)pS)[idx] = ((const uint4*)(attL + (size_t)bi*3072))[idx];
  __syncthreads();
  // node pre: thread t = c2
  {
    const int h = t >> 5, d2 = t & 31;
    const int chan = 256 + (d2 < 16 ? h*16 + d2 : 128 + h*16 + (d2 - 16));
    float a0=0.f, a1=0.f, a2=0.f, a3=0.f;
    for (int j = 0; j < N_; j += 4){
      a0 = fmaf(bf2f(pS[(j  )*8 + h]), bf2f(qkbf[(size_t)(b*N_+j  )*512 + chan]), a0);
      a1 = fmaf(bf2f(pS[(j+1)*8 + h]), bf2f(qkbf[(size_t)(b*N_+j+1)*512 + chan]), a1);
      a2 = fmaf(bf2f(pS[(j+2)*8 + h]), bf2f(qkbf[(size_t)(b*N_+j+2)*512 + chan]), a2);
      a3 = fmaf(bf2f(pS[(j+3)*8 + h]), bf2f(qkbf[(size_t)(b*N_+j+3)*512 + chan]), a3);
    }
    red[t] = (a0+a1)+(a2+a3);
  }
  __syncthreads();
  {
    const int c = t & 127, qq = t >> 7;
    float s = 0.f;
    #pragma unroll 4
    for (int k = qq*128; k < qq*128 + 128; ++k)
      s = fmaf(red[k], Wnode[(size_t)k*128 + c], s);
    halfb[t] = s;
  }
  __syncthreads();
  if (t < 128)
    node_out[(size_t)bi*128 + t] = halfb[t] + halfb[128 + t] + bnode[t];

  // coor
  {
    const float cix = coor[bi*3], ciy = coor[bi*3+1], ciz = coor[bi*3+2];
    float vx=0.f, vy=0.f, vz=0.f, cnt=0.f;
    for (int j = t; j < N_; j += 256){
      if (emask[(size_t)bi*N_ + j]){
        cnt += 1.f;
        const float val = cattB[(size_t)bi*N_ + j] + bc2[0];
        const float dx = cix - coor[(size_t)(b*N_+j)*3+0];
        const float dy = ciy - coor[(size_t)(b*N_+j)*3+1];
        const float dz = ciz - coor[(size_t)(b*N_+j)*3+2];
        const float nrm = sqrtf(dx*dx + dy*dy + dz*dz);
        if (nrm > 0.f){
          const float q = val / fmaxf(nrm, 1e-8f);
          vx += q*dx; vy += q*dy; vz += q*dz;
        }
      }
    }
    #pragma unroll
    for (int o = 32; o >= 1; o >>= 1){
      vx += __shfl_xor(vx, o); vy += __shfl_xor(vy, o);
      vz += __shfl_xor(vz, o); cnt += __shfl_xor(cnt, o);
    }
    const int w = t >> 6, l = t & 63;
    if (l == 0){ cred[w*4]=vx; cred[w*4+1]=vy; cred[w*4+2]=vz; cred[w*4+3]=cnt; }
  }
  __syncthreads();
  if (t == 0){
    float sx=0.f, sy=0.f, sz=0.f, sc=0.f;
    #pragma unroll
    for (int ww = 0; ww < 4; ++ww){
      sx += cred[ww*4]; sy += cred[ww*4+1]; sz += cred[ww*4+2]; sc += cred[ww*4+3];
    }
    const float d = sc + 1e-7f, fm = (float)fmask[bi];
    coor_out[bi*3+0] = sx/d*fm;
    coor_out[bi*3+1] = sy/d*fm;
    coor_out[bi*3+2] = sz/d*fm;
  }
}

// =====================================================================
// ================= FALLBACK (R3 monolithic) PATH =====================
// =====================================================================

__global__ __launch_bounds__(512) void prep_wt(
    const float* __restrict__ We, const float* __restrict__ Wedge,
    const float* __restrict__ Wc1, u16* __restrict__ WeT,
    u16* __restrict__ WgT, u16* __restrict__ Wc1T)
{
  const int id = blockIdx.x*512 + threadIdx.x;
  const float* src; u16* dst; int c, g, stride;
  if (id < 4096){        int q = id;      c = q>>4; g = q&15; src = We    + (size_t)g*8*256 + c; stride = 256; dst = WeT  + c*128 + ((g ^ (c&7))<<3); }
  else if (id < 5120){   int q = id-4096; c = q>>4; g = q&15; src = Wedge + (size_t)g*8*64  + c; stride = 64;  dst = WgT  + c*128 + ((g ^ (c&7))<<3); }
  else if (id < 7168){   int q = id-5120; c = q>>4; g = q&15; src = Wc1   + (size_t)g*8*128 + c; stride = 128; dst = Wc1T + c*128 + ((g ^ (c&7))<<3); }
  else return;
  float f[8];
  #pragma unroll
  for (int e = 0; e < 8; ++e) f[e] = src[(size_t)e*stride];
  *(uint4*)dst = pack8(f);
}

#define L_ATT   0
#define L_AS    12288
#define L_WE    45056
#define L_WG    45056
#define L_W1    61440
#define L_PART  94208
#define L_EVP   110592
#define L_CATT  110592
#define L_RED2  113664
#define L_MISC  126976
#define L_QIF   127488
#define L_TOTAL 129536

__global__ __launch_bounds__(512, 1) void se3_fused(
    const float* __restrict__ coor, const float* __restrict__ edge_attr,
    const float* __restrict__ be, const float* __restrict__ bedge,
    const float* __restrict__ Wnode, const float* __restrict__ bnode,
    const float* __restrict__ bc1, const float* __restrict__ Wc2,
    const float* __restrict__ bc2, const int* __restrict__ emask,
    const int* __restrict__ fmask, const u16* __restrict__ qkbf,
    const u16* __restrict__ WeTg, const u16* __restrict__ WgTg,
    const u16* __restrict__ Wc1Tg,
    float* __restrict__ node_out, float* __restrict__ edge_out, float* __restrict__ coor_out)
{
  extern __shared__ char smem[];
  float* att  = (float*)(smem + L_ATT);
  float* qif  = (float*)(smem + L_QIF);
  float* misc = (float*)(smem + L_MISC);

  const int t  = threadIdx.x;
  const int bi = blockIdx.x;
  const int b  = (bi >= N_) ? 1 : 0;
  const float cix = coor[bi*3], ciy = coor[bi*3+1], ciz = coor[bi*3+2];

  const int w  = t >> 6, l = t & 63;
  const int chh = w >> 2, jsb = (w & 3) * 16;
  const int lr = l & 15, kg = l >> 4;

  for (int idx = t; idx < 4096; idx += 512)
    ((uint4*)(smem + L_WE))[idx] = ((const uint4*)WeTg)[idx];
  qif[t] = bf2f(qkbf[(size_t)bi*512 + t]);
  __syncthreads();

  float bevf[8], lmvf[8];
  #pragma unroll
  for (int f = 0; f < 8; ++f){
    const int c = chh*128 + f*16 + lr;
    bevf[f] = be[c];
    lmvf[f] = (chh == 0) ? qif[c] : 0.f;
  }

  float4 pa0, pb0, pa1, pb1;
  const int gq = t & 15, rq = t >> 4;
  auto issue_ea = [&](int j0){
    if (gq < 8){
      const float* s0 = &edge_attr[((size_t)bi*N_ + j0 + rq)*64 + gq*8];
      const float* s1 = &edge_attr[((size_t)bi*N_ + j0 + rq + 32)*64 + gq*8];
      pa0 = *(const float4*)s0; pb0 = *(const float4*)(s0 + 4);
      pa1 = *(const float4*)s1; pb1 = *(const float4*)(s1 + 4);
    }
  };

  uint4* evg = (uint4*)(edge_out + (size_t)bi*24576);

  issue_ea(0);
  for (int ch = 0; ch < 6; ++ch){
    const int j0 = ch * 64;
    {
      u16* As = (u16*)(smem + L_AS + (ch & 1)*16384);
      #pragma unroll
      for (int q = 0; q < 2; ++q){
        const int row = rq + q*32;
        const int j = j0 + row;
        float f[8];
        if (gq < 8){
          float4 A = q ? pa1 : pa0, Bv = q ? pb1 : pb0;
          f[0]=A.x; f[1]=A.y; f[2]=A.z; f[3]=A.w;
          f[4]=Bv.x; f[5]=Bv.y; f[6]=Bv.z; f[7]=Bv.w;
        } else {
          const float dx = cix - coor[(size_t)(b*N_+j)*3+0];
          const float dy = ciy - coor[(size_t)(b*N_+j)*3+1];
          const float dz = ciz - coor[(size_t)(b*N_+j)*3+2];
          const float dm = fminf(sqrtf(dx*dx + dy*dy + dz*dz), 2.0f);
          const int k0 = (gq - 8)*8;
          #pragma unroll
          for (int e = 0; e < 8; ++e){
            const float dd = dm - (float)(k0+e)*(2.0f/63.0f);
            f[e] = __expf(-496.125f * dd * dd);
          }
        }
        ((uint4*)As)[row*16 + (gq ^ (row & 7))] = pack8(f);
      }
    }
    __syncthreads();
    if (ch + 1 < 6) issue_ea((ch+1)*64);

    f32x4 acc[8];
    #pragma unroll
    for (int f = 0; f < 8; ++f) acc[f] = (f32x4){0.f,0.f,0.f,0.f};
    {
      u16* As  = (u16*)(smem + L_AS + (ch & 1)*16384);
      u16* WeL = (u16*)(smem + L_WE);
      #pragma unroll
      for (int ks = 0; ks < 4; ++ks){
        const int k0 = ks*32 + kg*8;
        short8 a = *(const short8*)&As[swze(jsb + lr, k0)];
        #pragma unroll
        for (int f = 0; f < 8; ++f){
          const int c = chh*128 + f*16 + lr;
          short8 bb = *(const short8*)&WeL[swze(c, k0)];
          acc[f] = __builtin_amdgcn_mfma_f32_16x16x32_bf16(a, bb, acc[f], 0, 0, 0);
        }
      }
    }
    if (chh == 0){
      #pragma unroll
      for (int f = 0; f < 8; ++f){
        #pragma unroll
        for (int r = 0; r < 4; ++r){
          const int j = j0 + jsb + kg*4 + r;
          float e = acc[f][r] + bevf[f]; e = e > 0.f ? e : 0.01f*e;
          const float rm = bf2f(qkbf[(size_t)(b*N_+j)*512 + 128 + f*16 + lr]);
          float s = lmvf[f] * rm * e;
          s += __shfl_xor(s, 1); s += __shfl_xor(s, 2);
          s += __shfl_xor(s, 4); s += __shfl_xor(s, 8);
          if (lr == 0)
            att[j*8 + f] = emask[(size_t)bi*N_ + j] ? s*0.25f : -FLT_MAX;
        }
      }
    } else {
      u16* Evp = (u16*)(smem + L_EVP);
      #pragma unroll
      for (int f = 0; f < 8; ++f){
        #pragma unroll
        for (int r = 0; r < 4; ++r){
          float e = acc[f][r] + bevf[f]; e = e > 0.f ? e : 0.01f*e;
          const float pr = __shfl_xor(e, 1);
          if (!(lr & 1)){
            const int jl = jsb + kg*4 + r;
            const int cv = f*16 + lr;
            *(u32*)&Evp[jl*128 + (((cv>>3) ^ (jl&7))<<3) + (cv&7)] = packbf(e, pr);
          }
        }
      }
    }
    __syncthreads();
    {
      const uint4* Evp4 = (const uint4*)(smem + L_EVP);
      #pragma unroll
      for (int q = 0; q < 2; ++q)
        evg[ch*1024 + t + q*512] = Evp4[t + q*512];
    }
  }

  {
    const int h = w, lane = l;
    float m = -FLT_MAX;
    #pragma unroll
    for (int q = 0; q < 6; ++q) m = fmaxf(m, att[(lane + q*64)*8 + h]);
    #pragma unroll
    for (int o = 32; o >= 1; o >>= 1) m = fmaxf(m, __shfl_xor(m, o));
    float pv[6], s = 0.f;
    #pragma unroll
    for (int q = 0; q < 6; ++q){ float p = __expf(att[(lane + q*64)*8 + h] - m); pv[q] = p; s += p; }
    #pragma unroll
    for (int o = 32; o >= 1; o >>= 1) s += __shfl_xor(s, o);
    const float inv = 1.f / s;
    #pragma unroll
    for (int q = 0; q < 6; ++q) att[(lane + q*64)*8 + h] = pv[q] * inv;
  }

  for (int idx = t; idx < 1024; idx += 512)
    ((uint4*)(smem + L_WG))[idx] = ((const uint4*)WgTg)[idx];
  for (int idx = t; idx < 2048; idx += 512){
    const int c = idx >> 4, g = idx & 15;
    uint4 u = ((const uint4*)Wc1Tg)[idx];
    const int k0 = ((g ^ (c & 7)) << 3);
    float f[8]; unpack8(u, f);
    #pragma unroll
    for (int e = 0; e < 8; ++e) f[e] *= qif[256 + k0 + e];
    ((uint4*)(smem + L_W1))[idx] = pack8(f);
  }

  float bgv[2], bc1v[4], w2v[4];
  #pragma unroll
  for (int f = 0; f < 2; ++f) bgv[f] = bedge[chh*32 + f*16 + lr];
  #pragma unroll
  for (int f = 0; f < 4; ++f){
    const int c2 = chh*64 + f*16 + lr;
    bc1v[f] = bc1[c2]; w2v[f] = Wc2[c2];
  }

  uint4 eva, evb;
  auto issue_ev = [&](int ch){
    eva = evg[ch*1024 + t];
    evb = evg[ch*1024 + t + 512];
  };
  issue_ev(0);
  __syncthreads();

  float* catt = (float*)(smem + L_CATT);

  for (int ch = 0; ch < 6; ++ch){
    const int j0 = ch * 64;
    {
      uint4* Ev4 = (uint4*)(smem + L_AS + (ch & 1)*16384);
      Ev4[t] = eva; Ev4[t + 512] = evb;
    }
    if (ch + 1 < 6) issue_ev(ch + 1);
    __syncthreads();

    u16* Ev  = (u16*)(smem + L_AS + (ch & 1)*16384);
    u16* WgL = (u16*)(smem + L_WG);
    u16* W1L = (u16*)(smem + L_W1);
    const int jrow = j0 + jsb + lr;

    f32x4 eacc[2], cacc[4];
    eacc[0] = (f32x4){0.f,0.f,0.f,0.f}; eacc[1] = (f32x4){0.f,0.f,0.f,0.f};
    #pragma unroll
    for (int f = 0; f < 4; ++f) cacc[f] = (f32x4){0.f,0.f,0.f,0.f};

    #pragma unroll
    for (int ks = 0; ks < 4; ++ks){
      const int k0 = ks*32 + kg*8;
      short8 ar = *(const short8*)&Ev[swze(jsb + lr, k0)];
      const float p = att[jrow*8 + (k0 >> 4)];
      uint4 rvu = *(const uint4*)&qkbf[(size_t)(b*N_+jrow)*512 + 384 + k0];
      short8 ame, amc;
      const u16* arp = (const u16*)&ar; const u16* rvp = (const u16*)&rvu;
      u16* amep = (u16*)&ame; u16* amcp = (u16*)&amc;
      #pragma unroll
      for (int e = 0; e < 8; ++e){
        const float ef = bf2f(arp[e]) * p;
        amep[e] = (u16)f2bf(ef);
        amcp[e] = (u16)f2bf(ef * bf2f(rvp[e]));
      }
      #pragma unroll
      for (int f = 0; f < 2; ++f){
        short8 bb = *(const short8*)&WgL[swze(chh*32 + f*16 + lr, k0)];
        eacc[f] = __builtin_amdgcn_mfma_f32_16x16x32_bf16(ame, bb, eacc[f], 0, 0, 0);
      }
      #pragma unroll
      for (int f = 0; f < 4; ++f){
        short8 bb = *(const short8*)&W1L[swze(chh*64 + f*16 + lr, k0)];
        cacc[f] = __builtin_amdgcn_mfma_f32_16x16x32_bf16(amc, bb, cacc[f], 0, 0, 0);
      }
    }
    #pragma unroll
    for (int f = 0; f < 2; ++f){
      const int g = chh*32 + f*16 + lr;
      #pragma unroll
      for (int r = 0; r < 4; ++r){
        const int j = j0 + jsb + kg*4 + r;
        edge_out[((size_t)bi*N_ + j)*64 + g] = eacc[f][r] + bgv[f];
      }
    }
    {
      float sr[4] = {0.f,0.f,0.f,0.f};
      #pragma unroll
      for (int f = 0; f < 4; ++f){
        #pragma unroll
        for (int r = 0; r < 4; ++r){
          float y = cacc[f][r] + bc1v[f]; y = y > 0.f ? y : 0.01f*y;
          sr[r] += y * w2v[f];
        }
      }
      #pragma unroll
      for (int r = 0; r < 4; ++r){
        float s = sr[r];
        s += __shfl_xor(s, 1); s += __shfl_xor(s, 2);
        s += __shfl_xor(s, 4); s += __shfl_xor(s, 8);
        if (lr == 0) catt[chh*N_ + j0 + jsb + kg*4 + r] = s;
      }
    }
  }
  __syncthreads();

  {
    float vx = 0.f, vy = 0.f, vz = 0.f, cnt = 0.f;
    if (t < N_){
      const int j = t;
      const int mk = emask[(size_t)bi*N_ + j];
      cnt = (mk != 0) ? 1.f : 0.f;
      if (mk){
        const float val = catt[j] + catt[N_ + j] + bc2[0];
        const float dx = cix - coor[(size_t)(b*N_+j)*3+0];
        const float dy = ciy - coor[(size_t)(b*N_+j)*3+1];
        const float dz = ciz - coor[(size_t)(b*N_+j)*3+2];
        const float nrm = sqrtf(dx*dx + dy*dy + dz*dz);
        if (nrm > 0.f){
          const float qq = val / fmaxf(nrm, 1e-8f);
          vx = qq*dx; vy = qq*dy; vz = qq*dz;
        }
      }
    }
    #pragma unroll
    for (int o = 32; o >= 1; o >>= 1){
      vx += __shfl_xor(vx, o); vy += __shfl_xor(vy, o);
      vz += __shfl_xor(vz, o); cnt += __shfl_xor(cnt, o);
    }
    if (l == 0){
      float* wr = misc + 16 + w*4;
      wr[0] = vx; wr[1] = vy; wr[2] = vz; wr[3] = cnt;
    }
  }
  __syncthreads();
  if (t == 0){
    float sx=0.f, sy=0.f, sz=0.f, sc=0.f;
    #pragma unroll
    for (int ww = 0; ww < 8; ++ww){
      sx += misc[16+ww*4]; sy += misc[16+ww*4+1];
      sz += misc[16+ww*4+2]; sc += misc[16+ww*4+3];
    }
    const float d = sc + 1e-7f, fm = (float)fmask[bi];
    coor_out[bi*3+0] = sx/d*fm; coor_out[bi*3+1] = sy/d*fm; coor_out[bi*3+2] = sz/d*fm;
  }

  {
    float* part = (float*)(smem + L_PART);
    const int c8 = t & 31, jg = t >> 5;
    const int ch0 = 256 + c8*8;
    const int h = (c8 < 16) ? (c8 >> 1) : ((c8 - 16) >> 1);
    const int slot0 = (c8 < 16) ? (h*32 + (c8 & 1)*8) : (h*32 + 16 + (c8 & 1)*8);
    float a8[8];
    #pragma unroll
    for (int e = 0; e < 8; ++e) a8[e] = 0.f;
    for (int q = 0; q < 24; ++q){
      const int j = jg*24 + q;
      const float p = att[j*8 + h];
      uint4 v = *(const uint4*)&qkbf[(size_t)(b*N_+j)*512 + ch0];
      const u16* vp = (const u16*)&v;
      #pragma unroll
      for (int e = 0; e < 8; ++e) a8[e] = fmaf(p, bf2f(vp[e]), a8[e]);
    }
    float4 o0 = {a8[0],a8[1],a8[2],a8[3]}, o1 = {a8[4],a8[5],a8[6],a8[7]};
    *(float4*)&part[jg*256 + slot0]     = o0;
    *(float4*)&part[jg*256 + slot0 + 4] = o1;
  }
  __syncthreads();
  {
    float* part = (float*)(smem + L_PART);
    float* red2 = (float*)(smem + L_RED2);
    if (t < 256){
      float s = 0.f;
      #pragma unroll
      for (int g = 0; g < 16; ++g) s += part[g*256 + t];
      red2[t] = s;
    }
  }
  __syncthreads();
  {
    float* part = (float*)(smem + L_PART);
    float* red2 = (float*)(smem + L_RED2);
    const int c = t & 127, qq = t >> 7;
    float s = 0.f;
    #pragma unroll 4
    for (int k = qq*64; k < qq*64 + 64; ++k)
      s = fmaf(red2[k], Wnode[(size_t)k*128 + c], s);
    part[qq*128 + c] = s;
    __syncthreads();
    if (t < 128)
      node_out[(size_t)bi*128 + t] = part[t] + part[128+t] + part[256+t] + part[384+t] + bnode[t];
  }
}

extern "C" void kernel_launch(void* const* d_in, const int* in_sizes, int n_in,
                              void* d_out, int out_size, void* d_ws, size_t ws_size,
                              hipStream_t stream)
{
  const float* x     = (const float*)d_in[0];
  const float* coor  = (const float*)d_in[1];
  const float* eattr = (const float*)d_in[2];
  const float* Wqk   = (const float*)d_in[3];
  const float* bqk   = (const float*)d_in[4];
  const float* We    = (const float*)d_in[5];
  const float* be    = (const float*)d_in[6];
  const float* Wnode = (const float*)d_in[7];
  const float* bnode = (const float*)d_in[8];
  const float* Wedge = (const float*)d_in[9];
  const float* bedge = (const float*)d_in[10];
  const float* Wc1   = (const float*)d_in[11];
  const float* bc1   = (const float*)d_in[12];
  const float* Wc2   = (const float*)d_in[13];
  const float* bc2   = (const float*)d_in[14];
  const int*   emask = (const int*)d_in[15];
  const int*   fmask = (const int*)d_in[16];

  u16* qkbf = (u16*)d_ws;                         // 786432 B

  float* out      = (float*)d_out;
  float* node_out = out;                           // 2*384*128
  float* edge_out = out + 98304;                   // 2*384*384*64
  float* coor_out = out + 98304 + 18874368;        // 2*384*3

  const size_t NEED = 6799360;
  if (ws_size >= NEED){
    u16*   WeF   = (u16*)((char*)d_ws + 786432);   // 65536
    u16*   WgF   = (u16*)((char*)d_ws + 851968);   // 16384
    u16*   W1F   = (u16*)((char*)d_ws + 868352);   // 32768
    u16*   attL  = (u16*)((char*)d_ws + 901120);   // 4718592
    float* cattB = (float*)((char*)d_ws + 5619712);// 1179648

    prep_frag<<<dim3(28), dim3(256), 0, stream>>>(We, Wedge, Wc1, WeF, WgF, W1F);
    qk_kernel<<<dim3(192), dim3(256), 0, stream>>>(x, Wqk, bqk, qkbf);
    k1r_logits_ev<<<dim3(12, NB), dim3(256), 0, stream>>>(
        coor, eattr, be, emask, qkbf, WeF, attL, (u16*)edge_out);
    k2_softmax<<<dim3(NB), dim3(512), 0, stream>>>(attL);
    k3_edge_c1<<<dim3(6, NB), dim3(256), 0, stream>>>(
        bedge, bc1, Wc2, qkbf, WgF, W1F, attL, edge_out, cattB);
    k4_node_coor<<<dim3(NB), dim3(256), 0, stream>>>(
        coor, Wnode, bnode, bc2, emask, fmask, qkbf, attL, cattB, node_out, coor_out);
  } else {
    u16* WeT  = (u16*)((char*)d_ws + 786432);
    u16* WgT  = (u16*)((char*)d_ws + 851968);
    u16* Wc1T = (u16*)((char*)d_ws + 868352);
    prep_wt<<<dim3(14), dim3(512), 0, stream>>>(We, Wedge, Wc1, WeT, WgT, Wc1T);
    qk_kernel<<<dim3(192), dim3(256), 0, stream>>>(x, Wqk, bqk, qkbf);
    se3_fused<<<dim3(NB), dim3(512), L_TOTAL, stream>>>(
        coor, eattr, be, bedge, Wnode, bnode, bc1, Wc2, bc2,
        emask, fmask, qkbf, WeT, WgT, Wc1T, node_out, edge_out, coor_out);
  }
}

// Round 7
// 208.624 us; speedup vs baseline: 5.6141x; 1.1259x over previous
//
#include <hip/hip_runtime.h>
#include <stdint.h>
#include <float.h>

#define N_   384
#define NB   768
typedef unsigned short u16;
typedef unsigned int   u32;
typedef __attribute__((ext_vector_type(8))) short short8;   // 8 bf16 (4 VGPRs)
typedef __attribute__((ext_vector_type(4))) float f32x4;    // MFMA accumulator

__device__ __forceinline__ u32 f2bf(float x){
  union{float f; u32 u;} v; v.f = x;
  return (v.u + 0x7fffu + ((v.u >> 16) & 1u)) >> 16;   // RNE bf16
}
__device__ __forceinline__ float bf2f(u16 s){
  union{u32 u; float f;} v; v.u = ((u32)s) << 16; return v.f;
}
__device__ __forceinline__ u32 packbf(float a, float b){
  return f2bf(a) | (f2bf(b) << 16);
}
__device__ __forceinline__ uint4 pack8(const float* f){
  uint4 u;
  u.x = packbf(f[0],f[1]); u.y = packbf(f[2],f[3]);
  u.z = packbf(f[4],f[5]); u.w = packbf(f[6],f[7]);
  return u;
}
__device__ __forceinline__ void unpack8(uint4 u, float* f){
  u32 w[4] = {u.x, u.y, u.z, u.w};
  #pragma unroll
  for (int q = 0; q < 4; ++q){
    union{u32 u; float f;} lo, hi;
    lo.u = w[q] << 16; hi.u = w[q] & 0xffff0000u;
    f[2*q] = lo.f; f[2*q+1] = hi.f;
  }
}
// element index into a [rows][128] bf16 tile, 16B-granule XOR swizzle
__device__ __forceinline__ int swze(int row, int k){
  return row*128 + (((k >> 3) ^ (row & 7)) << 3) + (k & 7);
}

// ---------------- qk = x @ W_qk + b_qk  (bf16 out) ----------------
__global__ __launch_bounds__(256) void qk_kernel(
    const float* __restrict__ x, const float* __restrict__ Wqk,
    const float* __restrict__ bqk, u16* __restrict__ qkbf)
{
  __shared__ float xs[4][128];
  const int r0 = blockIdx.x * 4;
  const int t = threadIdx.x;
  for (int idx = t; idx < 512; idx += 256){
    int r = idx >> 7, k = idx & 127;
    xs[r][k] = x[(size_t)(r0 + r)*128 + k];
  }
  __syncthreads();
  float acc[4][2];
  #pragma unroll
  for (int r = 0; r < 4; ++r){ acc[r][0] = bqk[t]; acc[r][1] = bqk[t + 256]; }
  #pragma unroll 4
  for (int k = 0; k < 128; ++k){
    float w0 = Wqk[(size_t)k*512 + t], w1 = Wqk[(size_t)k*512 + t + 256];
    #pragma unroll
    for (int r = 0; r < 4; ++r){
      acc[r][0] = fmaf(xs[r][k], w0, acc[r][0]);
      acc[r][1] = fmaf(xs[r][k], w1, acc[r][1]);
    }
  }
  #pragma unroll
  for (int r = 0; r < 4; ++r){
    qkbf[(size_t)(r0+r)*512 + t]       = (u16)f2bf(acc[r][0]);
    qkbf[(size_t)(r0+r)*512 + t + 256] = (u16)f2bf(acc[r][1]);
  }
}

// =====================================================================
// ===================== PRIMARY (split) PATH ==========================
// =====================================================================

// fragment-major weight pack: frag (fc,ks): lane l holds W[k=ks*32+(l>>4)*8+e][c=fc*16+(l&15)]
__global__ __launch_bounds__(256) void prep_frag(
    const float* __restrict__ We, const float* __restrict__ Wedge,
    const float* __restrict__ Wc1, u16* __restrict__ WeF,
    u16* __restrict__ WgF, u16* __restrict__ W1F)
{
  const int id = blockIdx.x*256 + threadIdx.x;   // 28 blocks * 256 = 7168 = 112 frags * 64
  const int frag = id >> 6, lane = id & 63;
  if (frag >= 112) return;
  const float* src; u16* dst; int C, fc, ks;
  if (frag < 64){       fc = frag >> 2;      ks = frag & 3; src = We;    C = 256; dst = WeF + (size_t)frag*512; }
  else if (frag < 80){  int fr = frag - 64; fc = fr >> 2;   ks = fr & 3; src = Wedge; C = 64;  dst = WgF + (size_t)fr*512; }
  else {                int fr = frag - 80; fc = fr >> 2;   ks = fr & 3; src = Wc1;   C = 128; dst = W1F + (size_t)fr*512; }
  const int c = fc*16 + (lane & 15);
  const int kb = ks*32 + (lane >> 4)*8;
  float f[8];
  #pragma unroll
  for (int e = 0; e < 8; ++e) f[e] = src[(size_t)(kb + e)*C + c];
  *(uint4*)(dst + lane*8) = pack8(f);
}

// ---------------- K1s: barrier-free, SWAPPED-operand e-GEMM ----------------
// mfma(W_frag, edge_frag, acc) -> D[c, j]: lane holds j = l&15 (fixed),
// c = frag*16 + (l>>4)*4 + reg. Logits: per-head lane-local sum + 2 shfl.
// e_v: zero-shfl uint2 pack into swizzled LDS granule.
__global__ __launch_bounds__(256, 4) void k1s_logits_ev(
    const float* __restrict__ coor, const float* __restrict__ edge_attr,
    const float* __restrict__ be, const int* __restrict__ emask,
    const u16* __restrict__ qkbf, const u16* __restrict__ WeF,
    u16* __restrict__ attL, u16* __restrict__ evG)
{
  __shared__ u16 Evp[32*128];   // 8 KB, only e_v waves touch it (own rows only)
  const int t = threadIdx.x;
  const int ch2 = blockIdx.x, bi = blockIdx.y;     // ch2: 0..11 (32-j blocks)
  const int b = (bi >= N_) ? 1 : 0;
  const int w = t >> 6, l = t & 63, lr = l & 15, kg = l >> 4;
  const int half = w >> 1;
  const int jw = ch2*32 + (w & 1)*16;
  const int ja = jw + lr;              // this lane's j (B-operand row AND output col)

  // ---- edge fragments in registers (lane: 16-idx = j = l&15, k = kg*8+e) ----
  short8 afr[4];
  {
    const float* src = &edge_attr[((size_t)bi*N_ + ja)*64 + kg*8];
    #pragma unroll
    for (int ks = 0; ks < 2; ++ks){
      float4 a  = *(const float4*)(src + ks*32);
      float4 c4 = *(const float4*)(src + ks*32 + 4);
      float f[8] = {a.x,a.y,a.z,a.w,c4.x,c4.y,c4.z,c4.w};
      *(uint4*)&afr[ks] = pack8(f);
    }
    const float cix = coor[bi*3], ciy = coor[bi*3+1], ciz = coor[bi*3+2];
    const float dx = cix - coor[(size_t)(b*N_+ja)*3+0];
    const float dy = ciy - coor[(size_t)(b*N_+ja)*3+1];
    const float dz = ciz - coor[(size_t)(b*N_+ja)*3+2];
    const float dm = fminf(sqrtf(dx*dx + dy*dy + dz*dz), 2.0f);
    #pragma unroll
    for (int ks = 2; ks < 4; ++ks){
      const int g0 = (ks-2)*32 + kg*8;
      float f[8];
      #pragma unroll
      for (int e = 0; e < 8; ++e){
        const float dd = dm - (float)(g0+e)*(2.0f/63.0f);
        f[e] = __expf(-496.125f * dd * dd);   // coeff = -0.5/(2/63)^2
      }
      *(uint4*)&afr[ks] = pack8(f);
    }
  }

  // ---- swapped GEMM: D[c, j] ----
  f32x4 acc[8];
  #pragma unroll
  for (int f = 0; f < 8; ++f) acc[f] = (f32x4){0.f,0.f,0.f,0.f};
  #pragma unroll
  for (int ks = 0; ks < 4; ++ks){
    #pragma unroll
    for (int mf = 0; mf < 8; ++mf){
      const int fc = half*8 + mf;
      short8 wv = *(const short8*)&WeF[(size_t)((fc*4 + ks)*64 + l)*8];
      acc[mf] = __builtin_amdgcn_mfma_f32_16x16x32_bf16(wv, afr[ks], acc[mf], 0, 0, 0);
    }
  }

  if (half == 0){
    // logits: head h = mf; per lane 4 c's (c = mf*16 + kg*4 + r), j = ja fixed
    const int mk = emask[(size_t)bi*N_ + ja];
    float s8[8];
    #pragma unroll
    for (int mf = 0; mf < 8; ++mf){
      const int c = mf*16 + kg*4;
      uint2 lmu = *(const uint2*)&qkbf[(size_t)bi*512 + c];
      uint2 rmu = *(const uint2*)&qkbf[(size_t)(b*N_+ja)*512 + 128 + c];
      float4 bev = *(const float4*)&be[c];
      const u16* lmp = (const u16*)&lmu; const u16* rmp = (const u16*)&rmu;
      float s = 0.f;
      #pragma unroll
      for (int r = 0; r < 4; ++r){
        float e = acc[mf][r] + (&bev.x)[r]; e = e > 0.f ? e : 0.01f*e;
        s += e * bf2f(lmp[r]) * bf2f(rmp[r]);
      }
      s += __shfl_xor(s, 16); s += __shfl_xor(s, 32);
      s8[mf] = s * 0.25f;
    }
    if (kg == 0){
      const u32 NEG2 = packbf(-1e30f, -1e30f);
      uint4 o;
      o.x = mk ? packbf(s8[0], s8[1]) : NEG2;
      o.y = mk ? packbf(s8[2], s8[3]) : NEG2;
      o.z = mk ? packbf(s8[4], s8[5]) : NEG2;
      o.w = mk ? packbf(s8[6], s8[7]) : NEG2;
      *(uint4*)&attL[(size_t)bi*3072 + ja*8] = o;
    }
  } else {
    // e_v: pack 4 consecutive c per frag straight into swizzled LDS (no shfl)
    const int jl = (w & 1)*16 + lr;
    #pragma unroll
    for (int mf = 0; mf < 8; ++mf){
      const int c = mf*16 + kg*4;            // c within [0,128) of the e_v half
      float4 bev = *(const float4*)&be[128 + c];
      float e[4];
      #pragma unroll
      for (int r = 0; r < 4; ++r){
        float y = acc[mf][r] + (&bev.x)[r]; e[r] = y > 0.f ? y : 0.01f*y;
      }
      uint2 pk; pk.x = packbf(e[0], e[1]); pk.y = packbf(e[2], e[3]);
      const int g = c >> 3;
      *(uint2*)&Evp[jl*128 + ((g ^ (jl & 7)) << 3) + (kg & 1)*4] = pk;
    }
    // copy own 16 rows (4 KB) into the (bi, ch2>>1) parked image slice
    uint4* dst = (uint4*)evG + ((size_t)bi*6 + (ch2>>1))*1024 + (ch2&1)*512 + (w&1)*256;
    const uint4* E4 = (const uint4*)Evp;
    #pragma unroll
    for (int q = 0; q < 4; ++q) dst[l + q*64] = E4[(w&1)*256 + l + q*64];
  }
}

// ---------------- K2: softmax over j, probs bf16 in place ----------------
__global__ __launch_bounds__(512) void k2_softmax(u16* __restrict__ attL)
{
  __shared__ u16 sl[3072];
  const int t = threadIdx.x, bi = blockIdx.x;
  uint4* sl4 = (uint4*)sl;
  if (t < 384) sl4[t] = ((const uint4*)(attL + (size_t)bi*3072))[t];
  __syncthreads();
  const int h = t >> 6, lane = t & 63;
  float v[6]; float m = -FLT_MAX;
  #pragma unroll
  for (int q = 0; q < 6; ++q){ v[q] = bf2f(sl[(lane + q*64)*8 + h]); m = fmaxf(m, v[q]); }
  #pragma unroll
  for (int o = 32; o >= 1; o >>= 1) m = fmaxf(m, __shfl_xor(m, o));
  float s = 0.f;
  #pragma unroll
  for (int q = 0; q < 6; ++q){ v[q] = __expf(v[q] - m); s += v[q]; }
  #pragma unroll
  for (int o = 32; o >= 1; o >>= 1) s += __shfl_xor(s, o);
  const float inv = 1.f / s;
  #pragma unroll
  for (int q = 0; q < 6; ++q) sl[(lane + q*64)*8 + h] = (u16)f2bf(v[q] * inv);
  __syncthreads();
  if (t < 384) ((uint4*)(attL + (size_t)bi*3072))[t] = sl4[t];
}

// ---------------- K3s: barrier-free SWAPPED edge GEMM + c1 GEMM ----------------
__global__ __launch_bounds__(256, 4) void k3s_edge_c1(
    const float* __restrict__ bedge, const float* __restrict__ bc1,
    const float* __restrict__ Wc2, const u16* __restrict__ qkbf,
    const u16* __restrict__ WgF, const u16* __restrict__ W1F,
    const u16* __restrict__ attL, float* __restrict__ edge_out,
    float* __restrict__ cattB)
{
  const int t = threadIdx.x, ch = blockIdx.x, bi = blockIdx.y;
  const int b = (bi >= N_) ? 1 : 0;
  const int j0 = ch * 64;
  const int w = t >> 6, l = t & 63, lr = l & 15, kg = l >> 4;
  const int jloc = w*16 + lr;
  const int jglob = j0 + jloc;
  const u16* evS = (const u16*)edge_out + ((size_t)bi*6 + ch)*8192;

  f32x4 eacc[4], cacc[8];
  #pragma unroll
  for (int f = 0; f < 4; ++f) eacc[f] = (f32x4){0.f,0.f,0.f,0.f};
  #pragma unroll
  for (int f = 0; f < 8; ++f) cacc[f] = (f32x4){0.f,0.f,0.f,0.f};

  #pragma unroll
  for (int ks = 0; ks < 4; ++ks){
    const int k0 = ks*32 + kg*8;
    short8 ar = *(const short8*)&evS[swze(jloc, k0)];
    const float p = bf2f(attL[(size_t)bi*3072 + jglob*8 + (k0 >> 4)]);
    uint4 rvu = *(const uint4*)&qkbf[(size_t)(b*N_ + jglob)*512 + 384 + k0];
    uint4 lvu = *(const uint4*)&qkbf[(size_t)bi*512 + 256 + k0];
    short8 ame, amc;
    const u16* arp = (const u16*)&ar;
    const u16* rvp = (const u16*)&rvu;
    const u16* lvp = (const u16*)&lvu;
    u16* amep = (u16*)&ame; u16* amcp = (u16*)&amc;
    #pragma unroll
    for (int e = 0; e < 8; ++e){
      const float ef = bf2f(arp[e]) * p;
      amep[e] = (u16)f2bf(ef);
      amcp[e] = (u16)f2bf(ef * bf2f(lvp[e]) * bf2f(rvp[e]));
    }
    #pragma unroll
    for (int f = 0; f < 4; ++f){
      short8 wv = *(const short8*)&WgF[(size_t)((f*4 + ks)*64 + l)*8];
      eacc[f] = __builtin_amdgcn_mfma_f32_16x16x32_bf16(wv, ame, eacc[f], 0, 0, 0);
    }
    #pragma unroll
    for (int f = 0; f < 8; ++f){
      short8 wv = *(const short8*)&W1F[(size_t)((f*4 + ks)*64 + l)*8];
      cacc[f] = __builtin_amdgcn_mfma_f32_16x16x32_bf16(wv, amc, cacc[f], 0, 0, 0);
    }
  }
  // edge epilogue: D[g, j] -> lane j fixed, g = gf*16 + kg*4 + r -> float4 stores
  #pragma unroll
  for (int gf = 0; gf < 4; ++gf){
    const int g0 = gf*16 + kg*4;
    float4 bg = *(const float4*)&bedge[g0];
    float4 o;
    o.x = eacc[gf][0] + bg.x; o.y = eacc[gf][1] + bg.y;
    o.z = eacc[gf][2] + bg.z; o.w = eacc[gf][3] + bg.w;
    *(float4*)&edge_out[((size_t)bi*N_ + jglob)*64 + g0] = o;
  }
  // c1 epilogue: lane-local 32 terms + 2 shfl
  {
    float s = 0.f;
    #pragma unroll
    for (int cf = 0; cf < 8; ++cf){
      const int c0 = cf*16 + kg*4;
      float4 b1 = *(const float4*)&bc1[c0];
      float4 w2 = *(const float4*)&Wc2[c0];
      #pragma unroll
      for (int r = 0; r < 4; ++r){
        float y = cacc[cf][r] + (&b1.x)[r]; y = y > 0.f ? y : 0.01f*y;
        s += y * (&w2.x)[r];
      }
    }
    s += __shfl_xor(s, 16); s += __shfl_xor(s, 32);
    if (kg == 0) cattB[(size_t)bi*N_ + jglob] = s;
  }
}

// ---------------- K4: node einsum (vectorized) + W_node + coor finale ----------------
__global__ __launch_bounds__(256) void k4_node_coor(
    const float* __restrict__ coor, const float* __restrict__ Wnode,
    const float* __restrict__ bnode, const float* __restrict__ bc2,
    const int* __restrict__ emask, const int* __restrict__ fmask,
    const u16* __restrict__ qkbf, const u16* __restrict__ attL,
    const float* __restrict__ cattB, float* __restrict__ node_out,
    float* __restrict__ coor_out)
{
  __shared__ u16 pS[3072];
  __shared__ float part[8][256];
  __shared__ float red[256];
  __shared__ float halfb[256];
  __shared__ float cred[16];
  const int t = threadIdx.x, bi = blockIdx.x;
  const int b = (bi >= N_) ? 1 : 0;
  for (int idx = t; idx < 384; idx += 256)
    ((uint4*)pS)[idx] = ((const uint4*)(attL + (size_t)bi*3072))[idx];
  __syncthreads();
  // node pre: 32 chan-groups (uint4) x 8 j-groups of 48 j
  {
    const int q = t & 31, jg = t >> 5;
    const int ch0 = 256 + q*8;
    const int h = (q < 16) ? (q >> 1) : ((q - 16) >> 1);
    const int slot0 = (q < 16) ? (h*32 + (q & 1)*8) : (h*32 + 16 + (q & 1)*8);
    float a8[8];
    #pragma unroll
    for (int e = 0; e < 8; ++e) a8[e] = 0.f;
    for (int j = jg*48; j < jg*48 + 48; ++j){
      const float p = bf2f(pS[j*8 + h]);
      uint4 v = *(const uint4*)&qkbf[(size_t)(b*N_+j)*512 + ch0];
      const u16* vp = (const u16*)&v;
      #pragma unroll
      for (int e = 0; e < 8; ++e) a8[e] = fmaf(p, bf2f(vp[e]), a8[e]);
    }
    float4 o0 = {a8[0],a8[1],a8[2],a8[3]}, o1 = {a8[4],a8[5],a8[6],a8[7]};
    *(float4*)&part[jg][slot0]     = o0;
    *(float4*)&part[jg][slot0 + 4] = o1;
  }
  __syncthreads();
  {
    float s = 0.f;
    #pragma unroll
    for (int g = 0; g < 8; ++g) s += part[g][t];
    red[t] = s;
  }
  __syncthreads();
  {
    const int c = t & 127, qq = t >> 7;
    float s = 0.f;
    #pragma unroll 4
    for (int k = qq*128; k < qq*128 + 128; ++k)
      s = fmaf(red[k], Wnode[(size_t)k*128 + c], s);
    halfb[t] = s;
  }
  __syncthreads();
  if (t < 128)
    node_out[(size_t)bi*128 + t] = halfb[t] + halfb[128 + t] + bnode[t];

  // coor
  {
    const float cix = coor[bi*3], ciy = coor[bi*3+1], ciz = coor[bi*3+2];
    float vx=0.f, vy=0.f, vz=0.f, cnt=0.f;
    for (int j = t; j < N_; j += 256){
      if (emask[(size_t)bi*N_ + j]){
        cnt += 1.f;
        const float val = cattB[(size_t)bi*N_ + j] + bc2[0];
        const float dx = cix - coor[(size_t)(b*N_+j)*3+0];
        const float dy = ciy - coor[(size_t)(b*N_+j)*3+1];
        const float dz = ciz - coor[(size_t)(b*N_+j)*3+2];
        const float nrm = sqrtf(dx*dx + dy*dy + dz*dz);
        if (nrm > 0.f){
          const float qv = val / fmaxf(nrm, 1e-8f);
          vx += qv*dx; vy += qv*dy; vz += qv*dz;
        }
      }
    }
    #pragma unroll
    for (int o = 32; o >= 1; o >>= 1){
      vx += __shfl_xor(vx, o); vy += __shfl_xor(vy, o);
      vz += __shfl_xor(vz, o); cnt += __shfl_xor(cnt, o);
    }
    const int w = t >> 6, l = t & 63;
    if (l == 0){ cred[w*4]=vx; cred[w*4+1]=vy; cred[w*4+2]=vz; cred[w*4+3]=cnt; }
  }
  __syncthreads();
  if (t == 0){
    float sx=0.f, sy=0.f, sz=0.f, sc=0.f;
    #pragma unroll
    for (int ww = 0; ww < 4; ++ww){
      sx += cred[ww*4]; sy += cred[ww*4+1]; sz += cred[ww*4+2]; sc += cred[ww*4+3];
    }
    const float d = sc + 1e-7f, fm = (float)fmask[bi];
    coor_out[bi*3+0] = sx/d*fm;
    coor_out[bi*3+1] = sy/d*fm;
    coor_out[bi*3+2] = sz/d*fm;
  }
}

// =====================================================================
// ================= FALLBACK (R3 monolithic) PATH =====================
// =====================================================================

__global__ __launch_bounds__(512) void prep_wt(
    const float* __restrict__ We, const float* __restrict__ Wedge,
    const float* __restrict__ Wc1, u16* __restrict__ WeT,
    u16* __restrict__ WgT, u16* __restrict__ Wc1T)
{
  const int id = blockIdx.x*512 + threadIdx.x;
  const float* src; u16* dst; int c, g, stride;
  if (id < 4096){        int q = id;      c = q>>4; g = q&15; src = We    + (size_t)g*8*256 + c; stride = 256; dst = WeT  + c*128 + ((g ^ (c&7))<<3); }
  else if (id < 5120){   int q = id-4096; c = q>>4; g = q&15; src = Wedge + (size_t)g*8*64  + c; stride = 64;  dst = WgT  + c*128 + ((g ^ (c&7))<<3); }
  else if (id < 7168){   int q = id-5120; c = q>>4; g = q&15; src = Wc1   + (size_t)g*8*128 + c; stride = 128; dst = Wc1T + c*128 + ((g ^ (c&7))<<3); }
  else return;
  float f[8];
  #pragma unroll
  for (int e = 0; e < 8; ++e) f[e] = src[(size_t)e*stride];
  *(uint4*)dst = pack8(f);
}

#define L_ATT   0
#define L_AS    12288
#define L_WE    45056
#define L_WG    45056
#define L_W1    61440
#define L_PART  94208
#define L_EVP   110592
#define L_CATT  110592
#define L_RED2  113664
#define L_MISC  126976
#define L_QIF   127488
#define L_TOTAL 129536

__global__ __launch_bounds__(512, 1) void se3_fused(
    const float* __restrict__ coor, const float* __restrict__ edge_attr,
    const float* __restrict__ be, const float* __restrict__ bedge,
    const float* __restrict__ Wnode, const float* __restrict__ bnode,
    const float* __restrict__ bc1, const float* __restrict__ Wc2,
    const float* __restrict__ bc2, const int* __restrict__ emask,
    const int* __restrict__ fmask, const u16* __restrict__ qkbf,
    const u16* __restrict__ WeTg, const u16* __restrict__ WgTg,
    const u16* __restrict__ Wc1Tg,
    float* __restrict__ node_out, float* __restrict__ edge_out, float* __restrict__ coor_out)
{
  extern __shared__ char smem[];
  float* att  = (float*)(smem + L_ATT);
  float* qif  = (float*)(smem + L_QIF);
  float* misc = (float*)(smem + L_MISC);

  const int t  = threadIdx.x;
  const int bi = blockIdx.x;
  const int b  = (bi >= N_) ? 1 : 0;
  const float cix = coor[bi*3], ciy = coor[bi*3+1], ciz = coor[bi*3+2];

  const int w  = t >> 6, l = t & 63;
  const int chh = w >> 2, jsb = (w & 3) * 16;
  const int lr = l & 15, kg = l >> 4;

  for (int idx = t; idx < 4096; idx += 512)
    ((uint4*)(smem + L_WE))[idx] = ((const uint4*)WeTg)[idx];
  qif[t] = bf2f(qkbf[(size_t)bi*512 + t]);
  __syncthreads();

  float bevf[8], lmvf[8];
  #pragma unroll
  for (int f = 0; f < 8; ++f){
    const int c = chh*128 + f*16 + lr;
    bevf[f] = be[c];
    lmvf[f] = (chh == 0) ? qif[c] : 0.f;
  }

  float4 pa0, pb0, pa1, pb1;
  const int gq = t & 15, rq = t >> 4;
  auto issue_ea = [&](int j0){
    if (gq < 8){
      const float* s0 = &edge_attr[((size_t)bi*N_ + j0 + rq)*64 + gq*8];
      const float* s1 = &edge_attr[((size_t)bi*N_ + j0 + rq + 32)*64 + gq*8];
      pa0 = *(const float4*)s0; pb0 = *(const float4*)(s0 + 4);
      pa1 = *(const float4*)s1; pb1 = *(const float4*)(s1 + 4);
    }
  };

  uint4* evg = (uint4*)(edge_out + (size_t)bi*24576);

  issue_ea(0);
  for (int ch = 0; ch < 6; ++ch){
    const int j0 = ch * 64;
    {
      u16* As = (u16*)(smem + L_AS + (ch & 1)*16384);
      #pragma unroll
      for (int q = 0; q < 2; ++q){
        const int row = rq + q*32;
        const int j = j0 + row;
        float f[8];
        if (gq < 8){
          float4 A = q ? pa1 : pa0, Bv = q ? pb1 : pb0;
          f[0]=A.x; f[1]=A.y; f[2]=A.z; f[3]=A.w;
          f[4]=Bv.x; f[5]=Bv.y; f[6]=Bv.z; f[7]=Bv.w;
        } else {
          const float dx = cix - coor[(size_t)(b*N_+j)*3+0];
          const float dy = ciy - coor[(size_t)(b*N_+j)*3+1];
          const float dz = ciz - coor[(size_t)(b*N_+j)*3+2];
          const float dm = fminf(sqrtf(dx*dx + dy*dy + dz*dz), 2.0f);
          const int k0 = (gq - 8)*8;
          #pragma unroll
          for (int e = 0; e < 8; ++e){
            const float dd = dm - (float)(k0+e)*(2.0f/63.0f);
            f[e] = __expf(-496.125f * dd * dd);
          }
        }
        ((uint4*)As)[row*16 + (gq ^ (row & 7))] = pack8(f);
      }
    }
    __syncthreads();
    if (ch + 1 < 6) issue_ea((ch+1)*64);

    f32x4 acc[8];
    #pragma unroll
    for (int f = 0; f < 8; ++f) acc[f] = (f32x4){0.f,0.f,0.f,0.f};
    {
      u16* As  = (u16*)(smem + L_AS + (ch & 1)*16384);
      u16* WeL = (u16*)(smem + L_WE);
      #pragma unroll
      for (int ks = 0; ks < 4; ++ks){
        const int k0 = ks*32 + kg*8;
        short8 a = *(const short8*)&As[swze(jsb + lr, k0)];
        #pragma unroll
        for (int f = 0; f < 8; ++f){
          const int c = chh*128 + f*16 + lr;
          short8 bb = *(const short8*)&WeL[swze(c, k0)];
          acc[f] = __builtin_amdgcn_mfma_f32_16x16x32_bf16(a, bb, acc[f], 0, 0, 0);
        }
      }
    }
    if (chh == 0){
      #pragma unroll
      for (int f = 0; f < 8; ++f){
        #pragma unroll
        for (int r = 0; r < 4; ++r){
          const int j = j0 + jsb + kg*4 + r;
          float e = acc[f][r] + bevf[f]; e = e > 0.f ? e : 0.01f*e;
          const float rm = bf2f(qkbf[(size_t)(b*N_+j)*512 + 128 + f*16 + lr]);
          float s = lmvf[f] * rm * e;
          s += __shfl_xor(s, 1); s += __shfl_xor(s, 2);
          s += __shfl_xor(s, 4); s += __shfl_xor(s, 8);
          if (lr == 0)
            att[j*8 + f] = emask[(size_t)bi*N_ + j] ? s*0.25f : -FLT_MAX;
        }
      }
    } else {
      u16* Evp = (u16*)(smem + L_EVP);
      #pragma unroll
      for (int f = 0; f < 8; ++f){
        #pragma unroll
        for (int r = 0; r < 4; ++r){
          float e = acc[f][r] + bevf[f]; e = e > 0.f ? e : 0.01f*e;
          const float pr = __shfl_xor(e, 1);
          if (!(lr & 1)){
            const int jl = jsb + kg*4 + r;
            const int cv = f*16 + lr;
            *(u32*)&Evp[jl*128 + (((cv>>3) ^ (jl&7))<<3) + (cv&7)] = packbf(e, pr);
          }
        }
      }
    }
    __syncthreads();
    {
      const uint4* Evp4 = (const uint4*)(smem + L_EVP);
      #pragma unroll
      for (int q = 0; q < 2; ++q)
        evg[ch*1024 + t + q*512] = Evp4[t + q*512];
    }
  }

  {
    const int h = w, lane = l;
    float m = -FLT_MAX;
    #pragma unroll
    for (int q = 0; q < 6; ++q) m = fmaxf(m, att[(lane + q*64)*8 + h]);
    #pragma unroll
    for (int o = 32; o >= 1; o >>= 1) m = fmaxf(m, __shfl_xor(m, o));
    float pv[6], s = 0.f;
    #pragma unroll
    for (int q = 0; q < 6; ++q){ float p = __expf(att[(lane + q*64)*8 + h] - m); pv[q] = p; s += p; }
    #pragma unroll
    for (int o = 32; o >= 1; o >>= 1) s += __shfl_xor(s, o);
    const float inv = 1.f / s;
    #pragma unroll
    for (int q = 0; q < 6; ++q) att[(lane + q*64)*8 + h] = pv[q] * inv;
  }

  for (int idx = t; idx < 1024; idx += 512)
    ((uint4*)(smem + L_WG))[idx] = ((const uint4*)WgTg)[idx];
  for (int idx = t; idx < 2048; idx += 512){
    const int c = idx >> 4, g = idx & 15;
    uint4 u = ((const uint4*)Wc1Tg)[idx];
    const int k0 = ((g ^ (c & 7)) << 3);
    float f[8]; unpack8(u, f);
    #pragma unroll
    for (int e = 0; e < 8; ++e) f[e] *= qif[256 + k0 + e];
    ((uint4*)(smem + L_W1))[idx] = pack8(f);
  }

  float bgv[2], bc1v[4], w2v[4];
  #pragma unroll
  for (int f = 0; f < 2; ++f) bgv[f] = bedge[chh*32 + f*16 + lr];
  #pragma unroll
  for (int f = 0; f < 4; ++f){
    const int c2 = chh*64 + f*16 + lr;
    bc1v[f] = bc1[c2]; w2v[f] = Wc2[c2];
  }

  uint4 eva, evb;
  auto issue_ev = [&](int ch){
    eva = evg[ch*1024 + t];
    evb = evg[ch*1024 + t + 512];
  };
  issue_ev(0);
  __syncthreads();

  float* catt = (float*)(smem + L_CATT);

  for (int ch = 0; ch < 6; ++ch){
    const int j0 = ch * 64;
    {
      uint4* Ev4 = (uint4*)(smem + L_AS + (ch & 1)*16384);
      Ev4[t] = eva; Ev4[t + 512] = evb;
    }
    if (ch + 1 < 6) issue_ev(ch + 1);
    __syncthreads();

    u16* Ev  = (u16*)(smem + L_AS + (ch & 1)*16384);
    u16* WgL = (u16*)(smem + L_WG);
    u16* W1L = (u16*)(smem + L_W1);
    const int jrow = j0 + jsb + lr;

    f32x4 eacc[2], cacc[4];
    eacc[0] = (f32x4){0.f,0.f,0.f,0.f}; eacc[1] = (f32x4){0.f,0.f,0.f,0.f};
    #pragma unroll
    for (int f = 0; f < 4; ++f) cacc[f] = (f32x4){0.f,0.f,0.f,0.f};

    #pragma unroll
    for (int ks = 0; ks < 4; ++ks){
      const int k0 = ks*32 + kg*8;
      short8 ar = *(const short8*)&Ev[swze(jsb + lr, k0)];
      const float p = att[jrow*8 + (k0 >> 4)];
      uint4 rvu = *(const uint4*)&qkbf[(size_t)(b*N_+jrow)*512 + 384 + k0];
      short8 ame, amc;
      const u16* arp = (const u16*)&ar; const u16* rvp = (const u16*)&rvu;
      u16* amep = (u16*)&ame; u16* amcp = (u16*)&amc;
      #pragma unroll
      for (int e = 0; e < 8; ++e){
        const float ef = bf2f(arp[e]) * p;
        amep[e] = (u16)f2bf(ef);
        amcp[e] = (u16)f2bf(ef * bf2f(rvp[e]));
      }
      #pragma unroll
      for (int f = 0; f < 2; ++f){
        short8 bb = *(const short8*)&WgL[swze(chh*32 + f*16 + lr, k0)];
        eacc[f] = __builtin_amdgcn_mfma_f32_16x16x32_bf16(ame, bb, eacc[f], 0, 0, 0);
      }
      #pragma unroll
      for (int f = 0; f < 4; ++f){
        short8 bb = *(const short8*)&W1L[swze(chh*64 + f*16 + lr, k0)];
        cacc[f] = __builtin_amdgcn_mfma_f32_16x16x32_bf16(amc, bb, cacc[f], 0, 0, 0);
      }
    }
    #pragma unroll
    for (int f = 0; f < 2; ++f){
      const int g = chh*32 + f*16 + lr;
      #pragma unroll
      for (int r = 0; r < 4; ++r){
        const int j = j0 + jsb + kg*4 + r;
        edge_out[((size_t)bi*N_ + j)*64 + g] = eacc[f][r] + bgv[f];
      }
    }
    {
      float sr[4] = {0.f,0.f,0.f,0.f};
      #pragma unroll
      for (int f = 0; f < 4; ++f){
        #pragma unroll
        for (int r = 0; r < 4; ++r){
          float y = cacc[f][r] + bc1v[f]; y = y > 0.f ? y : 0.01f*y;
          sr[r] += y * w2v[f];
        }
      }
      #pragma unroll
      for (int r = 0; r < 4; ++r){
        float s = sr[r];
        s += __shfl_xor(s, 1); s += __shfl_xor(s, 2);
        s += __shfl_xor(s, 4); s += __shfl_xor(s, 8);
        if (lr == 0) catt[chh*N_ + j0 + jsb + kg*4 + r] = s;
      }
    }
  }
  __syncthreads();

  {
    float vx = 0.f, vy = 0.f, vz = 0.f, cnt = 0.f;
    if (t < N_){
      const int j = t;
      const int mk = emask[(size_t)bi*N_ + j];
      cnt = (mk != 0) ? 1.f : 0.f;
      if (mk){
        const float val = catt[j] + catt[N_ + j] + bc2[0];
        const float dx = cix - coor[(size_t)(b*N_+j)*3+0];
        const float dy = ciy - coor[(size_t)(b*N_+j)*3+1];
        const float dz = ciz - coor[(size_t)(b*N_+j)*3+2];
        const float nrm = sqrtf(dx*dx + dy*dy + dz*dz);
        if (nrm > 0.f){
          const float qq = val / fmaxf(nrm, 1e-8f);
          vx = qq*dx; vy = qq*dy; vz = qq*dz;
        }
      }
    }
    #pragma unroll
    for (int o = 32; o >= 1; o >>= 1){
      vx += __shfl_xor(vx, o); vy += __shfl_xor(vy, o);
      vz += __shfl_xor(vz, o); cnt += __shfl_xor(cnt, o);
    }
    if (l == 0){
      float* wr = misc + 16 + w*4;
      wr[0] = vx; wr[1] = vy; wr[2] = vz; wr[3] = cnt;
    }
  }
  __syncthreads();
  if (t == 0){
    float sx=0.f, sy=0.f, sz=0.f, sc=0.f;
    #pragma unroll
    for (int ww = 0; ww < 8; ++ww){
      sx += misc[16+ww*4]; sy += misc[16+ww*4+1];
      sz += misc[16+ww*4+2]; sc += misc[16+ww*4+3];
    }
    const float d = sc + 1e-7f, fm = (float)fmask[bi];
    coor_out[bi*3+0] = sx/d*fm; coor_out[bi*3+1] = sy/d*fm; coor_out[bi*3+2] = sz/d*fm;
  }

  {
    float* part = (float*)(smem + L_PART);
    const int c8 = t & 31, jg = t >> 5;
    const int ch0 = 256 + c8*8;
    const int h = (c8 < 16) ? (c8 >> 1) : ((c8 - 16) >> 1);
    const int slot0 = (c8 < 16) ? (h*32 + (c8 & 1)*8) : (h*32 + 16 + (c8 & 1)*8);
    float a8[8];
    #pragma unroll
    for (int e = 0; e < 8; ++e) a8[e] = 0.f;
    for (int q = 0; q < 24; ++q){
      const int j = jg*24 + q;
      const float p = att[j*8 + h];
      uint4 v = *(const uint4*)&qkbf[(size_t)(b*N_+j)*512 + ch0];
      const u16* vp = (const u16*)&v;
      #pragma unroll
      for (int e = 0; e < 8; ++e) a8[e] = fmaf(p, bf2f(vp[e]), a8[e]);
    }
    float4 o0 = {a8[0],a8[1],a8[2],a8[3]}, o1 = {a8[4],a8[5],a8[6],a8[7]};
    *(float4*)&part[jg*256 + slot0]     = o0;
    *(float4*)&part[jg*256 + slot0 + 4] = o1;
  }
  __syncthreads();
  {
    float* part = (float*)(smem + L_PART);
    float* red2 = (float*)(smem + L_RED2);
    if (t < 256){
      float s = 0.f;
      #pragma unroll
      for (int g = 0; g < 16; ++g) s += part[g*256 + t];
      red2[t] = s;
    }
  }
  __syncthreads();
  {
    float* part = (float*)(smem + L_PART);
    float* red2 = (float*)(smem + L_RED2);
    const int c = t & 127, qq = t >> 7;
    float s = 0.f;
    #pragma unroll 4
    for (int k = qq*64; k < qq*64 + 64; ++k)
      s = fmaf(red2[k], Wnode[(size_t)k*128 + c], s);
    part[qq*128 + c] = s;
    __syncthreads();
    if (t < 128)
      node_out[(size_t)bi*128 + t] = part[t] + part[128+t] + part[256+t] + part[384+t] + bnode[t];
  }
}

extern "C" void kernel_launch(void* const* d_in, const int* in_sizes, int n_in,
                              void* d_out, int out_size, void* d_ws, size_t ws_size,
                              hipStream_t stream)
{
  const float* x     = (const float*)d_in[0];
  const float* coor  = (const float*)d_in[1];
  const float* eattr = (const float*)d_in[2];
  const float* Wqk   = (const float*)d_in[3];
  const float* bqk   = (const float*)d_in[4];
  const float* We    = (const float*)d_in[5];
  const float* be    = (const float*)d_in[6];
  const float* Wnode = (const float*)d_in[7];
  const float* bnode = (const float*)d_in[8];
  const float* Wedge = (const float*)d_in[9];
  const float* bedge = (const float*)d_in[10];
  const float* Wc1   = (const float*)d_in[11];
  const float* bc1   = (const float*)d_in[12];
  const float* Wc2   = (const float*)d_in[13];
  const float* bc2   = (const float*)d_in[14];
  const int*   emask = (const int*)d_in[15];
  const int*   fmask = (const int*)d_in[16];

  u16* qkbf = (u16*)d_ws;                         // 786432 B

  float* out      = (float*)d_out;
  float* node_out = out;                           // 2*384*128
  float* edge_out = out + 98304;                   // 2*384*384*64
  float* coor_out = out + 98304 + 18874368;        // 2*384*3

  const size_t NEED = 6799360;
  if (ws_size >= NEED){
    u16*   WeF   = (u16*)((char*)d_ws + 786432);   // 65536
    u16*   WgF   = (u16*)((char*)d_ws + 851968);   // 16384
    u16*   W1F   = (u16*)((char*)d_ws + 868352);   // 32768
    u16*   attL  = (u16*)((char*)d_ws + 901120);   // 4718592
    float* cattB = (float*)((char*)d_ws + 5619712);// 1179648

    prep_frag<<<dim3(28), dim3(256), 0, stream>>>(We, Wedge, Wc1, WeF, WgF, W1F);
    qk_kernel<<<dim3(192), dim3(256), 0, stream>>>(x, Wqk, bqk, qkbf);
    k1s_logits_ev<<<dim3(12, NB), dim3(256), 0, stream>>>(
        coor, eattr, be, emask, qkbf, WeF, attL, (u16*)edge_out);
    k2_softmax<<<dim3(NB), dim3(512), 0, stream>>>(attL);
    k3s_edge_c1<<<dim3(6, NB), dim3(256), 0, stream>>>(
        bedge, bc1, Wc2, qkbf, WgF, W1F, attL, edge_out, cattB);
    k4_node_coor<<<dim3(NB), dim3(256), 0, stream>>>(
        coor, Wnode, bnode, bc2, emask, fmask, qkbf, attL, cattB, node_out, coor_out);
  } else {
    u16* WeT  = (u16*)((char*)d_ws + 786432);
    u16* WgT  = (u16*)((char*)d_ws + 851968);
    u16* Wc1T = (u16*)((char*)d_ws + 868352);
    prep_wt<<<dim3(14), dim3(512), 0, stream>>>(We, Wedge, Wc1, WeT, WgT, Wc1T);
    qk_kernel<<<dim3(192), dim3(256), 0, stream>>>(x, Wqk, bqk, qkbf);
    se3_fused<<<dim3(NB), dim3(512), L_TOTAL, stream>>>(
        coor, eattr, be, bedge, Wnode, bnode, bc1, Wc2, bc2,
        emask, fmask, qkbf, WeT, WgT, Wc1T, node_out, edge_out, coor_out);
  }
}

// Round 8
// 200.653 us; speedup vs baseline: 5.8372x; 1.0397x over previous
//
#include <hip/hip_runtime.h>
#include <stdint.h>
#include <float.h>

#define N_   384
#define NB   768
typedef unsigned short u16;
typedef unsigned int   u32;
typedef __attribute__((ext_vector_type(8))) short short8;   // 8 bf16 (4 VGPRs)
typedef __attribute__((ext_vector_type(4))) float f32x4;    // MFMA accumulator

__device__ __forceinline__ u32 f2bf(float x){
  union{float f; u32 u;} v; v.f = x;
  return (v.u + 0x7fffu + ((v.u >> 16) & 1u)) >> 16;   // RNE bf16
}
__device__ __forceinline__ float bf2f(u16 s){
  union{u32 u; float f;} v; v.u = ((u32)s) << 16; return v.f;
}
__device__ __forceinline__ u32 packbf(float a, float b){
  return f2bf(a) | (f2bf(b) << 16);
}
__device__ __forceinline__ uint4 pack8(const float* f){
  uint4 u;
  u.x = packbf(f[0],f[1]); u.y = packbf(f[2],f[3]);
  u.z = packbf(f[4],f[5]); u.w = packbf(f[6],f[7]);
  return u;
}
__device__ __forceinline__ void unpack8(uint4 u, float* f){
  u32 w[4] = {u.x, u.y, u.z, u.w};
  #pragma unroll
  for (int q = 0; q < 4; ++q){
    union{u32 u; float f;} lo, hi;
    lo.u = w[q] << 16; hi.u = w[q] & 0xffff0000u;
    f[2*q] = lo.f; f[2*q+1] = hi.f;
  }
}
// element index into a [rows][128] bf16 tile, 16B-granule XOR swizzle
__device__ __forceinline__ int swze(int row, int k){
  return row*128 + (((k >> 3) ^ (row & 7)) << 3) + (k & 7);
}

// ---------------- qk = x @ W_qk + b_qk  (bf16 out) ----------------
__global__ __launch_bounds__(256) void qk_kernel(
    const float* __restrict__ x, const float* __restrict__ Wqk,
    const float* __restrict__ bqk, u16* __restrict__ qkbf)
{
  __shared__ float xs[4][128];
  const int r0 = blockIdx.x * 4;
  const int t = threadIdx.x;
  for (int idx = t; idx < 512; idx += 256){
    int r = idx >> 7, k = idx & 127;
    xs[r][k] = x[(size_t)(r0 + r)*128 + k];
  }
  __syncthreads();
  float acc[4][2];
  #pragma unroll
  for (int r = 0; r < 4; ++r){ acc[r][0] = bqk[t]; acc[r][1] = bqk[t + 256]; }
  #pragma unroll 4
  for (int k = 0; k < 128; ++k){
    float w0 = Wqk[(size_t)k*512 + t], w1 = Wqk[(size_t)k*512 + t + 256];
    #pragma unroll
    for (int r = 0; r < 4; ++r){
      acc[r][0] = fmaf(xs[r][k], w0, acc[r][0]);
      acc[r][1] = fmaf(xs[r][k], w1, acc[r][1]);
    }
  }
  #pragma unroll
  for (int r = 0; r < 4; ++r){
    qkbf[(size_t)(r0+r)*512 + t]       = (u16)f2bf(acc[r][0]);
    qkbf[(size_t)(r0+r)*512 + t + 256] = (u16)f2bf(acc[r][1]);
  }
}

// =====================================================================
// ===================== PRIMARY (split) PATH ==========================
// =====================================================================

// fragment-major weight pack: frag (fc,ks): lane l holds W[k=ks*32+(l>>4)*8+e][c=fc*16+(l&15)]
__global__ __launch_bounds__(256) void prep_frag(
    const float* __restrict__ We, const float* __restrict__ Wedge,
    const float* __restrict__ Wc1, u16* __restrict__ WeF,
    u16* __restrict__ WgF, u16* __restrict__ W1F)
{
  const int id = blockIdx.x*256 + threadIdx.x;   // 28 blocks * 256 = 7168 = 112 frags * 64
  const int frag = id >> 6, lane = id & 63;
  if (frag >= 112) return;
  const float* src; u16* dst; int C, fc, ks;
  if (frag < 64){       fc = frag >> 2;      ks = frag & 3; src = We;    C = 256; dst = WeF + (size_t)frag*512; }
  else if (frag < 80){  int fr = frag - 64; fc = fr >> 2;   ks = fr & 3; src = Wedge; C = 64;  dst = WgF + (size_t)fr*512; }
  else {                int fr = frag - 80; fc = fr >> 2;   ks = fr & 3; src = Wc1;   C = 128; dst = W1F + (size_t)fr*512; }
  const int c = fc*16 + (lane & 15);
  const int kb = ks*32 + (lane >> 4)*8;
  float f[8];
  #pragma unroll
  for (int e = 0; e < 8; ++e) f[e] = src[(size_t)(kb + e)*C + c];
  *(uint4*)(dst + lane*8) = pack8(f);
}

// ---------------- K1m: merged barrier-free swapped e-GEMM ----------------
// One wave owns 16 j's and ALL 256 channels: one A-build, 64 MFMA in two
// acc-reusing groups (logits then e_v). mfma(W,A) -> D[c,j]: lane j = l&15,
// c = fc*16 + (l>>4)*4 + r.
__global__ __launch_bounds__(256, 4) void k1m_logits_ev(
    const float* __restrict__ coor, const float* __restrict__ edge_attr,
    const float* __restrict__ be, const int* __restrict__ emask,
    const u16* __restrict__ qkbf, const u16* __restrict__ WeF,
    u16* __restrict__ attL, u16* __restrict__ evG)
{
  __shared__ u16 Evp[64*128];   // 16 KB; each wave touches only its own 16 rows
  const int t = threadIdx.x;
  const int ch = blockIdx.x, bi = blockIdx.y;     // ch: 0..5 (64-j chunks)
  const int b = (bi >= N_) ? 1 : 0;
  const int w = t >> 6, l = t & 63, lr = l & 15, kg = l >> 4;
  const int jw = ch*64 + w*16;
  const int ja = jw + lr;              // this lane's j (B-operand 16-idx AND output col)

  // ---- edge fragments in registers (lane: 16-idx = j = l&15, k = kg*8+e) ----
  short8 afr[4];
  {
    const float* src = &edge_attr[((size_t)bi*N_ + ja)*64 + kg*8];
    #pragma unroll
    for (int ks = 0; ks < 2; ++ks){
      float4 a  = *(const float4*)(src + ks*32);
      float4 c4 = *(const float4*)(src + ks*32 + 4);
      float f[8] = {a.x,a.y,a.z,a.w,c4.x,c4.y,c4.z,c4.w};
      *(uint4*)&afr[ks] = pack8(f);
    }
    const float cix = coor[bi*3], ciy = coor[bi*3+1], ciz = coor[bi*3+2];
    const float dx = cix - coor[(size_t)(b*N_+ja)*3+0];
    const float dy = ciy - coor[(size_t)(b*N_+ja)*3+1];
    const float dz = ciz - coor[(size_t)(b*N_+ja)*3+2];
    const float dm = fminf(sqrtf(dx*dx + dy*dy + dz*dz), 2.0f);
    #pragma unroll
    for (int ks = 2; ks < 4; ++ks){
      const int g0 = (ks-2)*32 + kg*8;
      float f[8];
      #pragma unroll
      for (int e = 0; e < 8; ++e){
        const float dd = dm - (float)(g0+e)*(2.0f/63.0f);
        f[e] = __expf(-496.125f * dd * dd);   // coeff = -0.5/(2/63)^2
      }
      *(uint4*)&afr[ks] = pack8(f);
    }
  }

  // ---- group A: e_m channels (fc 0..7) -> logits ----
  f32x4 acc[8];
  #pragma unroll
  for (int f = 0; f < 8; ++f) acc[f] = (f32x4){0.f,0.f,0.f,0.f};
  #pragma unroll
  for (int ks = 0; ks < 4; ++ks){
    #pragma unroll
    for (int mf = 0; mf < 8; ++mf){
      short8 wv = *(const short8*)&WeF[(size_t)((mf*4 + ks)*64 + l)*8];
      acc[mf] = __builtin_amdgcn_mfma_f32_16x16x32_bf16(wv, afr[ks], acc[mf], 0, 0, 0);
    }
  }
  {
    const int mk = emask[(size_t)bi*N_ + ja];
    float s8[8];
    #pragma unroll
    for (int mf = 0; mf < 8; ++mf){
      const int c = mf*16 + kg*4;
      uint2 lmu = *(const uint2*)&qkbf[(size_t)bi*512 + c];
      uint2 rmu = *(const uint2*)&qkbf[(size_t)(b*N_+ja)*512 + 128 + c];
      float4 bev = *(const float4*)&be[c];
      const u16* lmp = (const u16*)&lmu; const u16* rmp = (const u16*)&rmu;
      float s = 0.f;
      #pragma unroll
      for (int r = 0; r < 4; ++r){
        float e = acc[mf][r] + (&bev.x)[r]; e = e > 0.f ? e : 0.01f*e;
        s += e * bf2f(lmp[r]) * bf2f(rmp[r]);
      }
      s += __shfl_xor(s, 16); s += __shfl_xor(s, 32);
      s8[mf] = s * 0.25f;
    }
    if (kg == 0){
      const u32 NEG2 = packbf(-1e30f, -1e30f);
      uint4 o;
      o.x = mk ? packbf(s8[0], s8[1]) : NEG2;
      o.y = mk ? packbf(s8[2], s8[3]) : NEG2;
      o.z = mk ? packbf(s8[4], s8[5]) : NEG2;
      o.w = mk ? packbf(s8[6], s8[7]) : NEG2;
      *(uint4*)&attL[(size_t)bi*3072 + ja*8] = o;
    }
  }

  // ---- group B: e_v channels (fc 8..15) -> parked image ----
  #pragma unroll
  for (int f = 0; f < 8; ++f) acc[f] = (f32x4){0.f,0.f,0.f,0.f};
  #pragma unroll
  for (int ks = 0; ks < 4; ++ks){
    #pragma unroll
    for (int mf = 0; mf < 8; ++mf){
      short8 wv = *(const short8*)&WeF[(size_t)(((8+mf)*4 + ks)*64 + l)*8];
      acc[mf] = __builtin_amdgcn_mfma_f32_16x16x32_bf16(wv, afr[ks], acc[mf], 0, 0, 0);
    }
  }
  {
    const int jl = w*16 + lr;
    #pragma unroll
    for (int mf = 0; mf < 8; ++mf){
      const int c = mf*16 + kg*4;            // c within [0,128) of the e_v half
      float4 bev = *(const float4*)&be[128 + c];
      float e[4];
      #pragma unroll
      for (int r = 0; r < 4; ++r){
        float y = acc[mf][r] + (&bev.x)[r]; e[r] = y > 0.f ? y : 0.01f*y;
      }
      uint2 pk; pk.x = packbf(e[0], e[1]); pk.y = packbf(e[2], e[3]);
      const int g = c >> 3;
      *(uint2*)&Evp[jl*128 + ((g ^ (jl & 7)) << 3) + (kg & 1)*4] = pk;
    }
    // copy own 16 rows (4 KB) into the (bi, ch) parked image slice
    uint4* dst = (uint4*)evG + ((size_t)bi*6 + ch)*1024 + w*256;
    const uint4* E4 = (const uint4*)Evp;
    #pragma unroll
    for (int q = 0; q < 4; ++q) dst[l + q*64] = E4[w*256 + l + q*64];
  }
}

// ---------------- K2: softmax over j, probs bf16 in place ----------------
__global__ __launch_bounds__(512) void k2_softmax(u16* __restrict__ attL)
{
  __shared__ u16 sl[3072];
  const int t = threadIdx.x, bi = blockIdx.x;
  uint4* sl4 = (uint4*)sl;
  if (t < 384) sl4[t] = ((const uint4*)(attL + (size_t)bi*3072))[t];
  __syncthreads();
  const int h = t >> 6, lane = t & 63;
  float v[6]; float m = -FLT_MAX;
  #pragma unroll
  for (int q = 0; q < 6; ++q){ v[q] = bf2f(sl[(lane + q*64)*8 + h]); m = fmaxf(m, v[q]); }
  #pragma unroll
  for (int o = 32; o >= 1; o >>= 1) m = fmaxf(m, __shfl_xor(m, o));
  float s = 0.f;
  #pragma unroll
  for (int q = 0; q < 6; ++q){ v[q] = __expf(v[q] - m); s += v[q]; }
  #pragma unroll
  for (int o = 32; o >= 1; o >>= 1) s += __shfl_xor(s, o);
  const float inv = 1.f / s;
  #pragma unroll
  for (int q = 0; q < 6; ++q) sl[(lane + q*64)*8 + h] = (u16)f2bf(v[q] * inv);
  __syncthreads();
  if (t < 384) ((uint4*)(attL + (size_t)bi*3072))[t] = sl4[t];
}

// ---------------- K3s: barrier-free SWAPPED edge GEMM + c1 GEMM ----------------
__global__ __launch_bounds__(256, 4) void k3s_edge_c1(
    const float* __restrict__ bedge, const float* __restrict__ bc1,
    const float* __restrict__ Wc2, const u16* __restrict__ qkbf,
    const u16* __restrict__ WgF, const u16* __restrict__ W1F,
    const u16* __restrict__ attL, float* __restrict__ edge_out,
    float* __restrict__ cattB)
{
  const int t = threadIdx.x, ch = blockIdx.x, bi = blockIdx.y;
  const int b = (bi >= N_) ? 1 : 0;
  const int j0 = ch * 64;
  const int w = t >> 6, l = t & 63, lr = l & 15, kg = l >> 4;
  const int jloc = w*16 + lr;
  const int jglob = j0 + jloc;
  const u16* evS = (const u16*)edge_out + ((size_t)bi*6 + ch)*8192;

  f32x4 eacc[4], cacc[8];
  #pragma unroll
  for (int f = 0; f < 4; ++f) eacc[f] = (f32x4){0.f,0.f,0.f,0.f};
  #pragma unroll
  for (int f = 0; f < 8; ++f) cacc[f] = (f32x4){0.f,0.f,0.f,0.f};

  #pragma unroll
  for (int ks = 0; ks < 4; ++ks){
    const int k0 = ks*32 + kg*8;
    short8 ar = *(const short8*)&evS[swze(jloc, k0)];
    const float p = bf2f(attL[(size_t)bi*3072 + jglob*8 + (k0 >> 4)]);
    uint4 rvu = *(const uint4*)&qkbf[(size_t)(b*N_ + jglob)*512 + 384 + k0];
    uint4 lvu = *(const uint4*)&qkbf[(size_t)bi*512 + 256 + k0];
    short8 ame, amc;
    const u16* arp = (const u16*)&ar;
    const u16* rvp = (const u16*)&rvu;
    const u16* lvp = (const u16*)&lvu;
    u16* amep = (u16*)&ame; u16* amcp = (u16*)&amc;
    #pragma unroll
    for (int e = 0; e < 8; ++e){
      const float ef = bf2f(arp[e]) * p;
      amep[e] = (u16)f2bf(ef);
      amcp[e] = (u16)f2bf(ef * bf2f(lvp[e]) * bf2f(rvp[e]));
    }
    #pragma unroll
    for (int f = 0; f < 4; ++f){
      short8 wv = *(const short8*)&WgF[(size_t)((f*4 + ks)*64 + l)*8];
      eacc[f] = __builtin_amdgcn_mfma_f32_16x16x32_bf16(wv, ame, eacc[f], 0, 0, 0);
    }
    #pragma unroll
    for (int f = 0; f < 8; ++f){
      short8 wv = *(const short8*)&W1F[(size_t)((f*4 + ks)*64 + l)*8];
      cacc[f] = __builtin_amdgcn_mfma_f32_16x16x32_bf16(wv, amc, cacc[f], 0, 0, 0);
    }
  }
  // edge epilogue: D[g, j] -> lane j fixed, g = gf*16 + kg*4 + r -> float4 stores
  #pragma unroll
  for (int gf = 0; gf < 4; ++gf){
    const int g0 = gf*16 + kg*4;
    float4 bg = *(const float4*)&bedge[g0];
    float4 o;
    o.x = eacc[gf][0] + bg.x; o.y = eacc[gf][1] + bg.y;
    o.z = eacc[gf][2] + bg.z; o.w = eacc[gf][3] + bg.w;
    *(float4*)&edge_out[((size_t)bi*N_ + jglob)*64 + g0] = o;
  }
  // c1 epilogue: lane-local 32 terms + 2 shfl
  {
    float s = 0.f;
    #pragma unroll
    for (int cf = 0; cf < 8; ++cf){
      const int c0 = cf*16 + kg*4;
      float4 b1 = *(const float4*)&bc1[c0];
      float4 w2 = *(const float4*)&Wc2[c0];
      #pragma unroll
      for (int r = 0; r < 4; ++r){
        float y = cacc[cf][r] + (&b1.x)[r]; y = y > 0.f ? y : 0.01f*y;
        s += y * (&w2.x)[r];
      }
    }
    s += __shfl_xor(s, 16); s += __shfl_xor(s, 32);
    if (kg == 0) cattB[(size_t)bi*N_ + jglob] = s;
  }
}

// ---------------- K4: node einsum (vectorized) + W_node + coor finale ----------------
__global__ __launch_bounds__(256) void k4_node_coor(
    const float* __restrict__ coor, const float* __restrict__ Wnode,
    const float* __restrict__ bnode, const float* __restrict__ bc2,
    const int* __restrict__ emask, const int* __restrict__ fmask,
    const u16* __restrict__ qkbf, const u16* __restrict__ attL,
    const float* __restrict__ cattB, float* __restrict__ node_out,
    float* __restrict__ coor_out)
{
  __shared__ u16 pS[3072];
  __shared__ float part[8][256];
  __shared__ float red[256];
  __shared__ float halfb[256];
  __shared__ float cred[16];
  const int t = threadIdx.x, bi = blockIdx.x;
  const int b = (bi >= N_) ? 1 : 0;
  for (int idx = t; idx < 384; idx += 256)
    ((uint4*)pS)[idx] = ((const uint4*)(attL + (size_t)bi*3072))[idx];
  __syncthreads();
  // node pre: 32 chan-groups (uint4) x 8 j-groups of 48 j
  {
    const int q = t & 31, jg = t >> 5;
    const int ch0 = 256 + q*8;
    const int h = (q < 16) ? (q >> 1) : ((q - 16) >> 1);
    const int slot0 = (q < 16) ? (h*32 + (q & 1)*8) : (h*32 + 16 + (q & 1)*8);
    float a8[8];
    #pragma unroll
    for (int e = 0; e < 8; ++e) a8[e] = 0.f;
    for (int j = jg*48; j < jg*48 + 48; ++j){
      const float p = bf2f(pS[j*8 + h]);
      uint4 v = *(const uint4*)&qkbf[(size_t)(b*N_+j)*512 + ch0];
      const u16* vp = (const u16*)&v;
      #pragma unroll
      for (int e = 0; e < 8; ++e) a8[e] = fmaf(p, bf2f(vp[e]), a8[e]);
    }
    float4 o0 = {a8[0],a8[1],a8[2],a8[3]}, o1 = {a8[4],a8[5],a8[6],a8[7]};
    *(float4*)&part[jg][slot0]     = o0;
    *(float4*)&part[jg][slot0 + 4] = o1;
  }
  __syncthreads();
  {
    float s = 0.f;
    #pragma unroll
    for (int g = 0; g < 8; ++g) s += part[g][t];
    red[t] = s;
  }
  __syncthreads();
  {
    const int c = t & 127, qq = t >> 7;
    float s = 0.f;
    #pragma unroll 4
    for (int k = qq*128; k < qq*128 + 128; ++k)
      s = fmaf(red[k], Wnode[(size_t)k*128 + c], s);
    halfb[t] = s;
  }
  __syncthreads();
  if (t < 128)
    node_out[(size_t)bi*128 + t] = halfb[t] + halfb[128 + t] + bnode[t];

  // coor
  {
    const float cix = coor[bi*3], ciy = coor[bi*3+1], ciz = coor[bi*3+2];
    float vx=0.f, vy=0.f, vz=0.f, cnt=0.f;
    for (int j = t; j < N_; j += 256){
      if (emask[(size_t)bi*N_ + j]){
        cnt += 1.f;
        const float val = cattB[(size_t)bi*N_ + j] + bc2[0];
        const float dx = cix - coor[(size_t)(b*N_+j)*3+0];
        const float dy = ciy - coor[(size_t)(b*N_+j)*3+1];
        const float dz = ciz - coor[(size_t)(b*N_+j)*3+2];
        const float nrm = sqrtf(dx*dx + dy*dy + dz*dz);
        if (nrm > 0.f){
          const float qv = val / fmaxf(nrm, 1e-8f);
          vx += qv*dx; vy += qv*dy; vz += qv*dz;
        }
      }
    }
    #pragma unroll
    for (int o = 32; o >= 1; o >>= 1){
      vx += __shfl_xor(vx, o); vy += __shfl_xor(vy, o);
      vz += __shfl_xor(vz, o); cnt += __shfl_xor(cnt, o);
    }
    const int w = t >> 6, l = t & 63;
    if (l == 0){ cred[w*4]=vx; cred[w*4+1]=vy; cred[w*4+2]=vz; cred[w*4+3]=cnt; }
  }
  __syncthreads();
  if (t == 0){
    float sx=0.f, sy=0.f, sz=0.f, sc=0.f;
    #pragma unroll
    for (int ww = 0; ww < 4; ++ww){
      sx += cred[ww*4]; sy += cred[ww*4+1]; sz += cred[ww*4+2]; sc += cred[ww*4+3];
    }
    const float d = sc + 1e-7f, fm = (float)fmask[bi];
    coor_out[bi*3+0] = sx/d*fm;
    coor_out[bi*3+1] = sy/d*fm;
    coor_out[bi*3+2] = sz/d*fm;
  }
}

// =====================================================================
// ================= FALLBACK (R3 monolithic) PATH =====================
// =====================================================================

__global__ __launch_bounds__(512) void prep_wt(
    const float* __restrict__ We, const float* __restrict__ Wedge,
    const float* __restrict__ Wc1, u16* __restrict__ WeT,
    u16* __restrict__ WgT, u16* __restrict__ Wc1T)
{
  const int id = blockIdx.x*512 + threadIdx.x;
  const float* src; u16* dst; int c, g, stride;
  if (id < 4096){        int q = id;      c = q>>4; g = q&15; src = We    + (size_t)g*8*256 + c; stride = 256; dst = WeT  + c*128 + ((g ^ (c&7))<<3); }
  else if (id < 5120){   int q = id-4096; c = q>>4; g = q&15; src = Wedge + (size_t)g*8*64  + c; stride = 64;  dst = WgT  + c*128 + ((g ^ (c&7))<<3); }
  else if (id < 7168){   int q = id-5120; c = q>>4; g = q&15; src = Wc1   + (size_t)g*8*128 + c; stride = 128; dst = Wc1T + c*128 + ((g ^ (c&7))<<3); }
  else return;
  float f[8];
  #pragma unroll
  for (int e = 0; e < 8; ++e) f[e] = src[(size_t)e*stride];
  *(uint4*)dst = pack8(f);
}

#define L_ATT   0
#define L_AS    12288
#define L_WE    45056
#define L_WG    45056
#define L_W1    61440
#define L_PART  94208
#define L_EVP   110592
#define L_CATT  110592
#define L_RED2  113664
#define L_MISC  126976
#define L_QIF   127488
#define L_TOTAL 129536

__global__ __launch_bounds__(512, 1) void se3_fused(
    const float* __restrict__ coor, const float* __restrict__ edge_attr,
    const float* __restrict__ be, const float* __restrict__ bedge,
    const float* __restrict__ Wnode, const float* __restrict__ bnode,
    const float* __restrict__ bc1, const float* __restrict__ Wc2,
    const float* __restrict__ bc2, const int* __restrict__ emask,
    const int* __restrict__ fmask, const u16* __restrict__ qkbf,
    const u16* __restrict__ WeTg, const u16* __restrict__ WgTg,
    const u16* __restrict__ Wc1Tg,
    float* __restrict__ node_out, float* __restrict__ edge_out, float* __restrict__ coor_out)
{
  extern __shared__ char smem[];
  float* att  = (float*)(smem + L_ATT);
  float* qif  = (float*)(smem + L_QIF);
  float* misc = (float*)(smem + L_MISC);

  const int t  = threadIdx.x;
  const int bi = blockIdx.x;
  const int b  = (bi >= N_) ? 1 : 0;
  const float cix = coor[bi*3], ciy = coor[bi*3+1], ciz = coor[bi*3+2];

  const int w  = t >> 6, l = t & 63;
  const int chh = w >> 2, jsb = (w & 3) * 16;
  const int lr = l & 15, kg = l >> 4;

  for (int idx = t; idx < 4096; idx += 512)
    ((uint4*)(smem + L_WE))[idx] = ((const uint4*)WeTg)[idx];
  qif[t] = bf2f(qkbf[(size_t)bi*512 + t]);
  __syncthreads();

  float bevf[8], lmvf[8];
  #pragma unroll
  for (int f = 0; f < 8; ++f){
    const int c = chh*128 + f*16 + lr;
    bevf[f] = be[c];
    lmvf[f] = (chh == 0) ? qif[c] : 0.f;
  }

  float4 pa0, pb0, pa1, pb1;
  const int gq = t & 15, rq = t >> 4;
  auto issue_ea = [&](int j0){
    if (gq < 8){
      const float* s0 = &edge_attr[((size_t)bi*N_ + j0 + rq)*64 + gq*8];
      const float* s1 = &edge_attr[((size_t)bi*N_ + j0 + rq + 32)*64 + gq*8];
      pa0 = *(const float4*)s0; pb0 = *(const float4*)(s0 + 4);
      pa1 = *(const float4*)s1; pb1 = *(const float4*)(s1 + 4);
    }
  };

  uint4* evg = (uint4*)(edge_out + (size_t)bi*24576);

  issue_ea(0);
  for (int ch = 0; ch < 6; ++ch){
    const int j0 = ch * 64;
    {
      u16* As = (u16*)(smem + L_AS + (ch & 1)*16384);
      #pragma unroll
      for (int q = 0; q < 2; ++q){
        const int row = rq + q*32;
        const int j = j0 + row;
        float f[8];
        if (gq < 8){
          float4 A = q ? pa1 : pa0, Bv = q ? pb1 : pb0;
          f[0]=A.x; f[1]=A.y; f[2]=A.z; f[3]=A.w;
          f[4]=Bv.x; f[5]=Bv.y; f[6]=Bv.z; f[7]=Bv.w;
        } else {
          const float dx = cix - coor[(size_t)(b*N_+j)*3+0];
          const float dy = ciy - coor[(size_t)(b*N_+j)*3+1];
          const float dz = ciz - coor[(size_t)(b*N_+j)*3+2];
          const float dm = fminf(sqrtf(dx*dx + dy*dy + dz*dz), 2.0f);
          const int k0 = (gq - 8)*8;
          #pragma unroll
          for (int e = 0; e < 8; ++e){
            const float dd = dm - (float)(k0+e)*(2.0f/63.0f);
            f[e] = __expf(-496.125f * dd * dd);
          }
        }
        ((uint4*)As)[row*16 + (gq ^ (row & 7))] = pack8(f);
      }
    }
    __syncthreads();
    if (ch + 1 < 6) issue_ea((ch+1)*64);

    f32x4 acc[8];
    #pragma unroll
    for (int f = 0; f < 8; ++f) acc[f] = (f32x4){0.f,0.f,0.f,0.f};
    {
      u16* As  = (u16*)(smem + L_AS + (ch & 1)*16384);
      u16* WeL = (u16*)(smem + L_WE);
      #pragma unroll
      for (int ks = 0; ks < 4; ++ks){
        const int k0 = ks*32 + kg*8;
        short8 a = *(const short8*)&As[swze(jsb + lr, k0)];
        #pragma unroll
        for (int f = 0; f < 8; ++f){
          const int c = chh*128 + f*16 + lr;
          short8 bb = *(const short8*)&WeL[swze(c, k0)];
          acc[f] = __builtin_amdgcn_mfma_f32_16x16x32_bf16(a, bb, acc[f], 0, 0, 0);
        }
      }
    }
    if (chh == 0){
      #pragma unroll
      for (int f = 0; f < 8; ++f){
        #pragma unroll
        for (int r = 0; r < 4; ++r){
          const int j = j0 + jsb + kg*4 + r;
          float e = acc[f][r] + bevf[f]; e = e > 0.f ? e : 0.01f*e;
          const float rm = bf2f(qkbf[(size_t)(b*N_+j)*512 + 128 + f*16 + lr]);
          float s = lmvf[f] * rm * e;
          s += __shfl_xor(s, 1); s += __shfl_xor(s, 2);
          s += __shfl_xor(s, 4); s += __shfl_xor(s, 8);
          if (lr == 0)
            att[j*8 + f] = emask[(size_t)bi*N_ + j] ? s*0.25f : -FLT_MAX;
        }
      }
    } else {
      u16* Evp = (u16*)(smem + L_EVP);
      #pragma unroll
      for (int f = 0; f < 8; ++f){
        #pragma unroll
        for (int r = 0; r < 4; ++r){
          float e = acc[f][r] + bevf[f]; e = e > 0.f ? e : 0.01f*e;
          const float pr = __shfl_xor(e, 1);
          if (!(lr & 1)){
            const int jl = jsb + kg*4 + r;
            const int cv = f*16 + lr;
            *(u32*)&Evp[jl*128 + (((cv>>3) ^ (jl&7))<<3) + (cv&7)] = packbf(e, pr);
          }
        }
      }
    }
    __syncthreads();
    {
      const uint4* Evp4 = (const uint4*)(smem + L_EVP);
      #pragma unroll
      for (int q = 0; q < 2; ++q)
        evg[ch*1024 + t + q*512] = Evp4[t + q*512];
    }
  }

  {
    const int h = w, lane = l;
    float m = -FLT_MAX;
    #pragma unroll
    for (int q = 0; q < 6; ++q) m = fmaxf(m, att[(lane + q*64)*8 + h]);
    #pragma unroll
    for (int o = 32; o >= 1; o >>= 1) m = fmaxf(m, __shfl_xor(m, o));
    float pv[6], s = 0.f;
    #pragma unroll
    for (int q = 0; q < 6; ++q){ float p = __expf(att[(lane + q*64)*8 + h] - m); pv[q] = p; s += p; }
    #pragma unroll
    for (int o = 32; o >= 1; o >>= 1) s += __shfl_xor(s, o);
    const float inv = 1.f / s;
    #pragma unroll
    for (int q = 0; q < 6; ++q) att[(lane + q*64)*8 + h] = pv[q] * inv;
  }

  for (int idx = t; idx < 1024; idx += 512)
    ((uint4*)(smem + L_WG))[idx] = ((const uint4*)WgTg)[idx];
  for (int idx = t; idx < 2048; idx += 512){
    const int c = idx >> 4, g = idx & 15;
    uint4 u = ((const uint4*)Wc1Tg)[idx];
    const int k0 = ((g ^ (c & 7)) << 3);
    float f[8]; unpack8(u, f);
    #pragma unroll
    for (int e = 0; e < 8; ++e) f[e] *= qif[256 + k0 + e];
    ((uint4*)(smem + L_W1))[idx] = pack8(f);
  }

  float bgv[2], bc1v[4], w2v[4];
  #pragma unroll
  for (int f = 0; f < 2; ++f) bgv[f] = bedge[chh*32 + f*16 + lr];
  #pragma unroll
  for (int f = 0; f < 4; ++f){
    const int c2 = chh*64 + f*16 + lr;
    bc1v[f] = bc1[c2]; w2v[f] = Wc2[c2];
  }

  uint4 eva, evb;
  auto issue_ev = [&](int ch){
    eva = evg[ch*1024 + t];
    evb = evg[ch*1024 + t + 512];
  };
  issue_ev(0);
  __syncthreads();

  float* catt = (float*)(smem + L_CATT);

  for (int ch = 0; ch < 6; ++ch){
    const int j0 = ch * 64;
    {
      uint4* Ev4 = (uint4*)(smem + L_AS + (ch & 1)*16384);
      Ev4[t] = eva; Ev4[t + 512] = evb;
    }
    if (ch + 1 < 6) issue_ev(ch + 1);
    __syncthreads();

    u16* Ev  = (u16*)(smem + L_AS + (ch & 1)*16384);
    u16* WgL = (u16*)(smem + L_WG);
    u16* W1L = (u16*)(smem + L_W1);
    const int jrow = j0 + jsb + lr;

    f32x4 eacc[2], cacc[4];
    eacc[0] = (f32x4){0.f,0.f,0.f,0.f}; eacc[1] = (f32x4){0.f,0.f,0.f,0.f};
    #pragma unroll
    for (int f = 0; f < 4; ++f) cacc[f] = (f32x4){0.f,0.f,0.f,0.f};

    #pragma unroll
    for (int ks = 0; ks < 4; ++ks){
      const int k0 = ks*32 + kg*8;
      short8 ar = *(const short8*)&Ev[swze(jsb + lr, k0)];
      const float p = att[jrow*8 + (k0 >> 4)];
      uint4 rvu = *(const uint4*)&qkbf[(size_t)(b*N_+jrow)*512 + 384 + k0];
      short8 ame, amc;
      const u16* arp = (const u16*)&ar; const u16* rvp = (const u16*)&rvu;
      u16* amep = (u16*)&ame; u16* amcp = (u16*)&amc;
      #pragma unroll
      for (int e = 0; e < 8; ++e){
        const float ef = bf2f(arp[e]) * p;
        amep[e] = (u16)f2bf(ef);
        amcp[e] = (u16)f2bf(ef * bf2f(rvp[e]));
      }
      #pragma unroll
      for (int f = 0; f < 2; ++f){
        short8 bb = *(const short8*)&WgL[swze(chh*32 + f*16 + lr, k0)];
        eacc[f] = __builtin_amdgcn_mfma_f32_16x16x32_bf16(ame, bb, eacc[f], 0, 0, 0);
      }
      #pragma unroll
      for (int f = 0; f < 4; ++f){
        short8 bb = *(const short8*)&W1L[swze(chh*64 + f*16 + lr, k0)];
        cacc[f] = __builtin_amdgcn_mfma_f32_16x16x32_bf16(amc, bb, cacc[f], 0, 0, 0);
      }
    }
    #pragma unroll
    for (int f = 0; f < 2; ++f){
      const int g = chh*32 + f*16 + lr;
      #pragma unroll
      for (int r = 0; r < 4; ++r){
        const int j = j0 + jsb + kg*4 + r;
        edge_out[((size_t)bi*N_ + j)*64 + g] = eacc[f][r] + bgv[f];
      }
    }
    {
      float sr[4] = {0.f,0.f,0.f,0.f};
      #pragma unroll
      for (int f = 0; f < 4; ++f){
        #pragma unroll
        for (int r = 0; r < 4; ++r){
          float y = cacc[f][r] + bc1v[f]; y = y > 0.f ? y : 0.01f*y;
          sr[r] += y * w2v[f];
        }
      }
      #pragma unroll
      for (int r = 0; r < 4; ++r){
        float s = sr[r];
        s += __shfl_xor(s, 1); s += __shfl_xor(s, 2);
        s += __shfl_xor(s, 4); s += __shfl_xor(s, 8);
        if (lr == 0) catt[chh*N_ + j0 + jsb + kg*4 + r] = s;
      }
    }
  }
  __syncthreads();

  {
    float vx = 0.f, vy = 0.f, vz = 0.f, cnt = 0.f;
    if (t < N_){
      const int j = t;
      const int mk = emask[(size_t)bi*N_ + j];
      cnt = (mk != 0) ? 1.f : 0.f;
      if (mk){
        const float val = catt[j] + catt[N_ + j] + bc2[0];
        const float dx = cix - coor[(size_t)(b*N_+j)*3+0];
        const float dy = ciy - coor[(size_t)(b*N_+j)*3+1];
        const float dz = ciz - coor[(size_t)(b*N_+j)*3+2];
        const float nrm = sqrtf(dx*dx + dy*dy + dz*dz);
        if (nrm > 0.f){
          const float qq = val / fmaxf(nrm, 1e-8f);
          vx = qq*dx; vy = qq*dy; vz = qq*dz;
        }
      }
    }
    #pragma unroll
    for (int o = 32; o >= 1; o >>= 1){
      vx += __shfl_xor(vx, o); vy += __shfl_xor(vy, o);
      vz += __shfl_xor(vz, o); cnt += __shfl_xor(cnt, o);
    }
    if (l == 0){
      float* wr = misc + 16 + w*4;
      wr[0] = vx; wr[1] = vy; wr[2] = vz; wr[3] = cnt;
    }
  }
  __syncthreads();
  if (t == 0){
    float sx=0.f, sy=0.f, sz=0.f, sc=0.f;
    #pragma unroll
    for (int ww = 0; ww < 8; ++ww){
      sx += misc[16+ww*4]; sy += misc[16+ww*4+1];
      sz += misc[16+ww*4+2]; sc += misc[16+ww*4+3];
    }
    const float d = sc + 1e-7f, fm = (float)fmask[bi];
    coor_out[bi*3+0] = sx/d*fm; coor_out[bi*3+1] = sy/d*fm; coor_out[bi*3+2] = sz/d*fm;
  }

  {
    float* part = (float*)(smem + L_PART);
    const int c8 = t & 31, jg = t >> 5;
    const int ch0 = 256 + c8*8;
    const int h = (c8 < 16) ? (c8 >> 1) : ((c8 - 16) >> 1);
    const int slot0 = (c8 < 16) ? (h*32 + (c8 & 1)*8) : (h*32 + 16 + (c8 & 1)*8);
    float a8[8];
    #pragma unroll
    for (int e = 0; e < 8; ++e) a8[e] = 0.f;
    for (int q = 0; q < 24; ++q){
      const int j = jg*24 + q;
      const float p = att[j*8 + h];
      uint4 v = *(const uint4*)&qkbf[(size_t)(b*N_+j)*512 + ch0];
      const u16* vp = (const u16*)&v;
      #pragma unroll
      for (int e = 0; e < 8; ++e) a8[e] = fmaf(p, bf2f(vp[e]), a8[e]);
    }
    float4 o0 = {a8[0],a8[1],a8[2],a8[3]}, o1 = {a8[4],a8[5],a8[6],a8[7]};
    *(float4*)&part[jg*256 + slot0]     = o0;
    *(float4*)&part[jg*256 + slot0 + 4] = o1;
  }
  __syncthreads();
  {
    float* part = (float*)(smem + L_PART);
    float* red2 = (float*)(smem + L_RED2);
    if (t < 256){
      float s = 0.f;
      #pragma unroll
      for (int g = 0; g < 16; ++g) s += part[g*256 + t];
      red2[t] = s;
    }
  }
  __syncthreads();
  {
    float* part = (float*)(smem + L_PART);
    float* red2 = (float*)(smem + L_RED2);
    const int c = t & 127, qq = t >> 7;
    float s = 0.f;
    #pragma unroll 4
    for (int k = qq*64; k < qq*64 + 64; ++k)
      s = fmaf(red2[k], Wnode[(size_t)k*128 + c], s);
    part[qq*128 + c] = s;
    __syncthreads();
    if (t < 128)
      node_out[(size_t)bi*128 + t] = part[t] + part[128+t] + part[256+t] + part[384+t] + bnode[t];
  }
}

extern "C" void kernel_launch(void* const* d_in, const int* in_sizes, int n_in,
                              void* d_out, int out_size, void* d_ws, size_t ws_size,
                              hipStream_t stream)
{
  const float* x     = (const float*)d_in[0];
  const float* coor  = (const float*)d_in[1];
  const float* eattr = (const float*)d_in[2];
  const float* Wqk   = (const float*)d_in[3];
  const float* bqk   = (const float*)d_in[4];
  const float* We    = (const float*)d_in[5];
  const float* be    = (const float*)d_in[6];
  const float* Wnode = (const float*)d_in[7];
  const float* bnode = (const float*)d_in[8];
  const float* Wedge = (const float*)d_in[9];
  const float* bedge = (const float*)d_in[10];
  const float* Wc1   = (const float*)d_in[11];
  const float* bc1   = (const float*)d_in[12];
  const float* Wc2   = (const float*)d_in[13];
  const float* bc2   = (const float*)d_in[14];
  const int*   emask = (const int*)d_in[15];
  const int*   fmask = (const int*)d_in[16];

  u16* qkbf = (u16*)d_ws;                         // 786432 B

  float* out      = (float*)d_out;
  float* node_out = out;                           // 2*384*128
  float* edge_out = out + 98304;                   // 2*384*384*64
  float* coor_out = out + 98304 + 18874368;        // 2*384*3

  const size_t NEED = 6799360;
  if (ws_size >= NEED){
    u16*   WeF   = (u16*)((char*)d_ws + 786432);   // 65536
    u16*   WgF   = (u16*)((char*)d_ws + 851968);   // 16384
    u16*   W1F   = (u16*)((char*)d_ws + 868352);   // 32768
    u16*   attL  = (u16*)((char*)d_ws + 901120);   // 4718592
    float* cattB = (float*)((char*)d_ws + 5619712);// 1179648

    prep_frag<<<dim3(28), dim3(256), 0, stream>>>(We, Wedge, Wc1, WeF, WgF, W1F);
    qk_kernel<<<dim3(192), dim3(256), 0, stream>>>(x, Wqk, bqk, qkbf);
    k1m_logits_ev<<<dim3(6, NB), dim3(256), 0, stream>>>(
        coor, eattr, be, emask, qkbf, WeF, attL, (u16*)edge_out);
    k2_softmax<<<dim3(NB), dim3(512), 0, stream>>>(attL);
    k3s_edge_c1<<<dim3(6, NB), dim3(256), 0, stream>>>(
        bedge, bc1, Wc2, qkbf, WgF, W1F, attL, edge_out, cattB);
    k4_node_coor<<<dim3(NB), dim3(256), 0, stream>>>(
        coor, Wnode, bnode, bc2, emask, fmask, qkbf, attL, cattB, node_out, coor_out);
  } else {
    u16* WeT  = (u16*)((char*)d_ws + 786432);
    u16* WgT  = (u16*)((char*)d_ws + 851968);
    u16* Wc1T = (u16*)((char*)d_ws + 868352);
    prep_wt<<<dim3(14), dim3(512), 0, stream>>>(We, Wedge, Wc1, WeT, WgT, Wc1T);
    qk_kernel<<<dim3(192), dim3(256), 0, stream>>>(x, Wqk, bqk, qkbf);
    se3_fused<<<dim3(NB), dim3(512), L_TOTAL, stream>>>(
        coor, eattr, be, bedge, Wnode, bnode, bc1, Wc2, bc2,
        emask, fmask, qkbf, WeT, WgT, Wc1T, node_out, edge_out, coor_out);
  }
}

// Round 9
// 199.642 us; speedup vs baseline: 5.8667x; 1.0051x over previous
//
#include <hip/hip_runtime.h>
#include <stdint.h>
#include <float.h>

#define N_   384
#define NB   768
typedef unsigned short u16;
typedef unsigned int   u32;
typedef __attribute__((ext_vector_type(8))) short short8;   // 8 bf16 (4 VGPRs)
typedef __attribute__((ext_vector_type(4))) float f32x4;    // MFMA accumulator

__device__ __forceinline__ u32 f2bf(float x){
  union{float f; u32 u;} v; v.f = x;
  return (v.u + 0x7fffu + ((v.u >> 16) & 1u)) >> 16;   // RNE bf16
}
__device__ __forceinline__ float bf2f(u16 s){
  union{u32 u; float f;} v; v.u = ((u32)s) << 16; return v.f;
}
__device__ __forceinline__ u32 packbf(float a, float b){
  return f2bf(a) | (f2bf(b) << 16);
}
__device__ __forceinline__ uint4 pack8(const float* f){
  uint4 u;
  u.x = packbf(f[0],f[1]); u.y = packbf(f[2],f[3]);
  u.z = packbf(f[4],f[5]); u.w = packbf(f[6],f[7]);
  return u;
}
__device__ __forceinline__ void unpack8(uint4 u, float* f){
  u32 w[4] = {u.x, u.y, u.z, u.w};
  #pragma unroll
  for (int q = 0; q < 4; ++q){
    union{u32 u; float f;} lo, hi;
    lo.u = w[q] << 16; hi.u = w[q] & 0xffff0000u;
    f[2*q] = lo.f; f[2*q+1] = hi.f;
  }
}
// element index into a [rows][128] bf16 tile, 16B-granule XOR swizzle
__device__ __forceinline__ int swze(int row, int k){
  return row*128 + (((k >> 3) ^ (row & 7)) << 3) + (k & 7);
}

// ---------------- qk = x @ W_qk + b_qk  (bf16 out) ----------------
__global__ __launch_bounds__(256) void qk_kernel(
    const float* __restrict__ x, const float* __restrict__ Wqk,
    const float* __restrict__ bqk, u16* __restrict__ qkbf)
{
  __shared__ float xs[4][128];
  const int r0 = blockIdx.x * 4;
  const int t = threadIdx.x;
  for (int idx = t; idx < 512; idx += 256){
    int r = idx >> 7, k = idx & 127;
    xs[r][k] = x[(size_t)(r0 + r)*128 + k];
  }
  __syncthreads();
  float acc[4][2];
  #pragma unroll
  for (int r = 0; r < 4; ++r){ acc[r][0] = bqk[t]; acc[r][1] = bqk[t + 256]; }
  #pragma unroll 4
  for (int k = 0; k < 128; ++k){
    float w0 = Wqk[(size_t)k*512 + t], w1 = Wqk[(size_t)k*512 + t + 256];
    #pragma unroll
    for (int r = 0; r < 4; ++r){
      acc[r][0] = fmaf(xs[r][k], w0, acc[r][0]);
      acc[r][1] = fmaf(xs[r][k], w1, acc[r][1]);
    }
  }
  #pragma unroll
  for (int r = 0; r < 4; ++r){
    qkbf[(size_t)(r0+r)*512 + t]       = (u16)f2bf(acc[r][0]);
    qkbf[(size_t)(r0+r)*512 + t + 256] = (u16)f2bf(acc[r][1]);
  }
}

// =====================================================================
// ===================== PRIMARY (split) PATH ==========================
// =====================================================================

// fragment-major weight pack: frag (fc,ks): lane l holds W[k=ks*32+(l>>4)*8+e][c=fc*16+(l&15)]
__global__ __launch_bounds__(256) void prep_frag(
    const float* __restrict__ We, const float* __restrict__ Wedge,
    const float* __restrict__ Wc1, u16* __restrict__ WeF,
    u16* __restrict__ WgF, u16* __restrict__ W1F)
{
  const int id = blockIdx.x*256 + threadIdx.x;   // 28 blocks * 256 = 7168 = 112 frags * 64
  const int frag = id >> 6, lane = id & 63;
  if (frag >= 112) return;
  const float* src; u16* dst; int C, fc, ks;
  if (frag < 64){       fc = frag >> 2;      ks = frag & 3; src = We;    C = 256; dst = WeF + (size_t)frag*512; }
  else if (frag < 80){  int fr = frag - 64; fc = fr >> 2;   ks = fr & 3; src = Wedge; C = 64;  dst = WgF + (size_t)fr*512; }
  else {                int fr = frag - 80; fc = fr >> 2;   ks = fr & 3; src = Wc1;   C = 128; dst = W1F + (size_t)fr*512; }
  const int c = fc*16 + (lane & 15);
  const int kb = ks*32 + (lane >> 4)*8;
  float f[8];
  #pragma unroll
  for (int e = 0; e < 8; ++e) f[e] = src[(size_t)(kb + e)*C + c];
  *(uint4*)(dst + lane*8) = pack8(f);
}

// ---------------- K1d: dual-tile barrier-free swapped e-GEMM ----------------
// One wave owns TWO 16-j tiles (32 j) and all 256 channels: one A-build pair,
// each WeF fragment loaded once feeds two MFMAs. mfma(W,A) -> D[c,j]:
// lane j = l&15, c = fc*16 + (l>>4)*4 + r.
__global__ __launch_bounds__(256, 3) void k1d_logits_ev(
    const float* __restrict__ coor, const float* __restrict__ edge_attr,
    const float* __restrict__ be, const int* __restrict__ emask,
    const u16* __restrict__ qkbf, const u16* __restrict__ WeF,
    u16* __restrict__ attL, u16* __restrict__ evG)
{
  __shared__ u16 Evp[128*128];   // 32 KB; each wave touches only its own 32 rows
  const int t = threadIdx.x;
  const int ch = blockIdx.x, bi = blockIdx.y;     // ch: 0..2 (128-j blocks)
  const int b = (bi >= N_) ? 1 : 0;
  const int w = t >> 6, l = t & 63, lr = l & 15, kg = l >> 4;
  const int jw = ch*128 + w*32;
  const int ja0 = jw + lr, ja1 = jw + 16 + lr;

  // ---- edge fragments for both tiles (lane: 16-idx = j, k = kg*8+e) ----
  short8 afr0[4], afr1[4];
  {
    const float cix = coor[bi*3], ciy = coor[bi*3+1], ciz = coor[bi*3+2];
    const float* s0 = &edge_attr[((size_t)bi*N_ + ja0)*64 + kg*8];
    const float* s1 = &edge_attr[((size_t)bi*N_ + ja1)*64 + kg*8];
    #pragma unroll
    for (int ks = 0; ks < 2; ++ks){
      float4 a  = *(const float4*)(s0 + ks*32);
      float4 c4 = *(const float4*)(s0 + ks*32 + 4);
      float f[8] = {a.x,a.y,a.z,a.w,c4.x,c4.y,c4.z,c4.w};
      *(uint4*)&afr0[ks] = pack8(f);
      a  = *(const float4*)(s1 + ks*32);
      c4 = *(const float4*)(s1 + ks*32 + 4);
      float g[8] = {a.x,a.y,a.z,a.w,c4.x,c4.y,c4.z,c4.w};
      *(uint4*)&afr1[ks] = pack8(g);
    }
    float dx = cix - coor[(size_t)(b*N_+ja0)*3+0];
    float dy = ciy - coor[(size_t)(b*N_+ja0)*3+1];
    float dz = ciz - coor[(size_t)(b*N_+ja0)*3+2];
    const float dm0 = fminf(sqrtf(dx*dx + dy*dy + dz*dz), 2.0f);
    dx = cix - coor[(size_t)(b*N_+ja1)*3+0];
    dy = ciy - coor[(size_t)(b*N_+ja1)*3+1];
    dz = ciz - coor[(size_t)(b*N_+ja1)*3+2];
    const float dm1 = fminf(sqrtf(dx*dx + dy*dy + dz*dz), 2.0f);
    #pragma unroll
    for (int ks = 2; ks < 4; ++ks){
      const int g0 = (ks-2)*32 + kg*8;
      float f[8], g[8];
      #pragma unroll
      for (int e = 0; e < 8; ++e){
        const float x0 = (float)(g0+e)*(2.0f/63.0f);
        const float d0 = dm0 - x0, d1 = dm1 - x0;
        f[e] = __expf(-496.125f * d0 * d0);   // coeff = -0.5/(2/63)^2
        g[e] = __expf(-496.125f * d1 * d1);
      }
      *(uint4*)&afr0[ks] = pack8(f);
      *(uint4*)&afr1[ks] = pack8(g);
    }
  }

  // ---- group A: e_m channels (fc 0..7) -> logits for both tiles ----
  f32x4 a0[8], a1[8];
  #pragma unroll
  for (int f = 0; f < 8; ++f){ a0[f] = (f32x4){0.f,0.f,0.f,0.f}; a1[f] = (f32x4){0.f,0.f,0.f,0.f}; }
  #pragma unroll
  for (int ks = 0; ks < 4; ++ks){
    #pragma unroll
    for (int mf = 0; mf < 8; ++mf){
      short8 wv = *(const short8*)&WeF[(size_t)((mf*4 + ks)*64 + l)*8];
      a0[mf] = __builtin_amdgcn_mfma_f32_16x16x32_bf16(wv, afr0[ks], a0[mf], 0, 0, 0);
      a1[mf] = __builtin_amdgcn_mfma_f32_16x16x32_bf16(wv, afr1[ks], a1[mf], 0, 0, 0);
    }
  }
  #pragma unroll
  for (int tile = 0; tile < 2; ++tile){
    const int ja = tile ? ja1 : ja0;
    const f32x4* ac = tile ? a1 : a0;
    const int mk = emask[(size_t)bi*N_ + ja];
    float s8[8];
    #pragma unroll
    for (int mf = 0; mf < 8; ++mf){
      const int c = mf*16 + kg*4;
      uint2 lmu = *(const uint2*)&qkbf[(size_t)bi*512 + c];
      uint2 rmu = *(const uint2*)&qkbf[(size_t)(b*N_+ja)*512 + 128 + c];
      float4 bev = *(const float4*)&be[c];
      const u16* lmp = (const u16*)&lmu; const u16* rmp = (const u16*)&rmu;
      float s = 0.f;
      #pragma unroll
      for (int r = 0; r < 4; ++r){
        float e = ac[mf][r] + (&bev.x)[r]; e = e > 0.f ? e : 0.01f*e;
        s += e * bf2f(lmp[r]) * bf2f(rmp[r]);
      }
      s += __shfl_xor(s, 16); s += __shfl_xor(s, 32);
      s8[mf] = s * 0.25f;
    }
    if (kg == 0){
      const u32 NEG2 = packbf(-1e30f, -1e30f);
      uint4 o;
      o.x = mk ? packbf(s8[0], s8[1]) : NEG2;
      o.y = mk ? packbf(s8[2], s8[3]) : NEG2;
      o.z = mk ? packbf(s8[4], s8[5]) : NEG2;
      o.w = mk ? packbf(s8[6], s8[7]) : NEG2;
      *(uint4*)&attL[(size_t)bi*3072 + ja*8] = o;
    }
  }

  // ---- group B: e_v channels (fc 8..15) -> parked image, both tiles ----
  #pragma unroll
  for (int f = 0; f < 8; ++f){ a0[f] = (f32x4){0.f,0.f,0.f,0.f}; a1[f] = (f32x4){0.f,0.f,0.f,0.f}; }
  #pragma unroll
  for (int ks = 0; ks < 4; ++ks){
    #pragma unroll
    for (int mf = 0; mf < 8; ++mf){
      short8 wv = *(const short8*)&WeF[(size_t)(((8+mf)*4 + ks)*64 + l)*8];
      a0[mf] = __builtin_amdgcn_mfma_f32_16x16x32_bf16(wv, afr0[ks], a0[mf], 0, 0, 0);
      a1[mf] = __builtin_amdgcn_mfma_f32_16x16x32_bf16(wv, afr1[ks], a1[mf], 0, 0, 0);
    }
  }
  #pragma unroll
  for (int tile = 0; tile < 2; ++tile){
    const f32x4* ac = tile ? a1 : a0;
    const int jl = w*32 + tile*16 + lr;
    #pragma unroll
    for (int mf = 0; mf < 8; ++mf){
      const int c = mf*16 + kg*4;            // c within [0,128) of the e_v half
      float4 bev = *(const float4*)&be[128 + c];
      float e[4];
      #pragma unroll
      for (int r = 0; r < 4; ++r){
        float y = ac[mf][r] + (&bev.x)[r]; e[r] = y > 0.f ? y : 0.01f*y;
      }
      uint2 pk; pk.x = packbf(e[0], e[1]); pk.y = packbf(e[2], e[3]);
      const int g = c >> 3;
      *(uint2*)&Evp[jl*128 + ((g ^ (jl & 7)) << 3) + (kg & 1)*4] = pk;
    }
  }
  // copy own 32 rows (8 KB) into the parked image (one 64-chunk per wave)
  {
    uint4* dst = (uint4*)evG + ((size_t)bi*6 + ch*2 + (w >> 1))*1024 + (w & 1)*512;
    const uint4* E4 = (const uint4*)Evp + w*512;
    #pragma unroll
    for (int q = 0; q < 8; ++q) dst[l + q*64] = E4[l + q*64];
  }
}

// ---------------- K2: softmax over j, probs bf16 in place ----------------
__global__ __launch_bounds__(512) void k2_softmax(u16* __restrict__ attL)
{
  __shared__ u16 sl[3072];
  const int t = threadIdx.x, bi = blockIdx.x;
  uint4* sl4 = (uint4*)sl;
  if (t < 384) sl4[t] = ((const uint4*)(attL + (size_t)bi*3072))[t];
  __syncthreads();
  const int h = t >> 6, lane = t & 63;
  float v[6]; float m = -FLT_MAX;
  #pragma unroll
  for (int q = 0; q < 6; ++q){ v[q] = bf2f(sl[(lane + q*64)*8 + h]); m = fmaxf(m, v[q]); }
  #pragma unroll
  for (int o = 32; o >= 1; o >>= 1) m = fmaxf(m, __shfl_xor(m, o));
  float s = 0.f;
  #pragma unroll
  for (int q = 0; q < 6; ++q){ v[q] = __expf(v[q] - m); s += v[q]; }
  #pragma unroll
  for (int o = 32; o >= 1; o >>= 1) s += __shfl_xor(s, o);
  const float inv = 1.f / s;
  #pragma unroll
  for (int q = 0; q < 6; ++q) sl[(lane + q*64)*8 + h] = (u16)f2bf(v[q] * inv);
  __syncthreads();
  if (t < 384) ((uint4*)(attL + (size_t)bi*3072))[t] = sl4[t];
}

// ---------------- K3s: barrier-free SWAPPED edge GEMM + c1 GEMM ----------------
__global__ __launch_bounds__(256, 4) void k3s_edge_c1(
    const float* __restrict__ bedge, const float* __restrict__ bc1,
    const float* __restrict__ Wc2, const u16* __restrict__ qkbf,
    const u16* __restrict__ WgF, const u16* __restrict__ W1F,
    const u16* __restrict__ attL, float* __restrict__ edge_out,
    float* __restrict__ cattB)
{
  const int t = threadIdx.x, ch = blockIdx.x, bi = blockIdx.y;
  const int b = (bi >= N_) ? 1 : 0;
  const int j0 = ch * 64;
  const int w = t >> 6, l = t & 63, lr = l & 15, kg = l >> 4;
  const int jloc = w*16 + lr;
  const int jglob = j0 + jloc;
  const u16* evS = (const u16*)edge_out + ((size_t)bi*6 + ch)*8192;

  f32x4 eacc[4], cacc[8];
  #pragma unroll
  for (int f = 0; f < 4; ++f) eacc[f] = (f32x4){0.f,0.f,0.f,0.f};
  #pragma unroll
  for (int f = 0; f < 8; ++f) cacc[f] = (f32x4){0.f,0.f,0.f,0.f};

  #pragma unroll
  for (int ks = 0; ks < 4; ++ks){
    const int k0 = ks*32 + kg*8;
    short8 ar = *(const short8*)&evS[swze(jloc, k0)];
    const float p = bf2f(attL[(size_t)bi*3072 + jglob*8 + (k0 >> 4)]);
    uint4 rvu = *(const uint4*)&qkbf[(size_t)(b*N_ + jglob)*512 + 384 + k0];
    uint4 lvu = *(const uint4*)&qkbf[(size_t)bi*512 + 256 + k0];
    short8 ame, amc;
    const u16* arp = (const u16*)&ar;
    const u16* rvp = (const u16*)&rvu;
    const u16* lvp = (const u16*)&lvu;
    u16* amep = (u16*)&ame; u16* amcp = (u16*)&amc;
    #pragma unroll
    for (int e = 0; e < 8; ++e){
      const float ef = bf2f(arp[e]) * p;
      amep[e] = (u16)f2bf(ef);
      amcp[e] = (u16)f2bf(ef * bf2f(lvp[e]) * bf2f(rvp[e]));
    }
    #pragma unroll
    for (int f = 0; f < 4; ++f){
      short8 wv = *(const short8*)&WgF[(size_t)((f*4 + ks)*64 + l)*8];
      eacc[f] = __builtin_amdgcn_mfma_f32_16x16x32_bf16(wv, ame, eacc[f], 0, 0, 0);
    }
    #pragma unroll
    for (int f = 0; f < 8; ++f){
      short8 wv = *(const short8*)&W1F[(size_t)((f*4 + ks)*64 + l)*8];
      cacc[f] = __builtin_amdgcn_mfma_f32_16x16x32_bf16(wv, amc, cacc[f], 0, 0, 0);
    }
  }
  // edge epilogue: D[g, j] -> lane j fixed, g = gf*16 + kg*4 + r -> float4 stores
  #pragma unroll
  for (int gf = 0; gf < 4; ++gf){
    const int g0 = gf*16 + kg*4;
    float4 bg = *(const float4*)&bedge[g0];
    float4 o;
    o.x = eacc[gf][0] + bg.x; o.y = eacc[gf][1] + bg.y;
    o.z = eacc[gf][2] + bg.z; o.w = eacc[gf][3] + bg.w;
    *(float4*)&edge_out[((size_t)bi*N_ + jglob)*64 + g0] = o;
  }
  // c1 epilogue: lane-local 32 terms + 2 shfl
  {
    float s = 0.f;
    #pragma unroll
    for (int cf = 0; cf < 8; ++cf){
      const int c0 = cf*16 + kg*4;
      float4 b1 = *(const float4*)&bc1[c0];
      float4 w2 = *(const float4*)&Wc2[c0];
      #pragma unroll
      for (int r = 0; r < 4; ++r){
        float y = cacc[cf][r] + (&b1.x)[r]; y = y > 0.f ? y : 0.01f*y;
        s += y * (&w2.x)[r];
      }
    }
    s += __shfl_xor(s, 16); s += __shfl_xor(s, 32);
    if (kg == 0) cattB[(size_t)bi*N_ + jglob] = s;
  }
}

// ---------------- K4: node einsum (vectorized) + W_node + coor finale ----------------
__global__ __launch_bounds__(256) void k4_node_coor(
    const float* __restrict__ coor, const float* __restrict__ Wnode,
    const float* __restrict__ bnode, const float* __restrict__ bc2,
    const int* __restrict__ emask, const int* __restrict__ fmask,
    const u16* __restrict__ qkbf, const u16* __restrict__ attL,
    const float* __restrict__ cattB, float* __restrict__ node_out,
    float* __restrict__ coor_out)
{
  __shared__ u16 pS[3072];
  __shared__ float part[8][256];
  __shared__ float red[256];
  __shared__ float halfb[256];
  __shared__ float cred[16];
  const int t = threadIdx.x, bi = blockIdx.x;
  const int b = (bi >= N_) ? 1 : 0;
  for (int idx = t; idx < 384; idx += 256)
    ((uint4*)pS)[idx] = ((const uint4*)(attL + (size_t)bi*3072))[idx];
  __syncthreads();
  // node pre: 32 chan-groups (uint4) x 8 j-groups of 48 j
  {
    const int q = t & 31, jg = t >> 5;
    const int ch0 = 256 + q*8;
    const int h = (q < 16) ? (q >> 1) : ((q - 16) >> 1);
    const int slot0 = (q < 16) ? (h*32 + (q & 1)*8) : (h*32 + 16 + (q & 1)*8);
    float a8[8];
    #pragma unroll
    for (int e = 0; e < 8; ++e) a8[e] = 0.f;
    for (int j = jg*48; j < jg*48 + 48; ++j){
      const float p = bf2f(pS[j*8 + h]);
      uint4 v = *(const uint4*)&qkbf[(size_t)(b*N_+j)*512 + ch0];
      const u16* vp = (const u16*)&v;
      #pragma unroll
      for (int e = 0; e < 8; ++e) a8[e] = fmaf(p, bf2f(vp[e]), a8[e]);
    }
    float4 o0 = {a8[0],a8[1],a8[2],a8[3]}, o1 = {a8[4],a8[5],a8[6],a8[7]};
    *(float4*)&part[jg][slot0]     = o0;
    *(float4*)&part[jg][slot0 + 4] = o1;
  }
  __syncthreads();
  {
    float s = 0.f;
    #pragma unroll
    for (int g = 0; g < 8; ++g) s += part[g][t];
    red[t] = s;
  }
  __syncthreads();
  {
    const int c = t & 127, qq = t >> 7;
    float s = 0.f;
    #pragma unroll 4
    for (int k = qq*128; k < qq*128 + 128; ++k)
      s = fmaf(red[k], Wnode[(size_t)k*128 + c], s);
    halfb[t] = s;
  }
  __syncthreads();
  if (t < 128)
    node_out[(size_t)bi*128 + t] = halfb[t] + halfb[128 + t] + bnode[t];

  // coor
  {
    const float cix = coor[bi*3], ciy = coor[bi*3+1], ciz = coor[bi*3+2];
    float vx=0.f, vy=0.f, vz=0.f, cnt=0.f;
    for (int j = t; j < N_; j += 256){
      if (emask[(size_t)bi*N_ + j]){
        cnt += 1.f;
        const float val = cattB[(size_t)bi*N_ + j] + bc2[0];
        const float dx = cix - coor[(size_t)(b*N_+j)*3+0];
        const float dy = ciy - coor[(size_t)(b*N_+j)*3+1];
        const float dz = ciz - coor[(size_t)(b*N_+j)*3+2];
        const float nrm = sqrtf(dx*dx + dy*dy + dz*dz);
        if (nrm > 0.f){
          const float qv = val / fmaxf(nrm, 1e-8f);
          vx += qv*dx; vy += qv*dy; vz += qv*dz;
        }
      }
    }
    #pragma unroll
    for (int o = 32; o >= 1; o >>= 1){
      vx += __shfl_xor(vx, o); vy += __shfl_xor(vy, o);
      vz += __shfl_xor(vz, o); cnt += __shfl_xor(cnt, o);
    }
    const int w = t >> 6, l = t & 63;
    if (l == 0){ cred[w*4]=vx; cred[w*4+1]=vy; cred[w*4+2]=vz; cred[w*4+3]=cnt; }
  }
  __syncthreads();
  if (t == 0){
    float sx=0.f, sy=0.f, sz=0.f, sc=0.f;
    #pragma unroll
    for (int ww = 0; ww < 4; ++ww){
      sx += cred[ww*4]; sy += cred[ww*4+1]; sz += cred[ww*4+2]; sc += cred[ww*4+3];
    }
    const float d = sc + 1e-7f, fm = (float)fmask[bi];
    coor_out[bi*3+0] = sx/d*fm;
    coor_out[bi*3+1] = sy/d*fm;
    coor_out[bi*3+2] = sz/d*fm;
  }
}

// =====================================================================
// ================= FALLBACK (R3 monolithic) PATH =====================
// =====================================================================

__global__ __launch_bounds__(512) void prep_wt(
    const float* __restrict__ We, const float* __restrict__ Wedge,
    const float* __restrict__ Wc1, u16* __restrict__ WeT,
    u16* __restrict__ WgT, u16* __restrict__ Wc1T)
{
  const int id = blockIdx.x*512 + threadIdx.x;
  const float* src; u16* dst; int c, g, stride;
  if (id < 4096){        int q = id;      c = q>>4; g = q&15; src = We    + (size_t)g*8*256 + c; stride = 256; dst = WeT  + c*128 + ((g ^ (c&7))<<3); }
  else if (id < 5120){   int q = id-4096; c = q>>4; g = q&15; src = Wedge + (size_t)g*8*64  + c; stride = 64;  dst = WgT  + c*128 + ((g ^ (c&7))<<3); }
  else if (id < 7168){   int q = id-5120; c = q>>4; g = q&15; src = Wc1   + (size_t)g*8*128 + c; stride = 128; dst = Wc1T + c*128 + ((g ^ (c&7))<<3); }
  else return;
  float f[8];
  #pragma unroll
  for (int e = 0; e < 8; ++e) f[e] = src[(size_t)e*stride];
  *(uint4*)dst = pack8(f);
}

#define L_ATT   0
#define L_AS    12288
#define L_WE    45056
#define L_WG    45056
#define L_W1    61440
#define L_PART  94208
#define L_EVP   110592
#define L_CATT  110592
#define L_RED2  113664
#define L_MISC  126976
#define L_QIF   127488
#define L_TOTAL 129536

__global__ __launch_bounds__(512, 1) void se3_fused(
    const float* __restrict__ coor, const float* __restrict__ edge_attr,
    const float* __restrict__ be, const float* __restrict__ bedge,
    const float* __restrict__ Wnode, const float* __restrict__ bnode,
    const float* __restrict__ bc1, const float* __restrict__ Wc2,
    const float* __restrict__ bc2, const int* __restrict__ emask,
    const int* __restrict__ fmask, const u16* __restrict__ qkbf,
    const u16* __restrict__ WeTg, const u16* __restrict__ WgTg,
    const u16* __restrict__ Wc1Tg,
    float* __restrict__ node_out, float* __restrict__ edge_out, float* __restrict__ coor_out)
{
  extern __shared__ char smem[];
  float* att  = (float*)(smem + L_ATT);
  float* qif  = (float*)(smem + L_QIF);
  float* misc = (float*)(smem + L_MISC);

  const int t  = threadIdx.x;
  const int bi = blockIdx.x;
  const int b  = (bi >= N_) ? 1 : 0;
  const float cix = coor[bi*3], ciy = coor[bi*3+1], ciz = coor[bi*3+2];

  const int w  = t >> 6, l = t & 63;
  const int chh = w >> 2, jsb = (w & 3) * 16;
  const int lr = l & 15, kg = l >> 4;

  for (int idx = t; idx < 4096; idx += 512)
    ((uint4*)(smem + L_WE))[idx] = ((const uint4*)WeTg)[idx];
  qif[t] = bf2f(qkbf[(size_t)bi*512 + t]);
  __syncthreads();

  float bevf[8], lmvf[8];
  #pragma unroll
  for (int f = 0; f < 8; ++f){
    const int c = chh*128 + f*16 + lr;
    bevf[f] = be[c];
    lmvf[f] = (chh == 0) ? qif[c] : 0.f;
  }

  float4 pa0, pb0, pa1, pb1;
  const int gq = t & 15, rq = t >> 4;
  auto issue_ea = [&](int j0){
    if (gq < 8){
      const float* s0 = &edge_attr[((size_t)bi*N_ + j0 + rq)*64 + gq*8];
      const float* s1 = &edge_attr[((size_t)bi*N_ + j0 + rq + 32)*64 + gq*8];
      pa0 = *(const float4*)s0; pb0 = *(const float4*)(s0 + 4);
      pa1 = *(const float4*)s1; pb1 = *(const float4*)(s1 + 4);
    }
  };

  uint4* evg = (uint4*)(edge_out + (size_t)bi*24576);

  issue_ea(0);
  for (int ch = 0; ch < 6; ++ch){
    const int j0 = ch * 64;
    {
      u16* As = (u16*)(smem + L_AS + (ch & 1)*16384);
      #pragma unroll
      for (int q = 0; q < 2; ++q){
        const int row = rq + q*32;
        const int j = j0 + row;
        float f[8];
        if (gq < 8){
          float4 A = q ? pa1 : pa0, Bv = q ? pb1 : pb0;
          f[0]=A.x; f[1]=A.y; f[2]=A.z; f[3]=A.w;
          f[4]=Bv.x; f[5]=Bv.y; f[6]=Bv.z; f[7]=Bv.w;
        } else {
          const float dx = cix - coor[(size_t)(b*N_+j)*3+0];
          const float dy = ciy - coor[(size_t)(b*N_+j)*3+1];
          const float dz = ciz - coor[(size_t)(b*N_+j)*3+2];
          const float dm = fminf(sqrtf(dx*dx + dy*dy + dz*dz), 2.0f);
          const int k0 = (gq - 8)*8;
          #pragma unroll
          for (int e = 0; e < 8; ++e){
            const float dd = dm - (float)(k0+e)*(2.0f/63.0f);
            f[e] = __expf(-496.125f * dd * dd);
          }
        }
        ((uint4*)As)[row*16 + (gq ^ (row & 7))] = pack8(f);
      }
    }
    __syncthreads();
    if (ch + 1 < 6) issue_ea((ch+1)*64);

    f32x4 acc[8];
    #pragma unroll
    for (int f = 0; f < 8; ++f) acc[f] = (f32x4){0.f,0.f,0.f,0.f};
    {
      u16* As  = (u16*)(smem + L_AS + (ch & 1)*16384);
      u16* WeL = (u16*)(smem + L_WE);
      #pragma unroll
      for (int ks = 0; ks < 4; ++ks){
        const int k0 = ks*32 + kg*8;
        short8 a = *(const short8*)&As[swze(jsb + lr, k0)];
        #pragma unroll
        for (int f = 0; f < 8; ++f){
          const int c = chh*128 + f*16 + lr;
          short8 bb = *(const short8*)&WeL[swze(c, k0)];
          acc[f] = __builtin_amdgcn_mfma_f32_16x16x32_bf16(a, bb, acc[f], 0, 0, 0);
        }
      }
    }
    if (chh == 0){
      #pragma unroll
      for (int f = 0; f < 8; ++f){
        #pragma unroll
        for (int r = 0; r < 4; ++r){
          const int j = j0 + jsb + kg*4 + r;
          float e = acc[f][r] + bevf[f]; e = e > 0.f ? e : 0.01f*e;
          const float rm = bf2f(qkbf[(size_t)(b*N_+j)*512 + 128 + f*16 + lr]);
          float s = lmvf[f] * rm * e;
          s += __shfl_xor(s, 1); s += __shfl_xor(s, 2);
          s += __shfl_xor(s, 4); s += __shfl_xor(s, 8);
          if (lr == 0)
            att[j*8 + f] = emask[(size_t)bi*N_ + j] ? s*0.25f : -FLT_MAX;
        }
      }
    } else {
      u16* Evp = (u16*)(smem + L_EVP);
      #pragma unroll
      for (int f = 0; f < 8; ++f){
        #pragma unroll
        for (int r = 0; r < 4; ++r){
          float e = acc[f][r] + bevf[f]; e = e > 0.f ? e : 0.01f*e;
          const float pr = __shfl_xor(e, 1);
          if (!(lr & 1)){
            const int jl = jsb + kg*4 + r;
            const int cv = f*16 + lr;
            *(u32*)&Evp[jl*128 + (((cv>>3) ^ (jl&7))<<3) + (cv&7)] = packbf(e, pr);
          }
        }
      }
    }
    __syncthreads();
    {
      const uint4* Evp4 = (const uint4*)(smem + L_EVP);
      #pragma unroll
      for (int q = 0; q < 2; ++q)
        evg[ch*1024 + t + q*512] = Evp4[t + q*512];
    }
  }

  {
    const int h = w, lane = l;
    float m = -FLT_MAX;
    #pragma unroll
    for (int q = 0; q < 6; ++q) m = fmaxf(m, att[(lane + q*64)*8 + h]);
    #pragma unroll
    for (int o = 32; o >= 1; o >>= 1) m = fmaxf(m, __shfl_xor(m, o));
    float pv[6], s = 0.f;
    #pragma unroll
    for (int q = 0; q < 6; ++q){ float p = __expf(att[(lane + q*64)*8 + h] - m); pv[q] = p; s += p; }
    #pragma unroll
    for (int o = 32; o >= 1; o >>= 1) s += __shfl_xor(s, o);
    const float inv = 1.f / s;
    #pragma unroll
    for (int q = 0; q < 6; ++q) att[(lane + q*64)*8 + h] = pv[q] * inv;
  }

  for (int idx = t; idx < 1024; idx += 512)
    ((uint4*)(smem + L_WG))[idx] = ((const uint4*)WgTg)[idx];
  for (int idx = t; idx < 2048; idx += 512){
    const int c = idx >> 4, g = idx & 15;
    uint4 u = ((const uint4*)Wc1Tg)[idx];
    const int k0 = ((g ^ (c & 7)) << 3);
    float f[8]; unpack8(u, f);
    #pragma unroll
    for (int e = 0; e < 8; ++e) f[e] *= qif[256 + k0 + e];
    ((uint4*)(smem + L_W1))[idx] = pack8(f);
  }

  float bgv[2], bc1v[4], w2v[4];
  #pragma unroll
  for (int f = 0; f < 2; ++f) bgv[f] = bedge[chh*32 + f*16 + lr];
  #pragma unroll
  for (int f = 0; f < 4; ++f){
    const int c2 = chh*64 + f*16 + lr;
    bc1v[f] = bc1[c2]; w2v[f] = Wc2[c2];
  }

  uint4 eva, evb;
  auto issue_ev = [&](int ch){
    eva = evg[ch*1024 + t];
    evb = evg[ch*1024 + t + 512];
  };
  issue_ev(0);
  __syncthreads();

  float* catt = (float*)(smem + L_CATT);

  for (int ch = 0; ch < 6; ++ch){
    const int j0 = ch * 64;
    {
      uint4* Ev4 = (uint4*)(smem + L_AS + (ch & 1)*16384);
      Ev4[t] = eva; Ev4[t + 512] = evb;
    }
    if (ch + 1 < 6) issue_ev(ch + 1);
    __syncthreads();

    u16* Ev  = (u16*)(smem + L_AS + (ch & 1)*16384);
    u16* WgL = (u16*)(smem + L_WG);
    u16* W1L = (u16*)(smem + L_W1);
    const int jrow = j0 + jsb + lr;

    f32x4 eacc[2], cacc[4];
    eacc[0] = (f32x4){0.f,0.f,0.f,0.f}; eacc[1] = (f32x4){0.f,0.f,0.f,0.f};
    #pragma unroll
    for (int f = 0; f < 4; ++f) cacc[f] = (f32x4){0.f,0.f,0.f,0.f};

    #pragma unroll
    for (int ks = 0; ks < 4; ++ks){
      const int k0 = ks*32 + kg*8;
      short8 ar = *(const short8*)&Ev[swze(jsb + lr, k0)];
      const float p = att[jrow*8 + (k0 >> 4)];
      uint4 rvu = *(const uint4*)&qkbf[(size_t)(b*N_+jrow)*512 + 384 + k0];
      short8 ame, amc;
      const u16* arp = (const u16*)&ar; const u16* rvp = (const u16*)&rvu;
      u16* amep = (u16*)&ame; u16* amcp = (u16*)&amc;
      #pragma unroll
      for (int e = 0; e < 8; ++e){
        const float ef = bf2f(arp[e]) * p;
        amep[e] = (u16)f2bf(ef);
        amcp[e] = (u16)f2bf(ef * bf2f(rvp[e]));
      }
      #pragma unroll
      for (int f = 0; f < 2; ++f){
        short8 bb = *(const short8*)&WgL[swze(chh*32 + f*16 + lr, k0)];
        eacc[f] = __builtin_amdgcn_mfma_f32_16x16x32_bf16(ame, bb, eacc[f], 0, 0, 0);
      }
      #pragma unroll
      for (int f = 0; f < 4; ++f){
        short8 bb = *(const short8*)&W1L[swze(chh*64 + f*16 + lr, k0)];
        cacc[f] = __builtin_amdgcn_mfma_f32_16x16x32_bf16(amc, bb, cacc[f], 0, 0, 0);
      }
    }
    #pragma unroll
    for (int f = 0; f < 2; ++f){
      const int g = chh*32 + f*16 + lr;
      #pragma unroll
      for (int r = 0; r < 4; ++r){
        const int j = j0 + jsb + kg*4 + r;
        edge_out[((size_t)bi*N_ + j)*64 + g] = eacc[f][r] + bgv[f];
      }
    }
    {
      float sr[4] = {0.f,0.f,0.f,0.f};
      #pragma unroll
      for (int f = 0; f < 4; ++f){
        #pragma unroll
        for (int r = 0; r < 4; ++r){
          float y = cacc[f][r] + bc1v[f]; y = y > 0.f ? y : 0.01f*y;
          sr[r] += y * w2v[f];
        }
      }
      #pragma unroll
      for (int r = 0; r < 4; ++r){
        float s = sr[r];
        s += __shfl_xor(s, 1); s += __shfl_xor(s, 2);
        s += __shfl_xor(s, 4); s += __shfl_xor(s, 8);
        if (lr == 0) catt[chh*N_ + j0 + jsb + kg*4 + r] = s;
      }
    }
  }
  __syncthreads();

  {
    float vx = 0.f, vy = 0.f, vz = 0.f, cnt = 0.f;
    if (t < N_){
      const int j = t;
      const int mk = emask[(size_t)bi*N_ + j];
      cnt = (mk != 0) ? 1.f : 0.f;
      if (mk){
        const float val = catt[j] + catt[N_ + j] + bc2[0];
        const float dx = cix - coor[(size_t)(b*N_+j)*3+0];
        const float dy = ciy - coor[(size_t)(b*N_+j)*3+1];
        const float dz = ciz - coor[(size_t)(b*N_+j)*3+2];
        const float nrm = sqrtf(dx*dx + dy*dy + dz*dz);
        if (nrm > 0.f){
          const float qq = val / fmaxf(nrm, 1e-8f);
          vx = qq*dx; vy = qq*dy; vz = qq*dz;
        }
      }
    }
    #pragma unroll
    for (int o = 32; o >= 1; o >>= 1){
      vx += __shfl_xor(vx, o); vy += __shfl_xor(vy, o);
      vz += __shfl_xor(vz, o); cnt += __shfl_xor(cnt, o);
    }
    if (l == 0){
      float* wr = misc + 16 + w*4;
      wr[0] = vx; wr[1] = vy; wr[2] = vz; wr[3] = cnt;
    }
  }
  __syncthreads();
  if (t == 0){
    float sx=0.f, sy=0.f, sz=0.f, sc=0.f;
    #pragma unroll
    for (int ww = 0; ww < 8; ++ww){
      sx += misc[16+ww*4]; sy += misc[16+ww*4+1];
      sz += misc[16+ww*4+2]; sc += misc[16+ww*4+3];
    }
    const float d = sc + 1e-7f, fm = (float)fmask[bi];
    coor_out[bi*3+0] = sx/d*fm; coor_out[bi*3+1] = sy/d*fm; coor_out[bi*3+2] = sz/d*fm;
  }

  {
    float* part = (float*)(smem + L_PART);
    const int c8 = t & 31, jg = t >> 5;
    const int ch0 = 256 + c8*8;
    const int h = (c8 < 16) ? (c8 >> 1) : ((c8 - 16) >> 1);
    const int slot0 = (c8 < 16) ? (h*32 + (c8 & 1)*8) : (h*32 + 16 + (c8 & 1)*8);
    float a8[8];
    #pragma unroll
    for (int e = 0; e < 8; ++e) a8[e] = 0.f;
    for (int q = 0; q < 24; ++q){
      const int j = jg*24 + q;
      const float p = att[j*8 + h];
      uint4 v = *(const uint4*)&qkbf[(size_t)(b*N_+j)*512 + ch0];
      const u16* vp = (const u16*)&v;
      #pragma unroll
      for (int e = 0; e < 8; ++e) a8[e] = fmaf(p, bf2f(vp[e]), a8[e]);
    }
    float4 o0 = {a8[0],a8[1],a8[2],a8[3]}, o1 = {a8[4],a8[5],a8[6],a8[7]};
    *(float4*)&part[jg*256 + slot0]     = o0;
    *(float4*)&part[jg*256 + slot0 + 4] = o1;
  }
  __syncthreads();
  {
    float* part = (float*)(smem + L_PART);
    float* red2 = (float*)(smem + L_RED2);
    if (t < 256){
      float s = 0.f;
      #pragma unroll
      for (int g = 0; g < 16; ++g) s += part[g*256 + t];
      red2[t] = s;
    }
  }
  __syncthreads();
  {
    float* part = (float*)(smem + L_PART);
    float* red2 = (float*)(smem + L_RED2);
    const int c = t & 127, qq = t >> 7;
    float s = 0.f;
    #pragma unroll 4
    for (int k = qq*64; k < qq*64 + 64; ++k)
      s = fmaf(red2[k], Wnode[(size_t)k*128 + c], s);
    part[qq*128 + c] = s;
    __syncthreads();
    if (t < 128)
      node_out[(size_t)bi*128 + t] = part[t] + part[128+t] + part[256+t] + part[384+t] + bnode[t];
  }
}

extern "C" void kernel_launch(void* const* d_in, const int* in_sizes, int n_in,
                              void* d_out, int out_size, void* d_ws, size_t ws_size,
                              hipStream_t stream)
{
  const float* x     = (const float*)d_in[0];
  const float* coor  = (const float*)d_in[1];
  const float* eattr = (const float*)d_in[2];
  const float* Wqk   = (const float*)d_in[3];
  const float* bqk   = (const float*)d_in[4];
  const float* We    = (const float*)d_in[5];
  const float* be    = (const float*)d_in[6];
  const float* Wnode = (const float*)d_in[7];
  const float* bnode = (const float*)d_in[8];
  const float* Wedge = (const float*)d_in[9];
  const float* bedge = (const float*)d_in[10];
  const float* Wc1   = (const float*)d_in[11];
  const float* bc1   = (const float*)d_in[12];
  const float* Wc2   = (const float*)d_in[13];
  const float* bc2   = (const float*)d_in[14];
  const int*   emask = (const int*)d_in[15];
  const int*   fmask = (const int*)d_in[16];

  u16* qkbf = (u16*)d_ws;                         // 786432 B

  float* out      = (float*)d_out;
  float* node_out = out;                           // 2*384*128
  float* edge_out = out + 98304;                   // 2*384*384*64
  float* coor_out = out + 98304 + 18874368;        // 2*384*3

  const size_t NEED = 6799360;
  if (ws_size >= NEED){
    u16*   WeF   = (u16*)((char*)d_ws + 786432);   // 65536
    u16*   WgF   = (u16*)((char*)d_ws + 851968);   // 16384
    u16*   W1F   = (u16*)((char*)d_ws + 868352);   // 32768
    u16*   attL  = (u16*)((char*)d_ws + 901120);   // 4718592
    float* cattB = (float*)((char*)d_ws + 5619712);// 1179648

    prep_frag<<<dim3(28), dim3(256), 0, stream>>>(We, Wedge, Wc1, WeF, WgF, W1F);
    qk_kernel<<<dim3(192), dim3(256), 0, stream>>>(x, Wqk, bqk, qkbf);
    k1d_logits_ev<<<dim3(3, NB), dim3(256), 0, stream>>>(
        coor, eattr, be, emask, qkbf, WeF, attL, (u16*)edge_out);
    k2_softmax<<<dim3(NB), dim3(512), 0, stream>>>(attL);
    k3s_edge_c1<<<dim3(6, NB), dim3(256), 0, stream>>>(
        bedge, bc1, Wc2, qkbf, WgF, W1F, attL, edge_out, cattB);
    k4_node_coor<<<dim3(NB), dim3(256), 0, stream>>>(
        coor, Wnode, bnode, bc2, emask, fmask, qkbf, attL, cattB, node_out, coor_out);
  } else {
    u16* WeT  = (u16*)((char*)d_ws + 786432);
    u16* WgT  = (u16*)((char*)d_ws + 851968);
    u16* Wc1T = (u16*)((char*)d_ws + 868352);
    prep_wt<<<dim3(14), dim3(512), 0, stream>>>(We, Wedge, Wc1, WeT, WgT, Wc1T);
    qk_kernel<<<dim3(192), dim3(256), 0, stream>>>(x, Wqk, bqk, qkbf);
    se3_fused<<<dim3(NB), dim3(512), L_TOTAL, stream>>>(
        coor, eattr, be, bedge, Wnode, bnode, bc1, Wc2, bc2,
        emask, fmask, qkbf, WeT, WgT, Wc1T, node_out, edge_out, coor_out);
  }
}

// Round 10
// 176.686 us; speedup vs baseline: 6.6290x; 1.1299x over previous
//
#include <hip/hip_runtime.h>
#include <stdint.h>
#include <float.h>

#define N_   384
#define NB   768
typedef unsigned short u16;
typedef unsigned int   u32;
typedef __attribute__((ext_vector_type(8))) short short8;   // 8 bf16 (4 VGPRs)
typedef __attribute__((ext_vector_type(4))) float f32x4;    // MFMA accumulator

__device__ __forceinline__ u32 f2bf(float x){
  union{float f; u32 u;} v; v.f = x;
  return (v.u + 0x7fffu + ((v.u >> 16) & 1u)) >> 16;   // RNE bf16
}
__device__ __forceinline__ float bf2f(u16 s){
  union{u32 u; float f;} v; v.u = ((u32)s) << 16; return v.f;
}
__device__ __forceinline__ u32 packbf(float a, float b){
  return f2bf(a) | (f2bf(b) << 16);
}
__device__ __forceinline__ uint4 pack8(const float* f){
  uint4 u;
  u.x = packbf(f[0],f[1]); u.y = packbf(f[2],f[3]);
  u.z = packbf(f[4],f[5]); u.w = packbf(f[6],f[7]);
  return u;
}
__device__ __forceinline__ void unpack8(uint4 u, float* f){
  u32 w[4] = {u.x, u.y, u.z, u.w};
  #pragma unroll
  for (int q = 0; q < 4; ++q){
    union{u32 u; float f;} lo, hi;
    lo.u = w[q] << 16; hi.u = w[q] & 0xffff0000u;
    f[2*q] = lo.f; f[2*q+1] = hi.f;
  }
}
// element index into a [rows][128] bf16 tile, 16B-granule XOR swizzle
__device__ __forceinline__ int swze(int row, int k){
  return row*128 + (((k >> 3) ^ (row & 7)) << 3) + (k & 7);
}

// ---------------- qk = x @ W_qk + b_qk  (bf16 out) ----------------
__global__ __launch_bounds__(256) void qk_kernel(
    const float* __restrict__ x, const float* __restrict__ Wqk,
    const float* __restrict__ bqk, u16* __restrict__ qkbf)
{
  __shared__ float xs[4][128];
  const int r0 = blockIdx.x * 4;
  const int t = threadIdx.x;
  for (int idx = t; idx < 512; idx += 256){
    int r = idx >> 7, k = idx & 127;
    xs[r][k] = x[(size_t)(r0 + r)*128 + k];
  }
  __syncthreads();
  float acc[4][2];
  #pragma unroll
  for (int r = 0; r < 4; ++r){ acc[r][0] = bqk[t]; acc[r][1] = bqk[t + 256]; }
  #pragma unroll 4
  for (int k = 0; k < 128; ++k){
    float w0 = Wqk[(size_t)k*512 + t], w1 = Wqk[(size_t)k*512 + t + 256];
    #pragma unroll
    for (int r = 0; r < 4; ++r){
      acc[r][0] = fmaf(xs[r][k], w0, acc[r][0]);
      acc[r][1] = fmaf(xs[r][k], w1, acc[r][1]);
    }
  }
  #pragma unroll
  for (int r = 0; r < 4; ++r){
    qkbf[(size_t)(r0+r)*512 + t]       = (u16)f2bf(acc[r][0]);
    qkbf[(size_t)(r0+r)*512 + t + 256] = (u16)f2bf(acc[r][1]);
  }
}

// =====================================================================
// ===================== PRIMARY (split) PATH ==========================
// =====================================================================

// fragment-major weight pack: frag (fc,ks): lane l holds W[k=ks*32+(l>>4)*8+e][c=fc*16+(l&15)]
__global__ __launch_bounds__(256) void prep_frag(
    const float* __restrict__ We, const float* __restrict__ Wedge,
    const float* __restrict__ Wc1, u16* __restrict__ WeF,
    u16* __restrict__ WgF, u16* __restrict__ W1F)
{
  const int id = blockIdx.x*256 + threadIdx.x;   // 28 blocks * 256 = 7168 = 112 frags * 64
  const int frag = id >> 6, lane = id & 63;
  if (frag >= 112) return;
  const float* src; u16* dst; int C, fc, ks;
  if (frag < 64){       fc = frag >> 2;      ks = frag & 3; src = We;    C = 256; dst = WeF + (size_t)frag*512; }
  else if (frag < 80){  int fr = frag - 64; fc = fr >> 2;   ks = fr & 3; src = Wedge; C = 64;  dst = WgF + (size_t)fr*512; }
  else {                int fr = frag - 80; fc = fr >> 2;   ks = fr & 3; src = Wc1;   C = 128; dst = W1F + (size_t)fr*512; }
  const int c = fc*16 + (lane & 15);
  const int kb = ks*32 + (lane >> 4)*8;
  float f[8];
  #pragma unroll
  for (int e = 0; e < 8; ++e) f[e] = src[(size_t)(kb + e)*C + c];
  *(uint4*)(dst + lane*8) = pack8(f);
}

// ---------------- K1L: dual-tile swapped e-GEMM, weights in LDS ----------------
// WeF (64 KB) staged once per block -> conflict-free linear ds_read_b128.
// One wave owns TWO 16-j tiles (32 j); e_v written DIRECTLY to the parked
// global image (swizzled), no Evp LDS. mfma(W,A) -> D[c,j]: lane j = l&15,
// c = fc*16 + (l>>4)*4 + r.
__global__ __launch_bounds__(256, 2) void k1L_logits_ev(
    const float* __restrict__ coor, const float* __restrict__ edge_attr,
    const float* __restrict__ be, const int* __restrict__ emask,
    const u16* __restrict__ qkbf, const u16* __restrict__ WeF,
    u16* __restrict__ attL, u16* __restrict__ evG)
{
  __shared__ u16 WeL[32768];   // 64 KB: 64 frags x 512 u16
  const int t = threadIdx.x;
  const int ch = blockIdx.x, bi = blockIdx.y;     // ch: 0..2 (128-j blocks)
  const int b = (bi >= N_) ? 1 : 0;
  const int w = t >> 6, l = t & 63, lr = l & 15, kg = l >> 4;
  const int jw = ch*128 + w*32;
  const int ja0 = jw + lr, ja1 = jw + 16 + lr;

  // ---- edge fragments for both tiles (lane: 16-idx = j, k = kg*8+e) ----
  short8 afr0[4], afr1[4];
  {
    const float cix = coor[bi*3], ciy = coor[bi*3+1], ciz = coor[bi*3+2];
    const float* s0 = &edge_attr[((size_t)bi*N_ + ja0)*64 + kg*8];
    const float* s1 = &edge_attr[((size_t)bi*N_ + ja1)*64 + kg*8];
    #pragma unroll
    for (int ks = 0; ks < 2; ++ks){
      float4 a  = *(const float4*)(s0 + ks*32);
      float4 c4 = *(const float4*)(s0 + ks*32 + 4);
      float f[8] = {a.x,a.y,a.z,a.w,c4.x,c4.y,c4.z,c4.w};
      *(uint4*)&afr0[ks] = pack8(f);
      a  = *(const float4*)(s1 + ks*32);
      c4 = *(const float4*)(s1 + ks*32 + 4);
      float g[8] = {a.x,a.y,a.z,a.w,c4.x,c4.y,c4.z,c4.w};
      *(uint4*)&afr1[ks] = pack8(g);
    }
    float dx = cix - coor[(size_t)(b*N_+ja0)*3+0];
    float dy = ciy - coor[(size_t)(b*N_+ja0)*3+1];
    float dz = ciz - coor[(size_t)(b*N_+ja0)*3+2];
    const float dm0 = fminf(sqrtf(dx*dx + dy*dy + dz*dz), 2.0f);
    dx = cix - coor[(size_t)(b*N_+ja1)*3+0];
    dy = ciy - coor[(size_t)(b*N_+ja1)*3+1];
    dz = ciz - coor[(size_t)(b*N_+ja1)*3+2];
    const float dm1 = fminf(sqrtf(dx*dx + dy*dy + dz*dz), 2.0f);
    #pragma unroll
    for (int ks = 2; ks < 4; ++ks){
      const int g0 = (ks-2)*32 + kg*8;
      float f[8], g[8];
      #pragma unroll
      for (int e = 0; e < 8; ++e){
        const float x0 = (float)(g0+e)*(2.0f/63.0f);
        const float d0 = dm0 - x0, d1 = dm1 - x0;
        f[e] = __expf(-496.125f * d0 * d0);   // coeff = -0.5/(2/63)^2
        g[e] = __expf(-496.125f * d1 * d1);
      }
      *(uint4*)&afr0[ks] = pack8(f);
      *(uint4*)&afr1[ks] = pack8(g);
    }
  }

  // ---- stage WeF into LDS (64 KB, coalesced; overlaps A-build loads) ----
  for (int idx = t; idx < 4096; idx += 256)
    ((uint4*)WeL)[idx] = ((const uint4*)WeF)[idx];
  __syncthreads();

  // ---- group A: e_m channels (fc 0..7) -> logits for both tiles ----
  f32x4 a0[8], a1[8];
  #pragma unroll
  for (int f = 0; f < 8; ++f){ a0[f] = (f32x4){0.f,0.f,0.f,0.f}; a1[f] = (f32x4){0.f,0.f,0.f,0.f}; }
  #pragma unroll
  for (int ks = 0; ks < 4; ++ks){
    #pragma unroll
    for (int mf = 0; mf < 8; ++mf){
      short8 wv = *(const short8*)&WeL[((mf*4 + ks)*64 + l)*8];
      a0[mf] = __builtin_amdgcn_mfma_f32_16x16x32_bf16(wv, afr0[ks], a0[mf], 0, 0, 0);
      a1[mf] = __builtin_amdgcn_mfma_f32_16x16x32_bf16(wv, afr1[ks], a1[mf], 0, 0, 0);
    }
  }
  #pragma unroll
  for (int tile = 0; tile < 2; ++tile){
    const int ja = tile ? ja1 : ja0;
    const f32x4* ac = tile ? a1 : a0;
    const int mk = emask[(size_t)bi*N_ + ja];
    float s8[8];
    #pragma unroll
    for (int mf = 0; mf < 8; ++mf){
      const int c = mf*16 + kg*4;
      uint2 lmu = *(const uint2*)&qkbf[(size_t)bi*512 + c];
      uint2 rmu = *(const uint2*)&qkbf[(size_t)(b*N_+ja)*512 + 128 + c];
      float4 bev = *(const float4*)&be[c];
      const u16* lmp = (const u16*)&lmu; const u16* rmp = (const u16*)&rmu;
      float s = 0.f;
      #pragma unroll
      for (int r = 0; r < 4; ++r){
        float e = ac[mf][r] + (&bev.x)[r]; e = e > 0.f ? e : 0.01f*e;
        s += e * bf2f(lmp[r]) * bf2f(rmp[r]);
      }
      s += __shfl_xor(s, 16); s += __shfl_xor(s, 32);
      s8[mf] = s * 0.25f;
    }
    if (kg == 0){
      const u32 NEG2 = packbf(-1e30f, -1e30f);
      uint4 o;
      o.x = mk ? packbf(s8[0], s8[1]) : NEG2;
      o.y = mk ? packbf(s8[2], s8[3]) : NEG2;
      o.z = mk ? packbf(s8[4], s8[5]) : NEG2;
      o.w = mk ? packbf(s8[6], s8[7]) : NEG2;
      *(uint4*)&attL[(size_t)bi*3072 + ja*8] = o;
    }
  }

  // ---- group B: e_v channels (fc 8..15) -> DIRECT swizzled global stores ----
  #pragma unroll
  for (int f = 0; f < 8; ++f){ a0[f] = (f32x4){0.f,0.f,0.f,0.f}; a1[f] = (f32x4){0.f,0.f,0.f,0.f}; }
  #pragma unroll
  for (int ks = 0; ks < 4; ++ks){
    #pragma unroll
    for (int mf = 0; mf < 8; ++mf){
      short8 wv = *(const short8*)&WeL[(((8+mf)*4 + ks)*64 + l)*8];
      a0[mf] = __builtin_amdgcn_mfma_f32_16x16x32_bf16(wv, afr0[ks], a0[mf], 0, 0, 0);
      a1[mf] = __builtin_amdgcn_mfma_f32_16x16x32_bf16(wv, afr1[ks], a1[mf], 0, 0, 0);
    }
  }
  #pragma unroll
  for (int tile = 0; tile < 2; ++tile){
    const f32x4* ac = tile ? a1 : a0;
    const int jl = w*32 + tile*16 + lr;          // 0..127 within block
    const int chunk = ch*2 + (jl >> 6);          // 64-j chunk index
    const int row = jl & 63;
    u16* dstb = evG + ((size_t)bi*6 + chunk)*8192 + row*128;
    #pragma unroll
    for (int mf = 0; mf < 8; ++mf){
      const int c = mf*16 + kg*4;                // c within [0,128) of the e_v half
      float4 bev = *(const float4*)&be[128 + c];
      float e[4];
      #pragma unroll
      for (int r = 0; r < 4; ++r){
        float y = ac[mf][r] + (&bev.x)[r]; e[r] = y > 0.f ? y : 0.01f*y;
      }
      uint2 pk; pk.x = packbf(e[0], e[1]); pk.y = packbf(e[2], e[3]);
      const int g = c >> 3;
      *(uint2*)&dstb[((g ^ (row & 7)) << 3) + (kg & 1)*4] = pk;
    }
  }
}

// ---------------- K2: softmax over j, probs bf16 in place ----------------
__global__ __launch_bounds__(512) void k2_softmax(u16* __restrict__ attL)
{
  __shared__ u16 sl[3072];
  const int t = threadIdx.x, bi = blockIdx.x;
  uint4* sl4 = (uint4*)sl;
  if (t < 384) sl4[t] = ((const uint4*)(attL + (size_t)bi*3072))[t];
  __syncthreads();
  const int h = t >> 6, lane = t & 63;
  float v[6]; float m = -FLT_MAX;
  #pragma unroll
  for (int q = 0; q < 6; ++q){ v[q] = bf2f(sl[(lane + q*64)*8 + h]); m = fmaxf(m, v[q]); }
  #pragma unroll
  for (int o = 32; o >= 1; o >>= 1) m = fmaxf(m, __shfl_xor(m, o));
  float s = 0.f;
  #pragma unroll
  for (int q = 0; q < 6; ++q){ v[q] = __expf(v[q] - m); s += v[q]; }
  #pragma unroll
  for (int o = 32; o >= 1; o >>= 1) s += __shfl_xor(s, o);
  const float inv = 1.f / s;
  #pragma unroll
  for (int q = 0; q < 6; ++q) sl[(lane + q*64)*8 + h] = (u16)f2bf(v[q] * inv);
  __syncthreads();
  if (t < 384) ((uint4*)(attL + (size_t)bi*3072))[t] = sl4[t];
}

// ---------------- K3L: swapped edge+c1 GEMM, weights in LDS ----------------
__global__ __launch_bounds__(256, 3) void k3L_edge_c1(
    const float* __restrict__ bedge, const float* __restrict__ bc1,
    const float* __restrict__ Wc2, const u16* __restrict__ qkbf,
    const u16* __restrict__ WgF, const u16* __restrict__ W1F,
    const u16* __restrict__ attL, float* __restrict__ edge_out,
    float* __restrict__ cattB)
{
  __shared__ u16 WL[24576];   // 48 KB: Wg 16 frags (8192 u16) + W1 32 frags (16384 u16)
  const int t = threadIdx.x, ch = blockIdx.x, bi = blockIdx.y;
  const int b = (bi >= N_) ? 1 : 0;
  const int j0 = ch * 64;
  const int w = t >> 6, l = t & 63, lr = l & 15, kg = l >> 4;
  const int jloc = w*16 + lr;
  const int jglob = j0 + jloc;
  const u16* evS = (const u16*)edge_out + ((size_t)bi*6 + ch)*8192;

  for (int idx = t; idx < 3072; idx += 256)
    ((uint4*)WL)[idx] = (idx < 1024) ? ((const uint4*)WgF)[idx]
                                     : ((const uint4*)W1F)[idx - 1024];
  __syncthreads();
  const u16* WgL = WL;
  const u16* W1L = WL + 8192;

  f32x4 eacc[4], cacc[8];
  #pragma unroll
  for (int f = 0; f < 4; ++f) eacc[f] = (f32x4){0.f,0.f,0.f,0.f};
  #pragma unroll
  for (int f = 0; f < 8; ++f) cacc[f] = (f32x4){0.f,0.f,0.f,0.f};

  #pragma unroll
  for (int ks = 0; ks < 4; ++ks){
    const int k0 = ks*32 + kg*8;
    short8 ar = *(const short8*)&evS[swze(jloc, k0)];
    const float p = bf2f(attL[(size_t)bi*3072 + jglob*8 + (k0 >> 4)]);
    uint4 rvu = *(const uint4*)&qkbf[(size_t)(b*N_ + jglob)*512 + 384 + k0];
    uint4 lvu = *(const uint4*)&qkbf[(size_t)bi*512 + 256 + k0];
    short8 ame, amc;
    const u16* arp = (const u16*)&ar;
    const u16* rvp = (const u16*)&rvu;
    const u16* lvp = (const u16*)&lvu;
    u16* amep = (u16*)&ame; u16* amcp = (u16*)&amc;
    #pragma unroll
    for (int e = 0; e < 8; ++e){
      const float ef = bf2f(arp[e]) * p;
      amep[e] = (u16)f2bf(ef);
      amcp[e] = (u16)f2bf(ef * bf2f(lvp[e]) * bf2f(rvp[e]));
    }
    #pragma unroll
    for (int f = 0; f < 4; ++f){
      short8 wv = *(const short8*)&WgL[((f*4 + ks)*64 + l)*8];
      eacc[f] = __builtin_amdgcn_mfma_f32_16x16x32_bf16(wv, ame, eacc[f], 0, 0, 0);
    }
    #pragma unroll
    for (int f = 0; f < 8; ++f){
      short8 wv = *(const short8*)&W1L[((f*4 + ks)*64 + l)*8];
      cacc[f] = __builtin_amdgcn_mfma_f32_16x16x32_bf16(wv, amc, cacc[f], 0, 0, 0);
    }
  }
  // edge epilogue: D[g, j] -> lane j fixed, g = gf*16 + kg*4 + r -> float4 stores
  #pragma unroll
  for (int gf = 0; gf < 4; ++gf){
    const int g0 = gf*16 + kg*4;
    float4 bg = *(const float4*)&bedge[g0];
    float4 o;
    o.x = eacc[gf][0] + bg.x; o.y = eacc[gf][1] + bg.y;
    o.z = eacc[gf][2] + bg.z; o.w = eacc[gf][3] + bg.w;
    *(float4*)&edge_out[((size_t)bi*N_ + jglob)*64 + g0] = o;
  }
  // c1 epilogue: lane-local 32 terms + 2 shfl
  {
    float s = 0.f;
    #pragma unroll
    for (int cf = 0; cf < 8; ++cf){
      const int c0 = cf*16 + kg*4;
      float4 b1 = *(const float4*)&bc1[c0];
      float4 w2 = *(const float4*)&Wc2[c0];
      #pragma unroll
      for (int r = 0; r < 4; ++r){
        float y = cacc[cf][r] + (&b1.x)[r]; y = y > 0.f ? y : 0.01f*y;
        s += y * (&w2.x)[r];
      }
    }
    s += __shfl_xor(s, 16); s += __shfl_xor(s, 32);
    if (kg == 0) cattB[(size_t)bi*N_ + jglob] = s;
  }
}

// ---------------- K4: node einsum (vectorized) + W_node + coor finale ----------------
__global__ __launch_bounds__(256) void k4_node_coor(
    const float* __restrict__ coor, const float* __restrict__ Wnode,
    const float* __restrict__ bnode, const float* __restrict__ bc2,
    const int* __restrict__ emask, const int* __restrict__ fmask,
    const u16* __restrict__ qkbf, const u16* __restrict__ attL,
    const float* __restrict__ cattB, float* __restrict__ node_out,
    float* __restrict__ coor_out)
{
  __shared__ u16 pS[3072];
  __shared__ float part[8][256];
  __shared__ float red[256];
  __shared__ float halfb[256];
  __shared__ float cred[16];
  const int t = threadIdx.x, bi = blockIdx.x;
  const int b = (bi >= N_) ? 1 : 0;
  for (int idx = t; idx < 384; idx += 256)
    ((uint4*)pS)[idx] = ((const uint4*)(attL + (size_t)bi*3072))[idx];
  __syncthreads();
  // node pre: 32 chan-groups (uint4) x 8 j-groups of 48 j
  {
    const int q = t & 31, jg = t >> 5;
    const int ch0 = 256 + q*8;
    const int h = (q < 16) ? (q >> 1) : ((q - 16) >> 1);
    const int slot0 = (q < 16) ? (h*32 + (q & 1)*8) : (h*32 + 16 + (q & 1)*8);
    float a8[8];
    #pragma unroll
    for (int e = 0; e < 8; ++e) a8[e] = 0.f;
    for (int j = jg*48; j < jg*48 + 48; ++j){
      const float p = bf2f(pS[j*8 + h]);
      uint4 v = *(const uint4*)&qkbf[(size_t)(b*N_+j)*512 + ch0];
      const u16* vp = (const u16*)&v;
      #pragma unroll
      for (int e = 0; e < 8; ++e) a8[e] = fmaf(p, bf2f(vp[e]), a8[e]);
    }
    float4 o0 = {a8[0],a8[1],a8[2],a8[3]}, o1 = {a8[4],a8[5],a8[6],a8[7]};
    *(float4*)&part[jg][slot0]     = o0;
    *(float4*)&part[jg][slot0 + 4] = o1;
  }
  __syncthreads();
  {
    float s = 0.f;
    #pragma unroll
    for (int g = 0; g < 8; ++g) s += part[g][t];
    red[t] = s;
  }
  __syncthreads();
  {
    const int c = t & 127, qq = t >> 7;
    float s = 0.f;
    #pragma unroll 4
    for (int k = qq*128; k < qq*128 + 128; ++k)
      s = fmaf(red[k], Wnode[(size_t)k*128 + c], s);
    halfb[t] = s;
  }
  __syncthreads();
  if (t < 128)
    node_out[(size_t)bi*128 + t] = halfb[t] + halfb[128 + t] + bnode[t];

  // coor
  {
    const float cix = coor[bi*3], ciy = coor[bi*3+1], ciz = coor[bi*3+2];
    float vx=0.f, vy=0.f, vz=0.f, cnt=0.f;
    for (int j = t; j < N_; j += 256){
      if (emask[(size_t)bi*N_ + j]){
        cnt += 1.f;
        const float val = cattB[(size_t)bi*N_ + j] + bc2[0];
        const float dx = cix - coor[(size_t)(b*N_+j)*3+0];
        const float dy = ciy - coor[(size_t)(b*N_+j)*3+1];
        const float dz = ciz - coor[(size_t)(b*N_+j)*3+2];
        const float nrm = sqrtf(dx*dx + dy*dy + dz*dz);
        if (nrm > 0.f){
          const float qv = val / fmaxf(nrm, 1e-8f);
          vx += qv*dx; vy += qv*dy; vz += qv*dz;
        }
      }
    }
    #pragma unroll
    for (int o = 32; o >= 1; o >>= 1){
      vx += __shfl_xor(vx, o); vy += __shfl_xor(vy, o);
      vz += __shfl_xor(vz, o); cnt += __shfl_xor(cnt, o);
    }
    const int w = t >> 6, l = t & 63;
    if (l == 0){ cred[w*4]=vx; cred[w*4+1]=vy; cred[w*4+2]=vz; cred[w*4+3]=cnt; }
  }
  __syncthreads();
  if (t == 0){
    float sx=0.f, sy=0.f, sz=0.f, sc=0.f;
    #pragma unroll
    for (int ww = 0; ww < 4; ++ww){
      sx += cred[ww*4]; sy += cred[ww*4+1]; sz += cred[ww*4+2]; sc += cred[ww*4+3];
    }
    const float d = sc + 1e-7f, fm = (float)fmask[bi];
    coor_out[bi*3+0] = sx/d*fm;
    coor_out[bi*3+1] = sy/d*fm;
    coor_out[bi*3+2] = sz/d*fm;
  }
}

// =====================================================================
// ================= FALLBACK (R3 monolithic) PATH =====================
// =====================================================================

__global__ __launch_bounds__(512) void prep_wt(
    const float* __restrict__ We, const float* __restrict__ Wedge,
    const float* __restrict__ Wc1, u16* __restrict__ WeT,
    u16* __restrict__ WgT, u16* __restrict__ Wc1T)
{
  const int id = blockIdx.x*512 + threadIdx.x;
  const float* src; u16* dst; int c, g, stride;
  if (id < 4096){        int q = id;      c = q>>4; g = q&15; src = We    + (size_t)g*8*256 + c; stride = 256; dst = WeT  + c*128 + ((g ^ (c&7))<<3); }
  else if (id < 5120){   int q = id-4096; c = q>>4; g = q&15; src = Wedge + (size_t)g*8*64  + c; stride = 64;  dst = WgT  + c*128 + ((g ^ (c&7))<<3); }
  else if (id < 7168){   int q = id-5120; c = q>>4; g = q&15; src = Wc1   + (size_t)g*8*128 + c; stride = 128; dst = Wc1T + c*128 + ((g ^ (c&7))<<3); }
  else return;
  float f[8];
  #pragma unroll
  for (int e = 0; e < 8; ++e) f[e] = src[(size_t)e*stride];
  *(uint4*)dst = pack8(f);
}

#define L_ATT   0
#define L_AS    12288
#define L_WE    45056
#define L_WG    45056
#define L_W1    61440
#define L_PART  94208
#define L_EVP   110592
#define L_CATT  110592
#define L_RED2  113664
#define L_MISC  126976
#define L_QIF   127488
#define L_TOTAL 129536

__global__ __launch_bounds__(512, 1) void se3_fused(
    const float* __restrict__ coor, const float* __restrict__ edge_attr,
    const float* __restrict__ be, const float* __restrict__ bedge,
    const float* __restrict__ Wnode, const float* __restrict__ bnode,
    const float* __restrict__ bc1, const float* __restrict__ Wc2,
    const float* __restrict__ bc2, const int* __restrict__ emask,
    const int* __restrict__ fmask, const u16* __restrict__ qkbf,
    const u16* __restrict__ WeTg, const u16* __restrict__ WgTg,
    const u16* __restrict__ Wc1Tg,
    float* __restrict__ node_out, float* __restrict__ edge_out, float* __restrict__ coor_out)
{
  extern __shared__ char smem[];
  float* att  = (float*)(smem + L_ATT);
  float* qif  = (float*)(smem + L_QIF);
  float* misc = (float*)(smem + L_MISC);

  const int t  = threadIdx.x;
  const int bi = blockIdx.x;
  const int b  = (bi >= N_) ? 1 : 0;
  const float cix = coor[bi*3], ciy = coor[bi*3+1], ciz = coor[bi*3+2];

  const int w  = t >> 6, l = t & 63;
  const int chh = w >> 2, jsb = (w & 3) * 16;
  const int lr = l & 15, kg = l >> 4;

  for (int idx = t; idx < 4096; idx += 512)
    ((uint4*)(smem + L_WE))[idx] = ((const uint4*)WeTg)[idx];
  qif[t] = bf2f(qkbf[(size_t)bi*512 + t]);
  __syncthreads();

  float bevf[8], lmvf[8];
  #pragma unroll
  for (int f = 0; f < 8; ++f){
    const int c = chh*128 + f*16 + lr;
    bevf[f] = be[c];
    lmvf[f] = (chh == 0) ? qif[c] : 0.f;
  }

  float4 pa0, pb0, pa1, pb1;
  const int gq = t & 15, rq = t >> 4;
  auto issue_ea = [&](int j0){
    if (gq < 8){
      const float* s0 = &edge_attr[((size_t)bi*N_ + j0 + rq)*64 + gq*8];
      const float* s1 = &edge_attr[((size_t)bi*N_ + j0 + rq + 32)*64 + gq*8];
      pa0 = *(const float4*)s0; pb0 = *(const float4*)(s0 + 4);
      pa1 = *(const float4*)s1; pb1 = *(const float4*)(s1 + 4);
    }
  };

  uint4* evg = (uint4*)(edge_out + (size_t)bi*24576);

  issue_ea(0);
  for (int ch = 0; ch < 6; ++ch){
    const int j0 = ch * 64;
    {
      u16* As = (u16*)(smem + L_AS + (ch & 1)*16384);
      #pragma unroll
      for (int q = 0; q < 2; ++q){
        const int row = rq + q*32;
        const int j = j0 + row;
        float f[8];
        if (gq < 8){
          float4 A = q ? pa1 : pa0, Bv = q ? pb1 : pb0;
          f[0]=A.x; f[1]=A.y; f[2]=A.z; f[3]=A.w;
          f[4]=Bv.x; f[5]=Bv.y; f[6]=Bv.z; f[7]=Bv.w;
        } else {
          const float dx = cix - coor[(size_t)(b*N_+j)*3+0];
          const float dy = ciy - coor[(size_t)(b*N_+j)*3+1];
          const float dz = ciz - coor[(size_t)(b*N_+j)*3+2];
          const float dm = fminf(sqrtf(dx*dx + dy*dy + dz*dz), 2.0f);
          const int k0 = (gq - 8)*8;
          #pragma unroll
          for (int e = 0; e < 8; ++e){
            const float dd = dm - (float)(k0+e)*(2.0f/63.0f);
            f[e] = __expf(-496.125f * dd * dd);
          }
        }
        ((uint4*)As)[row*16 + (gq ^ (row & 7))] = pack8(f);
      }
    }
    __syncthreads();
    if (ch + 1 < 6) issue_ea((ch+1)*64);

    f32x4 acc[8];
    #pragma unroll
    for (int f = 0; f < 8; ++f) acc[f] = (f32x4){0.f,0.f,0.f,0.f};
    {
      u16* As  = (u16*)(smem + L_AS + (ch & 1)*16384);
      u16* WeL = (u16*)(smem + L_WE);
      #pragma unroll
      for (int ks = 0; ks < 4; ++ks){
        const int k0 = ks*32 + kg*8;
        short8 a = *(const short8*)&As[swze(jsb + lr, k0)];
        #pragma unroll
        for (int f = 0; f < 8; ++f){
          const int c = chh*128 + f*16 + lr;
          short8 bb = *(const short8*)&WeL[swze(c, k0)];
          acc[f] = __builtin_amdgcn_mfma_f32_16x16x32_bf16(a, bb, acc[f], 0, 0, 0);
        }
      }
    }
    if (chh == 0){
      #pragma unroll
      for (int f = 0; f < 8; ++f){
        #pragma unroll
        for (int r = 0; r < 4; ++r){
          const int j = j0 + jsb + kg*4 + r;
          float e = acc[f][r] + bevf[f]; e = e > 0.f ? e : 0.01f*e;
          const float rm = bf2f(qkbf[(size_t)(b*N_+j)*512 + 128 + f*16 + lr]);
          float s = lmvf[f] * rm * e;
          s += __shfl_xor(s, 1); s += __shfl_xor(s, 2);
          s += __shfl_xor(s, 4); s += __shfl_xor(s, 8);
          if (lr == 0)
            att[j*8 + f] = emask[(size_t)bi*N_ + j] ? s*0.25f : -FLT_MAX;
        }
      }
    } else {
      u16* Evp = (u16*)(smem + L_EVP);
      #pragma unroll
      for (int f = 0; f < 8; ++f){
        #pragma unroll
        for (int r = 0; r < 4; ++r){
          float e = acc[f][r] + bevf[f]; e = e > 0.f ? e : 0.01f*e;
          const float pr = __shfl_xor(e, 1);
          if (!(lr & 1)){
            const int jl = jsb + kg*4 + r;
            const int cv = f*16 + lr;
            *(u32*)&Evp[jl*128 + (((cv>>3) ^ (jl&7))<<3) + (cv&7)] = packbf(e, pr);
          }
        }
      }
    }
    __syncthreads();
    {
      const uint4* Evp4 = (const uint4*)(smem + L_EVP);
      #pragma unroll
      for (int q = 0; q < 2; ++q)
        evg[ch*1024 + t + q*512] = Evp4[t + q*512];
    }
  }

  {
    const int h = w, lane = l;
    float m = -FLT_MAX;
    #pragma unroll
    for (int q = 0; q < 6; ++q) m = fmaxf(m, att[(lane + q*64)*8 + h]);
    #pragma unroll
    for (int o = 32; o >= 1; o >>= 1) m = fmaxf(m, __shfl_xor(m, o));
    float pv[6], s = 0.f;
    #pragma unroll
    for (int q = 0; q < 6; ++q){ float p = __expf(att[(lane + q*64)*8 + h] - m); pv[q] = p; s += p; }
    #pragma unroll
    for (int o = 32; o >= 1; o >>= 1) s += __shfl_xor(s, o);
    const float inv = 1.f / s;
    #pragma unroll
    for (int q = 0; q < 6; ++q) att[(lane + q*64)*8 + h] = pv[q] * inv;
  }

  for (int idx = t; idx < 1024; idx += 512)
    ((uint4*)(smem + L_WG))[idx] = ((const uint4*)WgTg)[idx];
  for (int idx = t; idx < 2048; idx += 512){
    const int c = idx >> 4, g = idx & 15;
    uint4 u = ((const uint4*)Wc1Tg)[idx];
    const int k0 = ((g ^ (c & 7)) << 3);
    float f[8]; unpack8(u, f);
    #pragma unroll
    for (int e = 0; e < 8; ++e) f[e] *= qif[256 + k0 + e];
    ((uint4*)(smem + L_W1))[idx] = pack8(f);
  }

  float bgv[2], bc1v[4], w2v[4];
  #pragma unroll
  for (int f = 0; f < 2; ++f) bgv[f] = bedge[chh*32 + f*16 + lr];
  #pragma unroll
  for (int f = 0; f < 4; ++f){
    const int c2 = chh*64 + f*16 + lr;
    bc1v[f] = bc1[c2]; w2v[f] = Wc2[c2];
  }

  uint4 eva, evb;
  auto issue_ev = [&](int ch){
    eva = evg[ch*1024 + t];
    evb = evg[ch*1024 + t + 512];
  };
  issue_ev(0);
  __syncthreads();

  float* catt = (float*)(smem + L_CATT);

  for (int ch = 0; ch < 6; ++ch){
    const int j0 = ch * 64;
    {
      uint4* Ev4 = (uint4*)(smem + L_AS + (ch & 1)*16384);
      Ev4[t] = eva; Ev4[t + 512] = evb;
    }
    if (ch + 1 < 6) issue_ev(ch + 1);
    __syncthreads();

    u16* Ev  = (u16*)(smem + L_AS + (ch & 1)*16384);
    u16* WgL = (u16*)(smem + L_WG);
    u16* W1L = (u16*)(smem + L_W1);
    const int jrow = j0 + jsb + lr;

    f32x4 eacc[2], cacc[4];
    eacc[0] = (f32x4){0.f,0.f,0.f,0.f}; eacc[1] = (f32x4){0.f,0.f,0.f,0.f};
    #pragma unroll
    for (int f = 0; f < 4; ++f) cacc[f] = (f32x4){0.f,0.f,0.f,0.f};

    #pragma unroll
    for (int ks = 0; ks < 4; ++ks){
      const int k0 = ks*32 + kg*8;
      short8 ar = *(const short8*)&Ev[swze(jsb + lr, k0)];
      const float p = att[jrow*8 + (k0 >> 4)];
      uint4 rvu = *(const uint4*)&qkbf[(size_t)(b*N_+jrow)*512 + 384 + k0];
      short8 ame, amc;
      const u16* arp = (const u16*)&ar; const u16* rvp = (const u16*)&rvu;
      u16* amep = (u16*)&ame; u16* amcp = (u16*)&amc;
      #pragma unroll
      for (int e = 0; e < 8; ++e){
        const float ef = bf2f(arp[e]) * p;
        amep[e] = (u16)f2bf(ef);
        amcp[e] = (u16)f2bf(ef * bf2f(rvp[e]));
      }
      #pragma unroll
      for (int f = 0; f < 2; ++f){
        short8 bb = *(const short8*)&WgL[swze(chh*32 + f*16 + lr, k0)];
        eacc[f] = __builtin_amdgcn_mfma_f32_16x16x32_bf16(ame, bb, eacc[f], 0, 0, 0);
      }
      #pragma unroll
      for (int f = 0; f < 4; ++f){
        short8 bb = *(const short8*)&W1L[swze(chh*64 + f*16 + lr, k0)];
        cacc[f] = __builtin_amdgcn_mfma_f32_16x16x32_bf16(amc, bb, cacc[f], 0, 0, 0);
      }
    }
    #pragma unroll
    for (int f = 0; f < 2; ++f){
      const int g = chh*32 + f*16 + lr;
      #pragma unroll
      for (int r = 0; r < 4; ++r){
        const int j = j0 + jsb + kg*4 + r;
        edge_out[((size_t)bi*N_ + j)*64 + g] = eacc[f][r] + bgv[f];
      }
    }
    {
      float sr[4] = {0.f,0.f,0.f,0.f};
      #pragma unroll
      for (int f = 0; f < 4; ++f){
        #pragma unroll
        for (int r = 0; r < 4; ++r){
          float y = cacc[f][r] + bc1v[f]; y = y > 0.f ? y : 0.01f*y;
          sr[r] += y * w2v[f];
        }
      }
      #pragma unroll
      for (int r = 0; r < 4; ++r){
        float s = sr[r];
        s += __shfl_xor(s, 1); s += __shfl_xor(s, 2);
        s += __shfl_xor(s, 4); s += __shfl_xor(s, 8);
        if (lr == 0) catt[chh*N_ + j0 + jsb + kg*4 + r] = s;
      }
    }
  }
  __syncthreads();

  {
    float vx = 0.f, vy = 0.f, vz = 0.f, cnt = 0.f;
    if (t < N_){
      const int j = t;
      const int mk = emask[(size_t)bi*N_ + j];
      cnt = (mk != 0) ? 1.f : 0.f;
      if (mk){
        const float val = catt[j] + catt[N_ + j] + bc2[0];
        const float dx = cix - coor[(size_t)(b*N_+j)*3+0];
        const float dy = ciy - coor[(size_t)(b*N_+j)*3+1];
        const float dz = ciz - coor[(size_t)(b*N_+j)*3+2];
        const float nrm = sqrtf(dx*dx + dy*dy + dz*dz);
        if (nrm > 0.f){
          const float qq = val / fmaxf(nrm, 1e-8f);
          vx = qq*dx; vy = qq*dy; vz = qq*dz;
        }
      }
    }
    #pragma unroll
    for (int o = 32; o >= 1; o >>= 1){
      vx += __shfl_xor(vx, o); vy += __shfl_xor(vy, o);
      vz += __shfl_xor(vz, o); cnt += __shfl_xor(cnt, o);
    }
    if (l == 0){
      float* wr = misc + 16 + w*4;
      wr[0] = vx; wr[1] = vy; wr[2] = vz; wr[3] = cnt;
    }
  }
  __syncthreads();
  if (t == 0){
    float sx=0.f, sy=0.f, sz=0.f, sc=0.f;
    #pragma unroll
    for (int ww = 0; ww < 8; ++ww){
      sx += misc[16+ww*4]; sy += misc[16+ww*4+1];
      sz += misc[16+ww*4+2]; sc += misc[16+ww*4+3];
    }
    const float d = sc + 1e-7f, fm = (float)fmask[bi];
    coor_out[bi*3+0] = sx/d*fm; coor_out[bi*3+1] = sy/d*fm; coor_out[bi*3+2] = sz/d*fm;
  }

  {
    float* part = (float*)(smem + L_PART);
    const int c8 = t & 31, jg = t >> 5;
    const int ch0 = 256 + c8*8;
    const int h = (c8 < 16) ? (c8 >> 1) : ((c8 - 16) >> 1);
    const int slot0 = (c8 < 16) ? (h*32 + (c8 & 1)*8) : (h*32 + 16 + (c8 & 1)*8);
    float a8[8];
    #pragma unroll
    for (int e = 0; e < 8; ++e) a8[e] = 0.f;
    for (int q = 0; q < 24; ++q){
      const int j = jg*24 + q;
      const float p = att[j*8 + h];
      uint4 v = *(const uint4*)&qkbf[(size_t)(b*N_+j)*512 + ch0];
      const u16* vp = (const u16*)&v;
      #pragma unroll
      for (int e = 0; e < 8; ++e) a8[e] = fmaf(p, bf2f(vp[e]), a8[e]);
    }
    float4 o0 = {a8[0],a8[1],a8[2],a8[3]}, o1 = {a8[4],a8[5],a8[6],a8[7]};
    *(float4*)&part[jg*256 + slot0]     = o0;
    *(float4*)&part[jg*256 + slot0 + 4] = o1;
  }
  __syncthreads();
  {
    float* part = (float*)(smem + L_PART);
    float* red2 = (float*)(smem + L_RED2);
    if (t < 256){
      float s = 0.f;
      #pragma unroll
      for (int g = 0; g < 16; ++g) s += part[g*256 + t];
      red2[t] = s;
    }
  }
  __syncthreads();
  {
    float* part = (float*)(smem + L_PART);
    float* red2 = (float*)(smem + L_RED2);
    const int c = t & 127, qq = t >> 7;
    float s = 0.f;
    #pragma unroll 4
    for (int k = qq*64; k < qq*64 + 64; ++k)
      s = fmaf(red2[k], Wnode[(size_t)k*128 + c], s);
    part[qq*128 + c] = s;
    __syncthreads();
    if (t < 128)
      node_out[(size_t)bi*128 + t] = part[t] + part[128+t] + part[256+t] + part[384+t] + bnode[t];
  }
}

extern "C" void kernel_launch(void* const* d_in, const int* in_sizes, int n_in,
                              void* d_out, int out_size, void* d_ws, size_t ws_size,
                              hipStream_t stream)
{
  const float* x     = (const float*)d_in[0];
  const float* coor  = (const float*)d_in[1];
  const float* eattr = (const float*)d_in[2];
  const float* Wqk   = (const float*)d_in[3];
  const float* bqk   = (const float*)d_in[4];
  const float* We    = (const float*)d_in[5];
  const float* be    = (const float*)d_in[6];
  const float* Wnode = (const float*)d_in[7];
  const float* bnode = (const float*)d_in[8];
  const float* Wedge = (const float*)d_in[9];
  const float* bedge = (const float*)d_in[10];
  const float* Wc1   = (const float*)d_in[11];
  const float* bc1   = (const float*)d_in[12];
  const float* Wc2   = (const float*)d_in[13];
  const float* bc2   = (const float*)d_in[14];
  const int*   emask = (const int*)d_in[15];
  const int*   fmask = (const int*)d_in[16];

  u16* qkbf = (u16*)d_ws;                         // 786432 B

  float* out      = (float*)d_out;
  float* node_out = out;                           // 2*384*128
  float* edge_out = out + 98304;                   // 2*384*384*64
  float* coor_out = out + 98304 + 18874368;        // 2*384*3

  const size_t NEED = 6799360;
  if (ws_size >= NEED){
    u16*   WeF   = (u16*)((char*)d_ws + 786432);   // 65536
    u16*   WgF   = (u16*)((char*)d_ws + 851968);   // 16384
    u16*   W1F   = (u16*)((char*)d_ws + 868352);   // 32768
    u16*   attL  = (u16*)((char*)d_ws + 901120);   // 4718592
    float* cattB = (float*)((char*)d_ws + 5619712);// 1179648

    prep_frag<<<dim3(28), dim3(256), 0, stream>>>(We, Wedge, Wc1, WeF, WgF, W1F);
    qk_kernel<<<dim3(192), dim3(256), 0, stream>>>(x, Wqk, bqk, qkbf);
    k1L_logits_ev<<<dim3(3, NB), dim3(256), 0, stream>>>(
        coor, eattr, be, emask, qkbf, WeF, attL, (u16*)edge_out);
    k2_softmax<<<dim3(NB), dim3(512), 0, stream>>>(attL);
    k3L_edge_c1<<<dim3(6, NB), dim3(256), 0, stream>>>(
        bedge, bc1, Wc2, qkbf, WgF, W1F, attL, edge_out, cattB);
    k4_node_coor<<<dim3(NB), dim3(256), 0, stream>>>(
        coor, Wnode, bnode, bc2, emask, fmask, qkbf, attL, cattB, node_out, coor_out);
  } else {
    u16* WeT  = (u16*)((char*)d_ws + 786432);
    u16* WgT  = (u16*)((char*)d_ws + 851968);
    u16* Wc1T = (u16*)((char*)d_ws + 868352);
    prep_wt<<<dim3(14), dim3(512), 0, stream>>>(We, Wedge, Wc1, WeT, WgT, Wc1T);
    qk_kernel<<<dim3(192), dim3(256), 0, stream>>>(x, Wqk, bqk, qkbf);
    se3_fused<<<dim3(NB), dim3(512), L_TOTAL, stream>>>(
        coor, eattr, be, bedge, Wnode, bnode, bc1, Wc2, bc2,
        emask, fmask, qkbf, WeT, WgT, Wc1T, node_out, edge_out, coor_out);
  }
}